// Round 1
// baseline (1078.649 us; speedup 1.0000x reference)
//
#include <hip/hip_runtime.h>
#include <math.h>

#define NN 50000
#define NE 800000
#define KIN 256
#define F 192      // HEADS*HID
#define NH 3
#define NC 40

// ---------------- CSR build ----------------
__global__ void count_kernel(const int* __restrict__ dst, int* __restrict__ cnt){
  int e = blockIdx.x*256 + threadIdx.x;
  if (e < NE) atomicAdd(&cnt[dst[e]], 1);
}

__global__ __launch_bounds__(1024) void scan_kernel(const int* __restrict__ cnt, int* __restrict__ row_ptr){
  __shared__ int part[1024];
  int t = threadIdx.x;
  const int CHUNK = (NN + 1023)/1024;
  int start = t*CHUNK;
  int end = start+CHUNK; if (end > NN) end = NN; if (start > NN) start = NN;
  int s = 0;
  for (int i=start;i<end;i++) s += cnt[i];
  part[t] = s;
  __syncthreads();
  for (int off=1; off<1024; off<<=1){
    int v = (t>=off)? part[t-off] : 0;
    __syncthreads();
    part[t] += v;
    __syncthreads();
  }
  int run = (t==0)? 0 : part[t-1];
  for (int i=start;i<end;i++){ row_ptr[i] = run; run += cnt[i]; }
  if (t==0) row_ptr[NN] = part[1023];
}

__global__ void fill_kernel(const int* __restrict__ src, const int* __restrict__ dst,
                            const int* __restrict__ row_ptr, int* __restrict__ cur,
                            int* __restrict__ col){
  int e = blockIdx.x*256 + threadIdx.x;
  if (e < NE){
    int d = dst[e];
    int p = row_ptr[d] + atomicAdd(&cur[d], 1);
    col[p] = src[e];
  }
}

// ---------------- GEMM: A[NN x K] @ B[K x 192] -> C[NN x 192] ----------------
template<int K>
__global__ __launch_bounds__(192) void gemm192(const float* __restrict__ A, const float* __restrict__ B,
                                               float* __restrict__ C){
  const int BM=32, BK=32;
  __shared__ float AsT[BK*33];   // [kk][r], stride 33 to break bank conflicts on store
  __shared__ float Bs[BK*F];
  int t = threadIdx.x;
  int r0 = blockIdx.x*BM;
  float acc[BM];
  #pragma unroll
  for (int r=0;r<BM;r++) acc[r]=0.f;
  for (int k0=0;k0<K;k0+=BK){
    __syncthreads();
    for (int idx=t; idx<BM*BK; idx+=192){
      int r = idx>>5, kk = idx&31;
      int row = r0+r;
      AsT[kk*33+r] = (row<NN)? A[(size_t)row*K + k0 + kk] : 0.f;
    }
    #pragma unroll
    for (int i=0;i<BK;i++) Bs[i*F+t] = B[(k0+i)*F + t];
    __syncthreads();
    #pragma unroll 4
    for (int kk=0;kk<BK;kk++){
      float bval = Bs[kk*F+t];
      #pragma unroll
      for (int r=0;r<BM;r++) acc[r] = fmaf(AsT[kk*33+r], bval, acc[r]);
    }
  }
  #pragma unroll
  for (int r=0;r<BM;r++){
    int row = r0+r;
    if (row<NN) C[(size_t)row*F+t] = acc[r];
  }
}

// ---------------- attention coefficients: a[n][h] = sum_c h[n][h*64+c]*att[h][c] ----------------
__global__ __launch_bounds__(192) void attn_kernel(const float* __restrict__ h,
    const float* __restrict__ att_src, const float* __restrict__ att_dst,
    float* __restrict__ a_src, float* __restrict__ a_dst){
  int n = blockIdx.x;
  int t = threadIdx.x, head=t>>6, lane=t&63;
  float v = h[(size_t)n*F+t];
  float ps = v*att_src[t], pd = v*att_dst[t];
  #pragma unroll
  for (int off=32; off; off>>=1){ ps += __shfl_down(ps,off); pd += __shfl_down(pd,off); }
  if (lane==0){ a_src[n*NH+head]=ps; a_dst[n*NH+head]=pd; }
}

// ---------------- GAT aggregation: one block per dst node, wave = head ----------------
__global__ __launch_bounds__(192) void gat_agg_kernel(const float* __restrict__ h,
    const float* __restrict__ a_src, const float* __restrict__ a_dst,
    const int* __restrict__ row_ptr, const int* __restrict__ col,
    const float* __restrict__ bias, float* __restrict__ out){
  __shared__ int   s_src[64];
  __shared__ float s_alpha[NH*64];
  int d = blockIdx.x;
  int t = threadIdx.x, head=t>>6, lane=t&63;
  int e0 = row_ptr[d], e1 = row_ptr[d+1];
  int deg = e1-e0;
  int ecount = deg+1;                 // implicit self-loop appended at j==deg
  float adst = a_dst[d*NH+head];
  // phase 1: online softmax stats (m,s) per head
  float m = -1e30f, s = 0.f;
  for (int j=lane; j<ecount; j+=64){
    int sn = (j<deg)? col[e0+j] : d;
    float l = a_src[sn*NH+head] + adst;
    l = (l>0.f)? l : 0.2f*l;          // leaky_relu 0.2
    float mn = fmaxf(m,l);
    s = s*__expf(m-mn) + __expf(l-mn);
    m = mn;
  }
  #pragma unroll
  for (int off=32; off; off>>=1){
    float m2 = __shfl_down(m,off), s2 = __shfl_down(s,off);
    float mn = fmaxf(m,m2);
    s = s*__expf(m-mn) + s2*__expf(m2-mn);
    m = mn;
  }
  m = __shfl(m,0); s = __shfl(s,0);
  float inv_s = 1.f/s;
  // phase 2: weighted gather, alpha staged in LDS in chunks of 64 edges
  float acc = 0.f;
  for (int base=0; base<ecount; base+=64){
    __syncthreads();
    int j = base+lane;
    if (j < ecount){
      int sn = (j<deg)? col[e0+j] : d;
      if (head==0) s_src[lane] = sn;
      float l = a_src[sn*NH+head] + adst;
      l = (l>0.f)? l : 0.2f*l;
      s_alpha[head*64+lane] = __expf(l-m)*inv_s;
    }
    __syncthreads();
    int cend = ecount-base; if (cend > 64) cend = 64;
    for (int jj=0; jj<cend; jj++){
      acc = fmaf(s_alpha[head*64+jj], h[(size_t)s_src[jj]*F + t], acc);
    }
  }
  out[(size_t)d*F+t] = fmaxf(acc + bias[t], 0.f);   // bias then ReLU (both layers)
}

// ---------------- output GEMM: A[NN x 192] @ W[192 x 40] + bout ----------------
__global__ __launch_bounds__(256) void gemm_out_kernel(const float* __restrict__ A,
    const float* __restrict__ W, const float* __restrict__ bias, float* __restrict__ C){
  __shared__ float hs[32*F];
  __shared__ float Ws[F*NC];
  int t = threadIdx.x;
  int r0 = blockIdx.x*32;
  for (int idx=t; idx<32*F; idx+=256){
    int r = idx/F, k = idx%F;
    hs[idx] = (r0+r<NN)? A[(size_t)(r0+r)*F + k] : 0.f;
  }
  for (int idx=t; idx<F*NC; idx+=256) Ws[idx] = W[idx];
  __syncthreads();
  for (int o=t; o<32*NC; o+=256){
    int r = o/NC, c = o%NC;
    float acc = 0.f;
    #pragma unroll 4
    for (int k=0;k<F;k++) acc = fmaf(hs[r*F+k], Ws[k*NC+c], acc);
    if (r0+r<NN) C[(size_t)(r0+r)*NC + c] = acc + bias[c];
  }
}

extern "C" void kernel_launch(void* const* d_in, const int* in_sizes, int n_in,
                              void* d_out, int out_size, void* d_ws, size_t ws_size,
                              hipStream_t stream){
  const float* x    = (const float*)d_in[0];
  const int*   ei   = (const int*)  d_in[1];
  const float* W1   = (const float*)d_in[2];
  const float* as1  = (const float*)d_in[3];
  const float* ad1  = (const float*)d_in[4];
  const float* b1   = (const float*)d_in[5];
  const float* W2   = (const float*)d_in[6];
  const float* as2  = (const float*)d_in[7];
  const float* ad2  = (const float*)d_in[8];
  const float* b2   = (const float*)d_in[9];
  const float* Wout = (const float*)d_in[10];
  const float* bout = (const float*)d_in[11];
  float* out = (float*)d_out;

  // workspace carve-out (~120 MB)
  float* bufA  = (float*)d_ws;                   // N*F  (h1, later reused for layer-2 agg out)
  float* bufB  = bufA + (size_t)NN*F;            // N*F  (relu(agg1+b1))
  float* bufC  = bufB + (size_t)NN*F;            // N*F  (bufB @ W2)
  float* a_src = bufC + (size_t)NN*F;            // N*3
  float* a_dst = a_src + (size_t)NN*NH;          // N*3
  int* row_ptr = (int*)(a_dst + (size_t)NN*NH);  // N+1
  int* col     = row_ptr + (NN+1);               // E
  int* cnt     = col + NE;                       // N

  const int* srcv = ei;
  const int* dstv = ei + NE;

  // CSR by destination (features-independent, rebuilt every call)
  hipMemsetAsync(cnt, 0, NN*sizeof(int), stream);
  count_kernel<<<(NE+255)/256, 256, 0, stream>>>(dstv, cnt);
  scan_kernel<<<1, 1024, 0, stream>>>(cnt, row_ptr);
  hipMemsetAsync(cnt, 0, NN*sizeof(int), stream);
  fill_kernel<<<(NE+255)/256, 256, 0, stream>>>(srcv, dstv, row_ptr, cnt, col);

  const int GB = (NN + 31)/32;
  // layer 1
  gemm192<KIN><<<GB, 192, 0, stream>>>(x, W1, bufA);
  attn_kernel<<<NN, 192, 0, stream>>>(bufA, as1, ad1, a_src, a_dst);
  gat_agg_kernel<<<NN, 192, 0, stream>>>(bufA, a_src, a_dst, row_ptr, col, b1, bufB);
  // layer 2
  gemm192<F><<<GB, 192, 0, stream>>>(bufB, W2, bufC);
  attn_kernel<<<NN, 192, 0, stream>>>(bufC, as2, ad2, a_src, a_dst);
  gat_agg_kernel<<<NN, 192, 0, stream>>>(bufC, a_src, a_dst, row_ptr, col, b2, bufA);
  // readout
  gemm_out_kernel<<<GB, 256, 0, stream>>>(bufA, Wout, bout, out);
}

// Round 2
// 645.618 us; speedup vs baseline: 1.6707x; 1.6707x over previous
//
#include <hip/hip_runtime.h>
#include <math.h>

#define NN 50000
#define NE 800000
#define KIN 256
#define F 192      // HEADS*HID
#define NH 3
#define NC 40

// ---------------- CSR build ----------------
__global__ void count_kernel(const int* __restrict__ dst, int* __restrict__ cnt){
  int e = blockIdx.x*256 + threadIdx.x;
  if (e < NE) atomicAdd(&cnt[dst[e]], 1);
}

__global__ __launch_bounds__(1024) void scan_kernel(const int* __restrict__ cnt, int* __restrict__ row_ptr){
  __shared__ int part[1024];
  int t = threadIdx.x;
  const int CHUNK = (NN + 1023)/1024;
  int start = t*CHUNK;
  int end = start+CHUNK; if (end > NN) end = NN; if (start > NN) start = NN;
  int s = 0;
  for (int i=start;i<end;i++) s += cnt[i];
  part[t] = s;
  __syncthreads();
  for (int off=1; off<1024; off<<=1){
    int v = (t>=off)? part[t-off] : 0;
    __syncthreads();
    part[t] += v;
    __syncthreads();
  }
  int run = (t==0)? 0 : part[t-1];
  for (int i=start;i<end;i++){ row_ptr[i] = run; run += cnt[i]; }
  if (t==0) row_ptr[NN] = part[1023];
}

__global__ void fill_kernel(const int* __restrict__ src, const int* __restrict__ dst,
                            const int* __restrict__ row_ptr, int* __restrict__ cur,
                            int* __restrict__ col){
  int e = blockIdx.x*256 + threadIdx.x;
  if (e < NE){
    int d = dst[e];
    int p = row_ptr[d] + atomicAdd(&cur[d], 1);
    col[p] = src[e];
  }
}

// ---------------- register-tiled GEMM: A[NN x K] @ B[K x 192] -> C[NN x 192] ----------
// BM=128 rows, BN=64 cols (== one head), BK=32. 256 threads: tx=t&15 (4 cols each),
// ty=t>>4 (8 rows each). acc[8][4]. Optionally fuses a_src/a_dst attention dots.
#define SA 132   // padded LDS stride for transposed A tile (keeps 16B align, limits conflicts)
template<int K, bool ATT>
__global__ __launch_bounds__(256) void gemm_reg(const float* __restrict__ A, const float* __restrict__ B,
                                                float* __restrict__ C,
                                                const float* __restrict__ att_src, const float* __restrict__ att_dst,
                                                float* __restrict__ a_src, float* __restrict__ a_dst){
  __shared__ __align__(16) float As[32*SA];   // [k][m]
  __shared__ __align__(16) float Bs[32*64];   // [k][c]
  const int t = threadIdx.x;
  const int tx = t & 15, ty = t >> 4;
  const int r0 = blockIdx.x*128;
  const int head = blockIdx.y;
  const int c0 = head*64;
  float acc[8][4];
  #pragma unroll
  for (int r=0;r<8;r++)
    #pragma unroll
    for (int c=0;c<4;c++) acc[r][c]=0.f;

  for (int k0=0; k0<K; k0+=32){
    __syncthreads();
    // A tile: 128 rows x 32 k, transposed into As[k][m]
    #pragma unroll
    for (int i=0;i<4;i++){
      int idx = t + i*256;            // 0..1023
      int row = idx >> 3, kq = idx & 7;
      float4 v = make_float4(0.f,0.f,0.f,0.f);
      if (r0+row < NN) v = *(const float4*)&A[(size_t)(r0+row)*K + k0 + kq*4];
      As[(kq*4+0)*SA + row] = v.x;
      As[(kq*4+1)*SA + row] = v.y;
      As[(kq*4+2)*SA + row] = v.z;
      As[(kq*4+3)*SA + row] = v.w;
    }
    // B tile: 32 k x 64 cols
    #pragma unroll
    for (int i=0;i<2;i++){
      int idx = t + i*256;            // 0..511
      int k = idx >> 4, cq = idx & 15;
      *(float4*)&Bs[k*64 + cq*4] = *(const float4*)&B[(size_t)(k0+k)*F + c0 + cq*4];
    }
    __syncthreads();
    #pragma unroll
    for (int k=0;k<32;k++){
      float4 b  = *(float4*)&Bs[k*64 + tx*4];
      float4 a0 = *(float4*)&As[k*SA + ty*8];
      float4 a1 = *(float4*)&As[k*SA + ty*8 + 4];
      float ar[8] = {a0.x,a0.y,a0.z,a0.w,a1.x,a1.y,a1.z,a1.w};
      #pragma unroll
      for (int r=0;r<8;r++){
        acc[r][0] = fmaf(ar[r], b.x, acc[r][0]);
        acc[r][1] = fmaf(ar[r], b.y, acc[r][1]);
        acc[r][2] = fmaf(ar[r], b.z, acc[r][2]);
        acc[r][3] = fmaf(ar[r], b.w, acc[r][3]);
      }
    }
  }
  // store C
  #pragma unroll
  for (int r=0;r<8;r++){
    int row = r0 + ty*8 + r;
    if (row < NN){
      float4 v = make_float4(acc[r][0],acc[r][1],acc[r][2],acc[r][3]);
      *(float4*)&C[(size_t)row*F + c0 + tx*4] = v;
    }
  }
  if (ATT){
    // attention dots: this block's 64 cols are exactly head `head`
    float ws[4], wd[4];
    #pragma unroll
    for (int j=0;j<4;j++){
      ws[j] = att_src[c0 + tx*4 + j];
      wd[j] = att_dst[c0 + tx*4 + j];
    }
    #pragma unroll
    for (int r=0;r<8;r++){
      float ps = acc[r][0]*ws[0] + acc[r][1]*ws[1] + acc[r][2]*ws[2] + acc[r][3]*ws[3];
      float pd = acc[r][0]*wd[0] + acc[r][1]*wd[1] + acc[r][2]*wd[2] + acc[r][3]*wd[3];
      #pragma unroll
      for (int off=8; off; off>>=1){
        ps += __shfl_down(ps, off);
        pd += __shfl_down(pd, off);
      }
      int row = r0 + ty*8 + r;
      if (tx==0 && row < NN){
        a_src[row*NH + head] = ps;
        a_dst[row*NH + head] = pd;
      }
    }
  }
}

// ---------------- GAT aggregation: one block per dst node, wave = head ----------------
__global__ __launch_bounds__(192) void gat_agg_kernel(const float* __restrict__ h,
    const float* __restrict__ a_src, const float* __restrict__ a_dst,
    const int* __restrict__ row_ptr, const int* __restrict__ col,
    const float* __restrict__ bias, float* __restrict__ out){
  __shared__ int   s_src[64];
  __shared__ float s_alpha[NH*64];
  int d = blockIdx.x;
  int t = threadIdx.x, head=t>>6, lane=t&63;
  int e0 = row_ptr[d], e1 = row_ptr[d+1];
  int deg = e1-e0;
  int ecount = deg+1;                 // implicit self-loop appended at j==deg
  float adst = a_dst[d*NH+head];
  // phase 1: online softmax stats (m,s) per head
  float m = -1e30f, s = 0.f;
  for (int j=lane; j<ecount; j+=64){
    int sn = (j<deg)? col[e0+j] : d;
    float l = a_src[sn*NH+head] + adst;
    l = (l>0.f)? l : 0.2f*l;          // leaky_relu 0.2
    float mn = fmaxf(m,l);
    s = s*__expf(m-mn) + __expf(l-mn);
    m = mn;
  }
  #pragma unroll
  for (int off=32; off; off>>=1){
    float m2 = __shfl_down(m,off), s2 = __shfl_down(s,off);
    float mn = fmaxf(m,m2);
    s = s*__expf(m-mn) + s2*__expf(m2-mn);
    m = mn;
  }
  m = __shfl(m,0); s = __shfl(s,0);
  float inv_s = 1.f/s;
  // phase 2: weighted gather, alpha staged in LDS in chunks of 64 edges
  float acc = 0.f;
  for (int base=0; base<ecount; base+=64){
    __syncthreads();
    int j = base+lane;
    if (j < ecount){
      int sn = (j<deg)? col[e0+j] : d;
      if (head==0) s_src[lane] = sn;
      float l = a_src[sn*NH+head] + adst;
      l = (l>0.f)? l : 0.2f*l;
      s_alpha[head*64+lane] = __expf(l-m)*inv_s;
    }
    __syncthreads();
    int cend = ecount-base; if (cend > 64) cend = 64;
    #pragma unroll 4
    for (int jj=0; jj<cend; jj++){
      acc = fmaf(s_alpha[head*64+jj], h[(size_t)s_src[jj]*F + t], acc);
    }
  }
  out[(size_t)d*F+t] = fmaxf(acc + bias[t], 0.f);   // bias then ReLU (both layers)
}

// ---------------- output GEMM: A[NN x 192] @ W[192 x 40] + bout -> C[NN x 40] ----------
// BM=128 rows, BK=32. 256 threads: tx=t&7 (5 cols each), ty=t>>3 (4 rows each). acc[4][5].
__global__ __launch_bounds__(256) void gemm_out_kernel(const float* __restrict__ A,
    const float* __restrict__ W, const float* __restrict__ bias, float* __restrict__ C){
  __shared__ __align__(16) float As[32*SA];   // [k][m]
  __shared__ float Ws[32*NC];                  // [k][c]
  const int t = threadIdx.x;
  const int tx = t & 7, ty = t >> 3;
  const int r0 = blockIdx.x*128;
  float acc[4][5];
  #pragma unroll
  for (int r=0;r<4;r++)
    #pragma unroll
    for (int c=0;c<5;c++) acc[r][c]=0.f;

  for (int k0=0; k0<F; k0+=32){
    __syncthreads();
    #pragma unroll
    for (int i=0;i<4;i++){
      int idx = t + i*256;
      int row = idx >> 3, kq = idx & 7;
      float4 v = make_float4(0.f,0.f,0.f,0.f);
      if (r0+row < NN) v = *(const float4*)&A[(size_t)(r0+row)*F + k0 + kq*4];
      As[(kq*4+0)*SA + row] = v.x;
      As[(kq*4+1)*SA + row] = v.y;
      As[(kq*4+2)*SA + row] = v.z;
      As[(kq*4+3)*SA + row] = v.w;
    }
    #pragma unroll
    for (int i=0;i<5;i++){
      int idx = t + i*256;            // 0..1279
      int k = idx/NC, c = idx%NC;
      Ws[k*NC + c] = W[(size_t)(k0+k)*NC + c];
    }
    __syncthreads();
    #pragma unroll
    for (int k=0;k<32;k++){
      float4 a = *(float4*)&As[k*SA + ty*4];
      float av[4] = {a.x,a.y,a.z,a.w};
      float bv[5];
      #pragma unroll
      for (int c=0;c<5;c++) bv[c] = Ws[k*NC + tx*5 + c];
      #pragma unroll
      for (int r=0;r<4;r++)
        #pragma unroll
        for (int c=0;c<5;c++) acc[r][c] = fmaf(av[r], bv[c], acc[r][c]);
    }
  }
  #pragma unroll
  for (int r=0;r<4;r++){
    int row = r0 + ty*4 + r;
    if (row < NN){
      #pragma unroll
      for (int c=0;c<5;c++) C[(size_t)row*NC + tx*5 + c] = acc[r][c] + bias[tx*5+c];
    }
  }
}

extern "C" void kernel_launch(void* const* d_in, const int* in_sizes, int n_in,
                              void* d_out, int out_size, void* d_ws, size_t ws_size,
                              hipStream_t stream){
  const float* x    = (const float*)d_in[0];
  const int*   ei   = (const int*)  d_in[1];
  const float* W1   = (const float*)d_in[2];
  const float* as1  = (const float*)d_in[3];
  const float* ad1  = (const float*)d_in[4];
  const float* b1   = (const float*)d_in[5];
  const float* W2   = (const float*)d_in[6];
  const float* as2  = (const float*)d_in[7];
  const float* ad2  = (const float*)d_in[8];
  const float* b2   = (const float*)d_in[9];
  const float* Wout = (const float*)d_in[10];
  const float* bout = (const float*)d_in[11];
  float* out = (float*)d_out;

  // workspace carve-out
  float* bufA  = (float*)d_ws;                   // N*F  (h1, later reused for layer-2 agg out)
  float* bufB  = bufA + (size_t)NN*F;            // N*F  (relu(agg1+b1))
  float* bufC  = bufB + (size_t)NN*F;            // N*F  (bufB @ W2)
  float* a_src = bufC + (size_t)NN*F;            // N*3
  float* a_dst = a_src + (size_t)NN*NH;          // N*3
  int* row_ptr = (int*)(a_dst + (size_t)NN*NH);  // N+1
  int* col     = row_ptr + (NN+1);               // E
  int* cnt     = col + NE;                       // N

  const int* srcv = ei;
  const int* dstv = ei + NE;

  // CSR by destination (rebuilt every call)
  hipMemsetAsync(cnt, 0, NN*sizeof(int), stream);
  count_kernel<<<(NE+255)/256, 256, 0, stream>>>(dstv, cnt);
  scan_kernel<<<1, 1024, 0, stream>>>(cnt, row_ptr);
  hipMemsetAsync(cnt, 0, NN*sizeof(int), stream);
  fill_kernel<<<(NE+255)/256, 256, 0, stream>>>(srcv, dstv, row_ptr, cnt, col);

  const dim3 gemm_grid((NN + 127)/128, NH);
  // layer 1 (attention dots fused into GEMM epilogue)
  gemm_reg<KIN,true><<<gemm_grid, 256, 0, stream>>>(x, W1, bufA, as1, ad1, a_src, a_dst);
  gat_agg_kernel<<<NN, 192, 0, stream>>>(bufA, a_src, a_dst, row_ptr, col, b1, bufB);
  // layer 2
  gemm_reg<F,true><<<gemm_grid, 256, 0, stream>>>(bufB, W2, bufC, as2, ad2, a_src, a_dst);
  gat_agg_kernel<<<NN, 192, 0, stream>>>(bufC, a_src, a_dst, row_ptr, col, b2, bufA);
  // readout
  gemm_out_kernel<<<(NN + 127)/128, 256, 0, stream>>>(bufA, Wout, bout, out);
}

// Round 3
// 620.536 us; speedup vs baseline: 1.7383x; 1.0404x over previous
//
#include <hip/hip_runtime.h>
#include <math.h>

#define NN 50000
#define NE 800000
#define KIN 256
#define F 192      // HEADS*HID
#define NH 3
#define NC 40

// ---------------- CSR build ----------------
__global__ void count_kernel(const int* __restrict__ dst, int* __restrict__ cnt){
  int e = blockIdx.x*256 + threadIdx.x;
  if (e < NE) atomicAdd(&cnt[dst[e]], 1);
}

__global__ __launch_bounds__(1024) void scan_kernel(const int* __restrict__ cnt, int* __restrict__ row_ptr){
  __shared__ int part[1024];
  int t = threadIdx.x;
  const int CHUNK = (NN + 1023)/1024;
  int start = t*CHUNK;
  int end = start+CHUNK; if (end > NN) end = NN; if (start > NN) start = NN;
  int s = 0;
  for (int i=start;i<end;i++) s += cnt[i];
  part[t] = s;
  __syncthreads();
  for (int off=1; off<1024; off<<=1){
    int v = (t>=off)? part[t-off] : 0;
    __syncthreads();
    part[t] += v;
    __syncthreads();
  }
  int run = (t==0)? 0 : part[t-1];
  for (int i=start;i<end;i++){ row_ptr[i] = run; run += cnt[i]; }
  if (t==0) row_ptr[NN] = part[1023];
}

__global__ void fill_kernel(const int* __restrict__ src, const int* __restrict__ dst,
                            const int* __restrict__ row_ptr, int* __restrict__ cur,
                            int* __restrict__ col){
  int e = blockIdx.x*256 + threadIdx.x;
  if (e < NE){
    int d = dst[e];
    int p = row_ptr[d] + atomicAdd(&cur[d], 1);
    col[p] = src[e];
  }
}

// ---------------- register-tiled GEMM: A[NN x K] @ B[K x 192] -> C[NN x 192] ----------
// BM=128 rows, BN=64 cols (== one head), BK=32. 256 threads: tx=t&15 (4 cols each),
// ty=t>>4 (8 rows each). acc[8][4]. Optionally fuses a_src/a_dst attention dots.
// grid = (NH, nRowBlocks): consecutive blocks share the same A tile -> L2 reuse.
#define SA 132   // padded LDS stride for transposed A tile
template<int K, bool ATT>
__global__ __launch_bounds__(256) void gemm_reg(const float* __restrict__ A, const float* __restrict__ B,
                                                float* __restrict__ C,
                                                const float* __restrict__ att_src, const float* __restrict__ att_dst,
                                                float* __restrict__ a_src, float* __restrict__ a_dst){
  __shared__ __align__(16) float As[32*SA];   // [k][m]
  __shared__ __align__(16) float Bs[32*64];   // [k][c]
  const int t = threadIdx.x;
  const int tx = t & 15, ty = t >> 4;
  const int r0 = blockIdx.y*128;
  const int head = blockIdx.x;
  const int c0 = head*64;
  float acc[8][4];
  #pragma unroll
  for (int r=0;r<8;r++)
    #pragma unroll
    for (int c=0;c<4;c++) acc[r][c]=0.f;

  for (int k0=0; k0<K; k0+=32){
    __syncthreads();
    // A tile: 128 rows x 32 k, transposed into As[k][m]
    #pragma unroll
    for (int i=0;i<4;i++){
      int idx = t + i*256;            // 0..1023
      int row = idx >> 3, kq = idx & 7;
      float4 v = make_float4(0.f,0.f,0.f,0.f);
      if (r0+row < NN) v = *(const float4*)&A[(size_t)(r0+row)*K + k0 + kq*4];
      As[(kq*4+0)*SA + row] = v.x;
      As[(kq*4+1)*SA + row] = v.y;
      As[(kq*4+2)*SA + row] = v.z;
      As[(kq*4+3)*SA + row] = v.w;
    }
    // B tile: 32 k x 64 cols
    #pragma unroll
    for (int i=0;i<2;i++){
      int idx = t + i*256;            // 0..511
      int k = idx >> 4, cq = idx & 15;
      *(float4*)&Bs[k*64 + cq*4] = *(const float4*)&B[(size_t)(k0+k)*F + c0 + cq*4];
    }
    __syncthreads();
    #pragma unroll
    for (int k=0;k<32;k++){
      float4 b  = *(float4*)&Bs[k*64 + tx*4];
      float4 a0 = *(float4*)&As[k*SA + ty*8];
      float4 a1 = *(float4*)&As[k*SA + ty*8 + 4];
      float ar[8] = {a0.x,a0.y,a0.z,a0.w,a1.x,a1.y,a1.z,a1.w};
      #pragma unroll
      for (int r=0;r<8;r++){
        acc[r][0] = fmaf(ar[r], b.x, acc[r][0]);
        acc[r][1] = fmaf(ar[r], b.y, acc[r][1]);
        acc[r][2] = fmaf(ar[r], b.z, acc[r][2]);
        acc[r][3] = fmaf(ar[r], b.w, acc[r][3]);
      }
    }
  }
  // store C
  #pragma unroll
  for (int r=0;r<8;r++){
    int row = r0 + ty*8 + r;
    if (row < NN){
      float4 v = make_float4(acc[r][0],acc[r][1],acc[r][2],acc[r][3]);
      *(float4*)&C[(size_t)row*F + c0 + tx*4] = v;
    }
  }
  if (ATT){
    float ws[4], wd[4];
    #pragma unroll
    for (int j=0;j<4;j++){
      ws[j] = att_src[c0 + tx*4 + j];
      wd[j] = att_dst[c0 + tx*4 + j];
    }
    #pragma unroll
    for (int r=0;r<8;r++){
      float ps = acc[r][0]*ws[0] + acc[r][1]*ws[1] + acc[r][2]*ws[2] + acc[r][3]*ws[3];
      float pd = acc[r][0]*wd[0] + acc[r][1]*wd[1] + acc[r][2]*wd[2] + acc[r][3]*wd[3];
      #pragma unroll
      for (int off=8; off; off>>=1){
        ps += __shfl_down(ps, off);
        pd += __shfl_down(pd, off);
      }
      int row = r0 + ty*8 + r;
      if (tx==0 && row < NN){
        a_src[row*NH + head] = ps;
        a_dst[row*NH + head] = pd;
      }
    }
  }
}

// ---------------- GAT aggregation: one block per dst node ----------------
// Phase 1: online softmax stats, 3 waves = 3 heads.
// Phase 2: float4 gather — 48 col-threads x 4 edge-groups, LDS cross-group reduce.
__global__ __launch_bounds__(192) void gat_agg_kernel(const float* __restrict__ h,
    const float* __restrict__ a_src, const float* __restrict__ a_dst,
    const int* __restrict__ row_ptr, const int* __restrict__ col,
    const float* __restrict__ bias, float* __restrict__ out){
  __shared__ int   s_src[64];
  __shared__ float s_alpha[NH*64];
  __shared__ float s_red[4*192];
  int d = blockIdx.x;
  int t = threadIdx.x, head=t>>6, lane=t&63;
  int e0 = row_ptr[d];
  int deg = row_ptr[d+1]-e0;
  int ecount = deg+1;                 // implicit self-loop appended at j==deg
  float adst = a_dst[d*NH+head];
  // phase 1: online softmax stats (m,s) per head
  float m = -1e30f, s = 0.f;
  for (int j=lane; j<ecount; j+=64){
    int sn = (j<deg)? col[e0+j] : d;
    float l = a_src[sn*NH+head] + adst;
    l = (l>0.f)? l : 0.2f*l;          // leaky_relu 0.2
    float mn = fmaxf(m,l);
    s = s*__expf(m-mn) + __expf(l-mn);
    m = mn;
  }
  #pragma unroll
  for (int off=32; off; off>>=1){
    float m2 = __shfl_down(m,off), s2 = __shfl_down(s,off);
    float mn = fmaxf(m,m2);
    s = s*__expf(m-mn) + s2*__expf(m2-mn);
    m = mn;
  }
  m = __shfl(m,0); s = __shfl(s,0);
  float inv_s = 1.f/s;

  // phase 2: vectorized weighted gather
  const int cth = t % 48;             // column group: cols cth*4 .. cth*4+3
  const int eq  = t / 48;             // edge subgroup 0..3
  const int hg  = cth >> 4;           // head owning these columns
  float4 acc = make_float4(0.f,0.f,0.f,0.f);
  for (int base=0; base<ecount; base+=64){
    __syncthreads();
    int j = base+lane;
    if (j < ecount){
      int sn = (j<deg)? col[e0+j] : d;
      if (head==0) s_src[lane] = sn;
      float l = a_src[sn*NH+head] + adst;
      l = (l>0.f)? l : 0.2f*l;
      s_alpha[head*64+lane] = __expf(l-m)*inv_s;
    }
    __syncthreads();
    int cend = ecount-base; if (cend > 64) cend = 64;
    for (int jj=eq; jj<cend; jj+=4){
      int sn = s_src[jj];
      float al = s_alpha[hg*64+jj];
      const float4 hv = *(const float4*)&h[(size_t)sn*F + cth*4];
      acc.x = fmaf(al, hv.x, acc.x);
      acc.y = fmaf(al, hv.y, acc.y);
      acc.z = fmaf(al, hv.z, acc.z);
      acc.w = fmaf(al, hv.w, acc.w);
    }
  }
  *(float4*)&s_red[eq*192 + cth*4] = acc;
  __syncthreads();
  if (t < 48){
    float4 r0 = *(float4*)&s_red[0*192 + t*4];
    float4 r1 = *(float4*)&s_red[1*192 + t*4];
    float4 r2 = *(float4*)&s_red[2*192 + t*4];
    float4 r3 = *(float4*)&s_red[3*192 + t*4];
    float4 b4 = *(const float4*)&bias[t*4];
    float4 o;
    o.x = fmaxf(r0.x+r1.x+r2.x+r3.x + b4.x, 0.f);
    o.y = fmaxf(r0.y+r1.y+r2.y+r3.y + b4.y, 0.f);
    o.z = fmaxf(r0.z+r1.z+r2.z+r3.z + b4.z, 0.f);
    o.w = fmaxf(r0.w+r1.w+r2.w+r3.w + b4.w, 0.f);
    *(float4*)&out[(size_t)d*F + t*4] = o;
  }
}

// ---------------- output GEMM: A[NN x 192] @ W[192 x 40] + bout -> C[NN x 40] ----------
__global__ __launch_bounds__(256) void gemm_out_kernel(const float* __restrict__ A,
    const float* __restrict__ W, const float* __restrict__ bias, float* __restrict__ C){
  __shared__ __align__(16) float As[32*SA];   // [k][m]
  __shared__ float Ws[32*NC];                  // [k][c]
  const int t = threadIdx.x;
  const int tx = t & 7, ty = t >> 3;
  const int r0 = blockIdx.x*128;
  float acc[4][5];
  #pragma unroll
  for (int r=0;r<4;r++)
    #pragma unroll
    for (int c=0;c<5;c++) acc[r][c]=0.f;

  for (int k0=0; k0<F; k0+=32){
    __syncthreads();
    #pragma unroll
    for (int i=0;i<4;i++){
      int idx = t + i*256;
      int row = idx >> 3, kq = idx & 7;
      float4 v = make_float4(0.f,0.f,0.f,0.f);
      if (r0+row < NN) v = *(const float4*)&A[(size_t)(r0+row)*F + k0 + kq*4];
      As[(kq*4+0)*SA + row] = v.x;
      As[(kq*4+1)*SA + row] = v.y;
      As[(kq*4+2)*SA + row] = v.z;
      As[(kq*4+3)*SA + row] = v.w;
    }
    #pragma unroll
    for (int i=0;i<5;i++){
      int idx = t + i*256;            // 0..1279
      int k = idx/NC, c = idx%NC;
      Ws[k*NC + c] = W[(size_t)(k0+k)*NC + c];
    }
    __syncthreads();
    #pragma unroll
    for (int k=0;k<32;k++){
      float4 a = *(float4*)&As[k*SA + ty*4];
      float av[4] = {a.x,a.y,a.z,a.w};
      float bv[5];
      #pragma unroll
      for (int c=0;c<5;c++) bv[c] = Ws[k*NC + tx*5 + c];
      #pragma unroll
      for (int r=0;r<4;r++)
        #pragma unroll
        for (int c=0;c<5;c++) acc[r][c] = fmaf(av[r], bv[c], acc[r][c]);
    }
  }
  #pragma unroll
  for (int r=0;r<4;r++){
    int row = r0 + ty*4 + r;
    if (row < NN){
      #pragma unroll
      for (int c=0;c<5;c++) C[(size_t)row*NC + tx*5 + c] = acc[r][c] + bias[tx*5+c];
    }
  }
}

extern "C" void kernel_launch(void* const* d_in, const int* in_sizes, int n_in,
                              void* d_out, int out_size, void* d_ws, size_t ws_size,
                              hipStream_t stream){
  const float* x    = (const float*)d_in[0];
  const int*   ei   = (const int*)  d_in[1];
  const float* W1   = (const float*)d_in[2];
  const float* as1  = (const float*)d_in[3];
  const float* ad1  = (const float*)d_in[4];
  const float* b1   = (const float*)d_in[5];
  const float* W2   = (const float*)d_in[6];
  const float* as2  = (const float*)d_in[7];
  const float* ad2  = (const float*)d_in[8];
  const float* b2   = (const float*)d_in[9];
  const float* Wout = (const float*)d_in[10];
  const float* bout = (const float*)d_in[11];
  float* out = (float*)d_out;

  // workspace carve-out
  float* bufA  = (float*)d_ws;                   // N*F  (h1, later reused for layer-2 agg out)
  float* bufB  = bufA + (size_t)NN*F;            // N*F  (relu(agg1+b1))
  float* bufC  = bufB + (size_t)NN*F;            // N*F  (bufB @ W2)
  float* a_src = bufC + (size_t)NN*F;            // N*3
  float* a_dst = a_src + (size_t)NN*NH;          // N*3
  int* row_ptr = (int*)(a_dst + (size_t)NN*NH);  // N+1
  int* col     = row_ptr + (NN+1);               // E
  int* cnt     = col + NE;                       // N

  const int* srcv = ei;
  const int* dstv = ei + NE;

  // CSR by destination (rebuilt every call)
  hipMemsetAsync(cnt, 0, NN*sizeof(int), stream);
  count_kernel<<<(NE+255)/256, 256, 0, stream>>>(dstv, cnt);
  scan_kernel<<<1, 1024, 0, stream>>>(cnt, row_ptr);
  hipMemsetAsync(cnt, 0, NN*sizeof(int), stream);
  fill_kernel<<<(NE+255)/256, 256, 0, stream>>>(srcv, dstv, row_ptr, cnt, col);

  const dim3 gemm_grid(NH, (NN + 127)/128);   // heads adjacent -> A tile shared in L2
  // layer 1 (attention dots fused into GEMM epilogue)
  gemm_reg<KIN,true><<<gemm_grid, 256, 0, stream>>>(x, W1, bufA, as1, ad1, a_src, a_dst);
  gat_agg_kernel<<<NN, 192, 0, stream>>>(bufA, a_src, a_dst, row_ptr, col, b1, bufB);
  // layer 2
  gemm_reg<F,true><<<gemm_grid, 256, 0, stream>>>(bufB, W2, bufC, as2, ad2, a_src, a_dst);
  gat_agg_kernel<<<NN, 192, 0, stream>>>(bufC, a_src, a_dst, row_ptr, col, b2, bufA);
  // readout
  gemm_out_kernel<<<(NN + 127)/128, 256, 0, stream>>>(bufA, Wout, bout, out);
}

// Round 4
// 573.468 us; speedup vs baseline: 1.8809x; 1.0821x over previous
//
#include <hip/hip_runtime.h>
#include <math.h>

#define NN 50000
#define NE 800000
#define KIN 256
#define F 192      // HEADS*HID
#define NH 3
#define NC 40

typedef unsigned short u16;
typedef unsigned int   u32;

static __device__ __forceinline__ u16 f2bf(float f){
  u32 u = __float_as_uint(f);
  u32 r = (u + 0x7fffu + ((u >> 16) & 1u)) >> 16;   // RNE
  return (u16)r;
}

// ---------------- CSR build ----------------
__global__ void count_kernel(const int* __restrict__ dst, int* __restrict__ cnt){
  int e = blockIdx.x*256 + threadIdx.x;
  if (e < NE) atomicAdd(&cnt[dst[e]], 1);
}

__global__ __launch_bounds__(1024) void scan_kernel(const int* __restrict__ cnt, int* __restrict__ row_ptr){
  __shared__ int part[1024];
  int t = threadIdx.x;
  const int CHUNK = (NN + 1023)/1024;
  int start = t*CHUNK;
  int end = start+CHUNK; if (end > NN) end = NN; if (start > NN) start = NN;
  int s = 0;
  for (int i=start;i<end;i++) s += cnt[i];
  part[t] = s;
  __syncthreads();
  for (int off=1; off<1024; off<<=1){
    int v = (t>=off)? part[t-off] : 0;
    __syncthreads();
    part[t] += v;
    __syncthreads();
  }
  int run = (t==0)? 0 : part[t-1];
  for (int i=start;i<end;i++){ row_ptr[i] = run; run += cnt[i]; }
  if (t==0) row_ptr[NN] = part[1023];
}

__global__ void fill_kernel(const int* __restrict__ src, const int* __restrict__ dst,
                            const int* __restrict__ row_ptr, int* __restrict__ cur,
                            int* __restrict__ col){
  int e = blockIdx.x*256 + threadIdx.x;
  if (e < NE){
    int d = dst[e];
    int p = row_ptr[d] + atomicAdd(&cur[d], 1);
    col[p] = src[e];
  }
}

// ---------------- register-tiled GEMM: A[NN x K](fp32) @ B[K x 192] -> C bf16 ----------
// BM=128, BN=64 (one head), BK=32. 256 thr: tx=t&15 (4 cols), ty=t>>4 (8 rows).
// Fuses attention dots (a_src4/a_dst4, stride 4) and fp32->bf16 C store.
#define SA 132
template<int K>
__global__ __launch_bounds__(256) void gemm_reg(const float* __restrict__ A, const float* __restrict__ B,
                                                u16* __restrict__ C,
                                                const float* __restrict__ att_src, const float* __restrict__ att_dst,
                                                float* __restrict__ a_src4, float* __restrict__ a_dst4){
  __shared__ __align__(16) float As[32*SA];   // [k][m]
  __shared__ __align__(16) float Bs[32*64];   // [k][c]
  const int t = threadIdx.x;
  const int tx = t & 15, ty = t >> 4;
  const int r0 = blockIdx.y*128;
  const int head = blockIdx.x;
  const int c0 = head*64;
  float acc[8][4];
  #pragma unroll
  for (int r=0;r<8;r++)
    #pragma unroll
    for (int c=0;c<4;c++) acc[r][c]=0.f;

  for (int k0=0; k0<K; k0+=32){
    __syncthreads();
    #pragma unroll
    for (int i=0;i<4;i++){
      int idx = t + i*256;            // 0..1023
      int row = idx >> 3, kq = idx & 7;
      float4 v = make_float4(0.f,0.f,0.f,0.f);
      if (r0+row < NN) v = *(const float4*)&A[(size_t)(r0+row)*K + k0 + kq*4];
      As[(kq*4+0)*SA + row] = v.x;
      As[(kq*4+1)*SA + row] = v.y;
      As[(kq*4+2)*SA + row] = v.z;
      As[(kq*4+3)*SA + row] = v.w;
    }
    #pragma unroll
    for (int i=0;i<2;i++){
      int idx = t + i*256;            // 0..511
      int k = idx >> 4, cq = idx & 15;
      *(float4*)&Bs[k*64 + cq*4] = *(const float4*)&B[(size_t)(k0+k)*F + c0 + cq*4];
    }
    __syncthreads();
    #pragma unroll
    for (int k=0;k<32;k++){
      float4 b  = *(float4*)&Bs[k*64 + tx*4];
      float4 a0 = *(float4*)&As[k*SA + ty*8];
      float4 a1 = *(float4*)&As[k*SA + ty*8 + 4];
      float ar[8] = {a0.x,a0.y,a0.z,a0.w,a1.x,a1.y,a1.z,a1.w};
      #pragma unroll
      for (int r=0;r<8;r++){
        acc[r][0] = fmaf(ar[r], b.x, acc[r][0]);
        acc[r][1] = fmaf(ar[r], b.y, acc[r][1]);
        acc[r][2] = fmaf(ar[r], b.z, acc[r][2]);
        acc[r][3] = fmaf(ar[r], b.w, acc[r][3]);
      }
    }
  }
  // store C as bf16 (8B per thread)
  #pragma unroll
  for (int r=0;r<8;r++){
    int row = r0 + ty*8 + r;
    if (row < NN){
      uint2 p;
      p.x = (u32)f2bf(acc[r][0]) | ((u32)f2bf(acc[r][1]) << 16);
      p.y = (u32)f2bf(acc[r][2]) | ((u32)f2bf(acc[r][3]) << 16);
      *(uint2*)&C[(size_t)row*F + c0 + tx*4] = p;
    }
  }
  // attention dots (fp32 accs)
  float ws[4], wd[4];
  #pragma unroll
  for (int j=0;j<4;j++){
    ws[j] = att_src[c0 + tx*4 + j];
    wd[j] = att_dst[c0 + tx*4 + j];
  }
  #pragma unroll
  for (int r=0;r<8;r++){
    float ps = acc[r][0]*ws[0] + acc[r][1]*ws[1] + acc[r][2]*ws[2] + acc[r][3]*ws[3];
    float pd = acc[r][0]*wd[0] + acc[r][1]*wd[1] + acc[r][2]*wd[2] + acc[r][3]*wd[3];
    #pragma unroll
    for (int off=8; off; off>>=1){
      ps += __shfl_down(ps, off);
      pd += __shfl_down(pd, off);
    }
    int row = r0 + ty*8 + r;
    if (tx==0 && row < NN){
      a_src4[(size_t)row*4 + head] = ps;
      a_dst4[(size_t)row*4 + head] = pd;
    }
  }
}

// ---------------- GAT aggregation: one WAVE per dst node, no LDS, no barriers -----
// Phase 1: lane j holds edge j's logits for all 3 heads; shfl_xor butterflies for (m,s).
// Phase 2: per-edge broadcast (sn, alpha0..2) via readlane; lanes 0..47 gather bf16x4.
__global__ __launch_bounds__(256) void gat_agg_wave(const u16* __restrict__ hb,
    const float* __restrict__ a_src4, const float* __restrict__ a_dst4,
    const int* __restrict__ row_ptr, const int* __restrict__ col,
    const float* __restrict__ bias, float* __restrict__ out){
  const int t = threadIdx.x;
  const int lane = t & 63;
  const int d = blockIdx.x*4 + (t >> 6);
  if (d >= NN) return;
  const int e0  = row_ptr[d];
  const int deg = row_ptr[d+1] - e0;
  const int ecount = deg + 1;                 // implicit self-loop at j==deg
  const float4 ad = *(const float4*)&a_dst4[(size_t)d*4];

  float m0=-1e30f, m1=-1e30f, m2=-1e30f;
  float s0=0.f, s1=0.f, s2=0.f;
  int   sn_r = d;
  float l0r=-1e30f, l1r=-1e30f, l2r=-1e30f;
  const int lastBase = ((ecount-1) >> 6) << 6;

  // ---- pass A: softmax stats ----
  for (int base=0; base<ecount; base+=64){
    int j = base + lane;
    bool valid = j < ecount;
    int sn = d;
    if (j < deg) sn = col[e0+j];
    float4 as = *(const float4*)&a_src4[(size_t)sn*4];
    float l0 = as.x + ad.x; l0 = (l0>0.f)? l0 : 0.2f*l0;
    float l1 = as.y + ad.y; l1 = (l1>0.f)? l1 : 0.2f*l1;
    float l2 = as.z + ad.z; l2 = (l2>0.f)? l2 : 0.2f*l2;
    if (!valid){ l0=-1e30f; l1=-1e30f; l2=-1e30f; }
    float M0=l0, M1=l1, M2=l2;
    #pragma unroll
    for (int off=32; off; off>>=1){
      M0 = fmaxf(M0, __shfl_xor(M0, off));
      M1 = fmaxf(M1, __shfl_xor(M1, off));
      M2 = fmaxf(M2, __shfl_xor(M2, off));
    }
    float E0 = valid? __expf(l0-M0) : 0.f;
    float E1 = valid? __expf(l1-M1) : 0.f;
    float E2 = valid? __expf(l2-M2) : 0.f;
    float S0=E0, S1=E1, S2=E2;
    #pragma unroll
    for (int off=32; off; off>>=1){
      S0 += __shfl_xor(S0, off);
      S1 += __shfl_xor(S1, off);
      S2 += __shfl_xor(S2, off);
    }
    float n0 = fmaxf(m0,M0); s0 = s0*__expf(m0-n0) + S0*__expf(M0-n0); m0 = n0;
    float n1 = fmaxf(m1,M1); s1 = s1*__expf(m1-n1) + S1*__expf(M1-n1); m1 = n1;
    float n2 = fmaxf(m2,M2); s2 = s2*__expf(m2-n2) + S2*__expf(M2-n2); m2 = n2;
    sn_r = sn; l0r = l0; l1r = l1; l2r = l2;
  }
  const float i0 = 1.f/s0, i1 = 1.f/s1, i2 = 1.f/s2;

  // ---- pass B: gather ----
  const int cg = (lane < 48)? lane : lane - 48;   // column group (lanes 48..63 shadow 0..15)
  const int hg = lane >> 4;                        // 0..2 real, 3 = shadow
  float4 acc = make_float4(0.f,0.f,0.f,0.f);
  for (int base=0; base<ecount; base+=64){
    int j = base + lane;
    bool valid = j < ecount;
    int sn; float l0,l1,l2;
    if (base == lastBase){ sn = sn_r; l0 = l0r; l1 = l1r; l2 = l2r; }
    else {
      sn = d;
      if (j < deg) sn = col[e0+j];
      float4 as = *(const float4*)&a_src4[(size_t)sn*4];
      l0 = as.x + ad.x; l0 = (l0>0.f)? l0 : 0.2f*l0;
      l1 = as.y + ad.y; l1 = (l1>0.f)? l1 : 0.2f*l1;
      l2 = as.z + ad.z; l2 = (l2>0.f)? l2 : 0.2f*l2;
    }
    float e0a = valid? __expf(l0-m0)*i0 : 0.f;
    float e1a = valid? __expf(l1-m1)*i1 : 0.f;
    float e2a = valid? __expf(l2-m2)*i2 : 0.f;
    int cnt = ecount - base; if (cnt > 64) cnt = 64;
    for (int jj=0; jj<cnt; jj++){
      int   snj = __builtin_amdgcn_readlane(sn, jj);
      float a0  = __int_as_float(__builtin_amdgcn_readlane(__float_as_int(e0a), jj));
      float a1  = __int_as_float(__builtin_amdgcn_readlane(__float_as_int(e1a), jj));
      float a2  = __int_as_float(__builtin_amdgcn_readlane(__float_as_int(e2a), jj));
      float al  = (hg==0)? a0 : ((hg==1)? a1 : a2);
      uint2 p = *(const uint2*)(hb + (size_t)snj*F + cg*4);
      acc.x = fmaf(al, __uint_as_float(p.x << 16),        acc.x);
      acc.y = fmaf(al, __uint_as_float(p.x & 0xffff0000u), acc.y);
      acc.z = fmaf(al, __uint_as_float(p.y << 16),        acc.z);
      acc.w = fmaf(al, __uint_as_float(p.y & 0xffff0000u), acc.w);
    }
  }
  if (lane < 48){
    float4 b4 = *(const float4*)&bias[cg*4];
    float4 o;
    o.x = fmaxf(acc.x + b4.x, 0.f);
    o.y = fmaxf(acc.y + b4.y, 0.f);
    o.z = fmaxf(acc.z + b4.z, 0.f);
    o.w = fmaxf(acc.w + b4.w, 0.f);
    *(float4*)&out[(size_t)d*F + cg*4] = o;
  }
}

// ---------------- output GEMM: A[NN x 192](fp32) @ W[192 x 40] + bout ----------
__global__ __launch_bounds__(256) void gemm_out_kernel(const float* __restrict__ A,
    const float* __restrict__ W, const float* __restrict__ bias, float* __restrict__ C){
  __shared__ __align__(16) float As[32*SA];   // [k][m]
  __shared__ float Ws[32*NC];                  // [k][c]
  const int t = threadIdx.x;
  const int tx = t & 7, ty = t >> 3;
  const int r0 = blockIdx.x*128;
  float acc[4][5];
  #pragma unroll
  for (int r=0;r<4;r++)
    #pragma unroll
    for (int c=0;c<5;c++) acc[r][c]=0.f;

  for (int k0=0; k0<F; k0+=32){
    __syncthreads();
    #pragma unroll
    for (int i=0;i<4;i++){
      int idx = t + i*256;
      int row = idx >> 3, kq = idx & 7;
      float4 v = make_float4(0.f,0.f,0.f,0.f);
      if (r0+row < NN) v = *(const float4*)&A[(size_t)(r0+row)*F + k0 + kq*4];
      As[(kq*4+0)*SA + row] = v.x;
      As[(kq*4+1)*SA + row] = v.y;
      As[(kq*4+2)*SA + row] = v.z;
      As[(kq*4+3)*SA + row] = v.w;
    }
    #pragma unroll
    for (int i=0;i<5;i++){
      int idx = t + i*256;
      int k = idx/NC, c = idx%NC;
      Ws[k*NC + c] = W[(size_t)(k0+k)*NC + c];
    }
    __syncthreads();
    #pragma unroll
    for (int k=0;k<32;k++){
      float4 a = *(float4*)&As[k*SA + ty*4];
      float av[4] = {a.x,a.y,a.z,a.w};
      float bv[5];
      #pragma unroll
      for (int c=0;c<5;c++) bv[c] = Ws[k*NC + tx*5 + c];
      #pragma unroll
      for (int r=0;r<4;r++)
        #pragma unroll
        for (int c=0;c<5;c++) acc[r][c] = fmaf(av[r], bv[c], acc[r][c]);
    }
  }
  #pragma unroll
  for (int r=0;r<4;r++){
    int row = r0 + ty*4 + r;
    if (row < NN){
      #pragma unroll
      for (int c=0;c<5;c++) C[(size_t)row*NC + tx*5 + c] = acc[r][c] + bias[tx*5+c];
    }
  }
}

extern "C" void kernel_launch(void* const* d_in, const int* in_sizes, int n_in,
                              void* d_out, int out_size, void* d_ws, size_t ws_size,
                              hipStream_t stream){
  const float* x    = (const float*)d_in[0];
  const int*   ei   = (const int*)  d_in[1];
  const float* W1   = (const float*)d_in[2];
  const float* as1  = (const float*)d_in[3];
  const float* ad1  = (const float*)d_in[4];
  const float* b1   = (const float*)d_in[5];
  const float* W2   = (const float*)d_in[6];
  const float* as2  = (const float*)d_in[7];
  const float* ad2  = (const float*)d_in[8];
  const float* b2   = (const float*)d_in[9];
  const float* Wout = (const float*)d_in[10];
  const float* bout = (const float*)d_in[11];
  float* out = (float*)d_out;

  // workspace carve-out (~82 MB)
  u16* hb1 = (u16*)d_ws;                          // N*F bf16 (h1)
  u16* hb2 = hb1 + (size_t)NN*F;                  // N*F bf16 (h2)
  float* bufB   = (float*)(hb2 + (size_t)NN*F);   // N*F fp32 (agg1 out; reused for agg2 out)
  float* a_src4 = bufB + (size_t)NN*F;            // N*4
  float* a_dst4 = a_src4 + (size_t)NN*4;          // N*4
  int* row_ptr  = (int*)(a_dst4 + (size_t)NN*4);  // N+1
  int* col      = row_ptr + (NN+1);               // E
  int* cnt      = col + NE;                       // N

  const int* srcv = ei;
  const int* dstv = ei + NE;

  // CSR by destination (rebuilt every call)
  hipMemsetAsync(cnt, 0, NN*sizeof(int), stream);
  count_kernel<<<(NE+255)/256, 256, 0, stream>>>(dstv, cnt);
  scan_kernel<<<1, 1024, 0, stream>>>(cnt, row_ptr);
  hipMemsetAsync(cnt, 0, NN*sizeof(int), stream);
  fill_kernel<<<(NE+255)/256, 256, 0, stream>>>(srcv, dstv, row_ptr, cnt, col);

  const dim3 gemm_grid(NH, (NN + 127)/128);   // heads adjacent -> A tile shared in L2
  const int AGG_GRID = (NN + 3)/4;            // one wave per node, 4 waves/block
  // layer 1
  gemm_reg<KIN><<<gemm_grid, 256, 0, stream>>>(x, W1, hb1, as1, ad1, a_src4, a_dst4);
  gat_agg_wave<<<AGG_GRID, 256, 0, stream>>>(hb1, a_src4, a_dst4, row_ptr, col, b1, bufB);
  // layer 2
  gemm_reg<F><<<gemm_grid, 256, 0, stream>>>(bufB, W2, hb2, as2, ad2, a_src4, a_dst4);
  gat_agg_wave<<<AGG_GRID, 256, 0, stream>>>(hb2, a_src4, a_dst4, row_ptr, col, b2, bufB);
  // readout
  gemm_out_kernel<<<(NN + 127)/128, 256, 0, stream>>>(bufB, Wout, bout, out);
}

// Round 5
// 524.942 us; speedup vs baseline: 2.0548x; 1.0924x over previous
//
#include <hip/hip_runtime.h>
#include <math.h>

#define NN 50000
#define NE 800000
#define KIN 256
#define F 192      // HEADS*HID
#define NH 3
#define NC 40

typedef unsigned short u16;
typedef unsigned int   u32;
typedef __attribute__((ext_vector_type(8))) short bf16x8;
typedef __attribute__((ext_vector_type(4))) float f32x4;

static __device__ __forceinline__ u16 f2bf(float f){
  u32 u = __float_as_uint(f);
  u32 r = (u + 0x7fffu + ((u >> 16) & 1u)) >> 16;   // RNE
  return (u16)r;
}
static __device__ __forceinline__ float bf2f(u16 h){
  return __uint_as_float(((u32)h) << 16);
}

// ---------------- CSR build ----------------
__global__ void count_kernel(const int* __restrict__ dst, int* __restrict__ cnt){
  int e = blockIdx.x*256 + threadIdx.x;
  if (e < NE) atomicAdd(&cnt[dst[e]], 1);
}

__global__ __launch_bounds__(1024) void scan_kernel(const int* __restrict__ cnt, int* __restrict__ row_ptr){
  __shared__ int part[1024];
  int t = threadIdx.x;
  const int CHUNK = (NN + 1023)/1024;
  int start = t*CHUNK;
  int end = start+CHUNK; if (end > NN) end = NN; if (start > NN) start = NN;
  int s = 0;
  for (int i=start;i<end;i++) s += cnt[i];
  part[t] = s;
  __syncthreads();
  for (int off=1; off<1024; off<<=1){
    int v = (t>=off)? part[t-off] : 0;
    __syncthreads();
    part[t] += v;
    __syncthreads();
  }
  int run = (t==0)? 0 : part[t-1];
  for (int i=start;i<end;i++){ row_ptr[i] = run; run += cnt[i]; }
  if (t==0) row_ptr[NN] = part[1023];
}

__global__ void fill_kernel(const int* __restrict__ src, const int* __restrict__ dst,
                            const int* __restrict__ row_ptr, int* __restrict__ cur,
                            int* __restrict__ col){
  int e = blockIdx.x*256 + threadIdx.x;
  if (e < NE){
    int d = dst[e];
    int p = row_ptr[d] + atomicAdd(&cur[d], 1);
    col[p] = src[e];
  }
}

// ---------------- fp32 -> bf16 convert (x) ----------------
__global__ void conv_x_kernel(const float* __restrict__ src, u16* __restrict__ dst, int n4){
  int i = blockIdx.x*256 + threadIdx.x;
  if (i < n4){
    float4 v = *(const float4*)&src[(size_t)i*4];
    uint2 p;
    p.x = (u32)f2bf(v.x) | ((u32)f2bf(v.y) << 16);
    p.y = (u32)f2bf(v.z) | ((u32)f2bf(v.w) << 16);
    *(uint2*)&dst[(size_t)i*4] = p;
  }
}

// ---------------- fp32 [R x C] -> bf16 transposed [C x R] ----------------
__global__ void conv_wt_kernel(const float* __restrict__ src, u16* __restrict__ dst, int R, int C){
  int e = blockIdx.x*256 + threadIdx.x;
  if (e < R*C){
    int r = e / C, c = e % C;
    dst[(size_t)c*R + r] = f2bf(src[e]);
  }
}

// ---------------- MFMA GEMM: Ab[NN x K](bf16) @ Bt[192 x K](bf16, pre-transposed)
// -> C[NN x 192](bf16), + fused attention dots (fp32 from accumulators).
// BM=64, BN=192, BK=32. 256 thr = 4 waves; wave w owns 48 cols (3 16-tiles) x 64 rows
// (4 16-tiles). mfma_f32_16x16x32_bf16: A[m=l&15][k=quad*8+j], B[n=l&15][k=quad*8+j],
// C col=l&15 row=quad*4+reg (m89-verified). LDS stride 40 u16 (80 B): b128 starts
// {0,20,8,28,16,4,24,12}*... -> <=2-way bank aliasing (free).
#define SAK 40
template<int K>
__global__ __launch_bounds__(256) void gemm_mfma(const u16* __restrict__ Ab, const u16* __restrict__ Bt,
                                                 u16* __restrict__ C,
                                                 const float* __restrict__ att_src, const float* __restrict__ att_dst,
                                                 float* __restrict__ a_src4, float* __restrict__ a_dst4){
  __shared__ __align__(16) u16 As[64*SAK];
  __shared__ __align__(16) u16 Bs[192*SAK];
  __shared__ float sd_src[64*NH];
  __shared__ float sd_dst[64*NH];
  const int t = threadIdx.x;
  const int wave = t >> 6, lane = t & 63;
  const int quad = lane >> 4, l16 = lane & 15;
  const int r0 = blockIdx.x*64;

  for (int i=t; i<64*NH; i+=256){ sd_src[i]=0.f; sd_dst[i]=0.f; }

  f32x4 acc[4][3];
  #pragma unroll
  for (int rt=0;rt<4;rt++)
    #pragma unroll
    for (int ct=0;ct<3;ct++) acc[rt][ct] = (f32x4){0.f,0.f,0.f,0.f};

  for (int k0=0; k0<K; k0+=32){
    __syncthreads();
    // A tile: 64 rows x 32 k; thread -> 8 bf16 (16 B)
    {
      int row = t >> 2, kq = t & 3;
      uint4 v = make_uint4(0,0,0,0);
      if (r0+row < NN) v = *(const uint4*)&Ab[(size_t)(r0+row)*K + k0 + kq*8];
      *(uint4*)&As[row*SAK + kq*8] = v;
    }
    // B tile: 192 rows x 32 k
    #pragma unroll
    for (int i=0;i<3;i++){
      int idx = t + i*256;            // 0..767
      int n = idx >> 2, kq = idx & 3;
      *(uint4*)&Bs[n*SAK + kq*8] = *(const uint4*)&Bt[(size_t)n*K + k0 + kq*8];
    }
    __syncthreads();
    bf16x8 af[4], bf[3];
    #pragma unroll
    for (int rt=0;rt<4;rt++) af[rt] = *(const bf16x8*)&As[(rt*16 + l16)*SAK + quad*8];
    #pragma unroll
    for (int ct=0;ct<3;ct++) bf[ct] = *(const bf16x8*)&Bs[(wave*48 + ct*16 + l16)*SAK + quad*8];
    #pragma unroll
    for (int rt=0;rt<4;rt++)
      #pragma unroll
      for (int ct=0;ct<3;ct++)
        acc[rt][ct] = __builtin_amdgcn_mfma_f32_16x16x32_bf16(af[rt], bf[ct], acc[rt][ct], 0, 0, 0);
  }

  // epilogue: bf16 C store + attention dots
  #pragma unroll
  for (int ct=0;ct<3;ct++){
    const int nbase = wave*48 + ct*16;
    const int n = nbase + l16;
    const int head = nbase >> 6;
    const float as_n = att_src[n], ad_n = att_dst[n];
    #pragma unroll
    for (int rt=0;rt<4;rt++){
      #pragma unroll
      for (int reg=0;reg<4;reg++){
        const int m = rt*16 + quad*4 + reg;
        const float v = acc[rt][ct][reg];
        const int grow = r0 + m;
        if (grow < NN) C[(size_t)grow*F + n] = f2bf(v);
        float ps = v*as_n, pd = v*ad_n;
        #pragma unroll
        for (int off=1; off<16; off<<=1){
          ps += __shfl_xor(ps, off);
          pd += __shfl_xor(pd, off);
        }
        if (l16 == 0){
          atomicAdd(&sd_src[m*NH + head], ps);
          atomicAdd(&sd_dst[m*NH + head], pd);
        }
      }
    }
  }
  __syncthreads();
  if (t < 64){
    int grow = r0 + t;
    if (grow < NN){
      float4 vs = make_float4(sd_src[t*NH+0], sd_src[t*NH+1], sd_src[t*NH+2], 0.f);
      float4 vd = make_float4(sd_dst[t*NH+0], sd_dst[t*NH+1], sd_dst[t*NH+2], 0.f);
      *(float4*)&a_src4[(size_t)grow*4] = vs;
      *(float4*)&a_dst4[(size_t)grow*4] = vd;
    }
  }
}

// ---------------- GAT aggregation: one WAVE per dst node, no LDS, no barriers -----
// out is bf16 now (feeds the next MFMA GEMM / readout).
__global__ __launch_bounds__(256) void gat_agg_wave(const u16* __restrict__ hb,
    const float* __restrict__ a_src4, const float* __restrict__ a_dst4,
    const int* __restrict__ row_ptr, const int* __restrict__ col,
    const float* __restrict__ bias, u16* __restrict__ out){
  const int t = threadIdx.x;
  const int lane = t & 63;
  const int d = blockIdx.x*4 + (t >> 6);
  if (d >= NN) return;
  const int e0  = row_ptr[d];
  const int deg = row_ptr[d+1] - e0;
  const int ecount = deg + 1;                 // implicit self-loop at j==deg
  const float4 ad = *(const float4*)&a_dst4[(size_t)d*4];

  float m0=-1e30f, m1=-1e30f, m2=-1e30f;
  float s0=0.f, s1=0.f, s2=0.f;
  int   sn_r = d;
  float l0r=-1e30f, l1r=-1e30f, l2r=-1e30f;
  const int lastBase = ((ecount-1) >> 6) << 6;

  // ---- pass A: softmax stats ----
  for (int base=0; base<ecount; base+=64){
    int j = base + lane;
    bool valid = j < ecount;
    int sn = d;
    if (j < deg) sn = col[e0+j];
    float4 as = *(const float4*)&a_src4[(size_t)sn*4];
    float l0 = as.x + ad.x; l0 = (l0>0.f)? l0 : 0.2f*l0;
    float l1 = as.y + ad.y; l1 = (l1>0.f)? l1 : 0.2f*l1;
    float l2 = as.z + ad.z; l2 = (l2>0.f)? l2 : 0.2f*l2;
    if (!valid){ l0=-1e30f; l1=-1e30f; l2=-1e30f; }
    float M0=l0, M1=l1, M2=l2;
    #pragma unroll
    for (int off=32; off; off>>=1){
      M0 = fmaxf(M0, __shfl_xor(M0, off));
      M1 = fmaxf(M1, __shfl_xor(M1, off));
      M2 = fmaxf(M2, __shfl_xor(M2, off));
    }
    float E0 = valid? __expf(l0-M0) : 0.f;
    float E1 = valid? __expf(l1-M1) : 0.f;
    float E2 = valid? __expf(l2-M2) : 0.f;
    float S0=E0, S1=E1, S2=E2;
    #pragma unroll
    for (int off=32; off; off>>=1){
      S0 += __shfl_xor(S0, off);
      S1 += __shfl_xor(S1, off);
      S2 += __shfl_xor(S2, off);
    }
    float n0 = fmaxf(m0,M0); s0 = s0*__expf(m0-n0) + S0*__expf(M0-n0); m0 = n0;
    float n1 = fmaxf(m1,M1); s1 = s1*__expf(m1-n1) + S1*__expf(M1-n1); m1 = n1;
    float n2 = fmaxf(m2,M2); s2 = s2*__expf(m2-n2) + S2*__expf(M2-n2); m2 = n2;
    sn_r = sn; l0r = l0; l1r = l1; l2r = l2;
  }
  const float i0 = 1.f/s0, i1 = 1.f/s1, i2 = 1.f/s2;

  // ---- pass B: gather ----
  const int cg = (lane < 48)? lane : lane - 48;   // column group (lanes 48..63 shadow 0..15)
  const int hg = lane >> 4;                        // 0..2 real, 3 = shadow
  float4 acc = make_float4(0.f,0.f,0.f,0.f);
  for (int base=0; base<ecount; base+=64){
    int j = base + lane;
    bool valid = j < ecount;
    int sn; float l0,l1,l2;
    if (base == lastBase){ sn = sn_r; l0 = l0r; l1 = l1r; l2 = l2r; }
    else {
      sn = d;
      if (j < deg) sn = col[e0+j];
      float4 as = *(const float4*)&a_src4[(size_t)sn*4];
      l0 = as.x + ad.x; l0 = (l0>0.f)? l0 : 0.2f*l0;
      l1 = as.y + ad.y; l1 = (l1>0.f)? l1 : 0.2f*l1;
      l2 = as.z + ad.z; l2 = (l2>0.f)? l2 : 0.2f*l2;
    }
    float e0a = valid? __expf(l0-m0)*i0 : 0.f;
    float e1a = valid? __expf(l1-m1)*i1 : 0.f;
    float e2a = valid? __expf(l2-m2)*i2 : 0.f;
    int cnt = ecount - base; if (cnt > 64) cnt = 64;
    for (int jj=0; jj<cnt; jj++){
      int   snj = __builtin_amdgcn_readlane(sn, jj);
      float a0  = __int_as_float(__builtin_amdgcn_readlane(__float_as_int(e0a), jj));
      float a1  = __int_as_float(__builtin_amdgcn_readlane(__float_as_int(e1a), jj));
      float a2  = __int_as_float(__builtin_amdgcn_readlane(__float_as_int(e2a), jj));
      float al  = (hg==0)? a0 : ((hg==1)? a1 : a2);
      uint2 p = *(const uint2*)(hb + (size_t)snj*F + cg*4);
      acc.x = fmaf(al, __uint_as_float(p.x << 16),        acc.x);
      acc.y = fmaf(al, __uint_as_float(p.x & 0xffff0000u), acc.y);
      acc.z = fmaf(al, __uint_as_float(p.y << 16),        acc.z);
      acc.w = fmaf(al, __uint_as_float(p.y & 0xffff0000u), acc.w);
    }
  }
  if (lane < 48){
    float4 b4 = *(const float4*)&bias[cg*4];
    uint2 o;
    o.x = (u32)f2bf(fmaxf(acc.x + b4.x, 0.f)) | ((u32)f2bf(fmaxf(acc.y + b4.y, 0.f)) << 16);
    o.y = (u32)f2bf(fmaxf(acc.z + b4.z, 0.f)) | ((u32)f2bf(fmaxf(acc.w + b4.w, 0.f)) << 16);
    *(uint2*)&out[(size_t)d*F + cg*4] = o;
  }
}

// ---------------- output GEMM: A[NN x 192](bf16) @ W[192 x 40](fp32) + bout -> fp32 ----
#define SA 132
__global__ __launch_bounds__(256) void gemm_out_kernel(const u16* __restrict__ A,
    const float* __restrict__ W, const float* __restrict__ bias, float* __restrict__ C){
  __shared__ __align__(16) float As[32*SA];   // [k][m]
  __shared__ float Ws[32*NC];                  // [k][c]
  const int t = threadIdx.x;
  const int tx = t & 7, ty = t >> 3;
  const int r0 = blockIdx.x*128;
  float acc[4][5];
  #pragma unroll
  for (int r=0;r<4;r++)
    #pragma unroll
    for (int c=0;c<5;c++) acc[r][c]=0.f;

  for (int k0=0; k0<F; k0+=32){
    __syncthreads();
    #pragma unroll
    for (int i=0;i<4;i++){
      int idx = t + i*256;
      int row = idx >> 3, kq = idx & 7;
      uint2 v = make_uint2(0,0);
      if (r0+row < NN) v = *(const uint2*)&A[(size_t)(r0+row)*F + k0 + kq*4];
      As[(kq*4+0)*SA + row] = __uint_as_float(v.x << 16);
      As[(kq*4+1)*SA + row] = __uint_as_float(v.x & 0xffff0000u);
      As[(kq*4+2)*SA + row] = __uint_as_float(v.y << 16);
      As[(kq*4+3)*SA + row] = __uint_as_float(v.y & 0xffff0000u);
    }
    #pragma unroll
    for (int i=0;i<5;i++){
      int idx = t + i*256;
      int k = idx/NC, c = idx%NC;
      Ws[k*NC + c] = W[(size_t)(k0+k)*NC + c];
    }
    __syncthreads();
    #pragma unroll
    for (int k=0;k<32;k++){
      float4 a = *(float4*)&As[k*SA + ty*4];
      float av[4] = {a.x,a.y,a.z,a.w};
      float bv[5];
      #pragma unroll
      for (int c=0;c<5;c++) bv[c] = Ws[k*NC + tx*5 + c];
      #pragma unroll
      for (int r=0;r<4;r++)
        #pragma unroll
        for (int c=0;c<5;c++) acc[r][c] = fmaf(av[r], bv[c], acc[r][c]);
    }
  }
  #pragma unroll
  for (int r=0;r<4;r++){
    int row = r0 + ty*4 + r;
    if (row < NN){
      #pragma unroll
      for (int c=0;c<5;c++) C[(size_t)row*NC + tx*5 + c] = acc[r][c] + bias[tx*5+c];
    }
  }
}

extern "C" void kernel_launch(void* const* d_in, const int* in_sizes, int n_in,
                              void* d_out, int out_size, void* d_ws, size_t ws_size,
                              hipStream_t stream){
  const float* x    = (const float*)d_in[0];
  const int*   ei   = (const int*)  d_in[1];
  const float* W1   = (const float*)d_in[2];
  const float* as1  = (const float*)d_in[3];
  const float* ad1  = (const float*)d_in[4];
  const float* b1   = (const float*)d_in[5];
  const float* W2   = (const float*)d_in[6];
  const float* as2  = (const float*)d_in[7];
  const float* ad2  = (const float*)d_in[8];
  const float* b2   = (const float*)d_in[9];
  const float* Wout = (const float*)d_in[10];
  const float* bout = (const float*)d_in[11];
  float* out = (float*)d_out;

  // workspace carve-out (~108 MB)
  u16* xb  = (u16*)d_ws;                          // NN*KIN
  u16* w1t = xb  + (size_t)NN*KIN;                // F*KIN   (W1^T bf16: [192][256])
  u16* w2t = w1t + (size_t)F*KIN;                 // F*F     (W2^T bf16: [192][192])
  u16* hb1 = w2t + (size_t)F*F;                   // NN*F
  u16* hb2 = hb1 + (size_t)NN*F;                  // NN*F
  u16* gb1 = hb2 + (size_t)NN*F;                  // NN*F  (relu(agg1+b1), bf16)
  u16* gb2 = gb1 + (size_t)NN*F;                  // NN*F  (relu(agg2+b2), bf16)
  float* a_src4 = (float*)(gb2 + (size_t)NN*F);   // NN*4
  float* a_dst4 = a_src4 + (size_t)NN*4;          // NN*4
  int* row_ptr  = (int*)(a_dst4 + (size_t)NN*4);  // NN+1
  int* col      = row_ptr + (NN+1);               // NE
  int* cnt      = col + NE;                       // NN

  const int* srcv = ei;
  const int* dstv = ei + NE;

  // CSR by destination (rebuilt every call)
  hipMemsetAsync(cnt, 0, NN*sizeof(int), stream);
  count_kernel<<<(NE+255)/256, 256, 0, stream>>>(dstv, cnt);
  scan_kernel<<<1, 1024, 0, stream>>>(cnt, row_ptr);
  hipMemsetAsync(cnt, 0, NN*sizeof(int), stream);
  fill_kernel<<<(NE+255)/256, 256, 0, stream>>>(srcv, dstv, row_ptr, cnt, col);

  // bf16 converts
  conv_x_kernel<<<(NN*KIN/4 + 255)/256, 256, 0, stream>>>(x, xb, NN*KIN/4);
  conv_wt_kernel<<<(KIN*F + 255)/256, 256, 0, stream>>>(W1, w1t, KIN, F);
  conv_wt_kernel<<<(F*F + 255)/256, 256, 0, stream>>>(W2, w2t, F, F);

  const int GEMM_GRID = (NN + 63)/64;
  const int AGG_GRID  = (NN + 3)/4;
  // layer 1
  gemm_mfma<KIN><<<GEMM_GRID, 256, 0, stream>>>(xb, w1t, hb1, as1, ad1, a_src4, a_dst4);
  gat_agg_wave<<<AGG_GRID, 256, 0, stream>>>(hb1, a_src4, a_dst4, row_ptr, col, b1, gb1);
  // layer 2
  gemm_mfma<F><<<GEMM_GRID, 256, 0, stream>>>(gb1, w2t, hb2, as2, ad2, a_src4, a_dst4);
  gat_agg_wave<<<AGG_GRID, 256, 0, stream>>>(hb2, a_src4, a_dst4, row_ptr, col, b2, gb2);
  // readout
  gemm_out_kernel<<<(NN + 127)/128, 256, 0, stream>>>(gb2, Wout, bout, out);
}

// Round 6
// 455.027 us; speedup vs baseline: 2.3705x; 1.1537x over previous
//
#include <hip/hip_runtime.h>
#include <math.h>

#define NN 50000
#define NE 800000
#define KIN 256
#define F 192      // HEADS*HID
#define NH 3
#define NC 40
#define NBLK 49    // ceil(NN/1024) scan blocks

typedef unsigned short u16;
typedef unsigned int   u32;
typedef __attribute__((ext_vector_type(8))) short bf16x8;
typedef __attribute__((ext_vector_type(4))) float f32x4;

static __device__ __forceinline__ u16 f2bf(float f){
  u32 u = __float_as_uint(f);
  u32 r = (u + 0x7fffu + ((u >> 16) & 1u)) >> 16;   // RNE
  return (u16)r;
}

// ---------------- CSR build ----------------
__global__ void count_kernel(const int* __restrict__ dst, int* __restrict__ cnt){
  int e = blockIdx.x*256 + threadIdx.x;
  if (e < NE) atomicAdd(&cnt[dst[e]], 1);
}

// phase 1: per-1024-chunk sums
__global__ __launch_bounds__(256) void partial_kernel(const int* __restrict__ cnt, int* __restrict__ partials){
  __shared__ int red[256];
  const int t = threadIdx.x;
  const int base = blockIdx.x*1024 + t*4;
  int s = 0;
  if (base + 3 < NN){
    int4 v = *(const int4*)&cnt[base];
    s = v.x + v.y + v.z + v.w;
  } else if (base < NN){
    for (int i=base; i<NN; i++) s += cnt[i];
  }
  red[t] = s;
  __syncthreads();
  for (int off=128; off; off>>=1){
    if (t < off) red[t] += red[t+off];
    __syncthreads();
  }
  if (t==0) partials[blockIdx.x] = red[0];
}

// phase 2: one wave scans the 49 partials -> exclusive block offsets + total
__global__ __launch_bounds__(64) void scan_partials(const int* __restrict__ partials,
                                                    int* __restrict__ offsets, int* __restrict__ row_ptr){
  const int lane = threadIdx.x;
  int p = (lane < NBLK)? partials[lane] : 0;
  int inc = p;
  #pragma unroll
  for (int off=1; off<64; off<<=1){
    int v = __shfl_up(inc, off);
    if (lane >= off) inc += v;
  }
  if (lane < NBLK) offsets[lane] = inc - p;       // exclusive
  if (lane == NBLK-1) row_ptr[NN] = inc;          // total
}

// phase 3: per-chunk exclusive scan + block offset -> row_ptr
__global__ __launch_bounds__(256) void emit_kernel(const int* __restrict__ cnt,
                                                   const int* __restrict__ offsets,
                                                   int* __restrict__ row_ptr){
  __shared__ int ts[256];
  const int t = threadIdx.x;
  const int base = blockIdx.x*1024 + t*4;
  int4 v = make_int4(0,0,0,0);
  if (base + 3 < NN) v = *(const int4*)&cnt[base];
  else if (base < NN){
    v.x = cnt[base];
    if (base+1 < NN) v.y = cnt[base+1];
    if (base+2 < NN) v.z = cnt[base+2];
  }
  int tot = v.x + v.y + v.z + v.w;
  ts[t] = tot;
  __syncthreads();
  // Hillis-Steele inclusive scan over 256 thread-sums
  #pragma unroll
  for (int off=1; off<256; off<<=1){
    int val = (t >= off)? ts[t-off] : 0;
    __syncthreads();
    ts[t] += val;
    __syncthreads();
  }
  int off0 = offsets[blockIdx.x] + ts[t] - tot;   // exclusive prefix for this thread
  if (base < NN)     row_ptr[base]   = off0;
  if (base+1 < NN)   row_ptr[base+1] = off0 + v.x;
  if (base+2 < NN)   row_ptr[base+2] = off0 + v.x + v.y;
  if (base+3 < NN)   row_ptr[base+3] = off0 + v.x + v.y + v.z;
}

__global__ void fill_kernel(const int* __restrict__ src, const int* __restrict__ dst,
                            const int* __restrict__ row_ptr, int* __restrict__ cur,
                            int* __restrict__ col){
  int e = blockIdx.x*256 + threadIdx.x;
  if (e < NE){
    int d = dst[e];
    int p = row_ptr[d] + atomicAdd(&cur[d], 1);
    col[p] = src[e];
  }
}

// ---------------- fp32 -> bf16 convert (x) ----------------
__global__ void conv_x_kernel(const float* __restrict__ src, u16* __restrict__ dst, int n4){
  int i = blockIdx.x*256 + threadIdx.x;
  if (i < n4){
    float4 v = *(const float4*)&src[(size_t)i*4];
    uint2 p;
    p.x = (u32)f2bf(v.x) | ((u32)f2bf(v.y) << 16);
    p.y = (u32)f2bf(v.z) | ((u32)f2bf(v.w) << 16);
    *(uint2*)&dst[(size_t)i*4] = p;
  }
}

// ---------------- fp32 [R x C] -> bf16 transposed [C x R] ----------------
__global__ void conv_wt_kernel(const float* __restrict__ src, u16* __restrict__ dst, int R, int C){
  int e = blockIdx.x*256 + threadIdx.x;
  if (e < R*C){
    int r = e / C, c = e % C;
    dst[(size_t)c*R + r] = f2bf(src[e]);
  }
}

// ---------------- MFMA GEMM: Ab[NN x K](bf16) @ Bt[192 x K](bf16, pre-transposed)
// -> C[NN x 192](bf16), + fused attention dots (fp32 from accumulators).
#define SAK 40
template<int K>
__global__ __launch_bounds__(256) void gemm_mfma(const u16* __restrict__ Ab, const u16* __restrict__ Bt,
                                                 u16* __restrict__ C,
                                                 const float* __restrict__ att_src, const float* __restrict__ att_dst,
                                                 float* __restrict__ a_src4, float* __restrict__ a_dst4){
  __shared__ __align__(16) u16 As[64*SAK];
  __shared__ __align__(16) u16 Bs[192*SAK];
  __shared__ float sd_src[64*NH];
  __shared__ float sd_dst[64*NH];
  const int t = threadIdx.x;
  const int wave = t >> 6, lane = t & 63;
  const int quad = lane >> 4, l16 = lane & 15;
  const int r0 = blockIdx.x*64;

  for (int i=t; i<64*NH; i+=256){ sd_src[i]=0.f; sd_dst[i]=0.f; }

  f32x4 acc[4][3];
  #pragma unroll
  for (int rt=0;rt<4;rt++)
    #pragma unroll
    for (int ct=0;ct<3;ct++) acc[rt][ct] = (f32x4){0.f,0.f,0.f,0.f};

  for (int k0=0; k0<K; k0+=32){
    __syncthreads();
    {
      int row = t >> 2, kq = t & 3;
      uint4 v = make_uint4(0,0,0,0);
      if (r0+row < NN) v = *(const uint4*)&Ab[(size_t)(r0+row)*K + k0 + kq*8];
      *(uint4*)&As[row*SAK + kq*8] = v;
    }
    #pragma unroll
    for (int i=0;i<3;i++){
      int idx = t + i*256;            // 0..767
      int n = idx >> 2, kq = idx & 3;
      *(uint4*)&Bs[n*SAK + kq*8] = *(const uint4*)&Bt[(size_t)n*K + k0 + kq*8];
    }
    __syncthreads();
    bf16x8 af[4], bf[3];
    #pragma unroll
    for (int rt=0;rt<4;rt++) af[rt] = *(const bf16x8*)&As[(rt*16 + l16)*SAK + quad*8];
    #pragma unroll
    for (int ct=0;ct<3;ct++) bf[ct] = *(const bf16x8*)&Bs[(wave*48 + ct*16 + l16)*SAK + quad*8];
    #pragma unroll
    for (int rt=0;rt<4;rt++)
      #pragma unroll
      for (int ct=0;ct<3;ct++)
        acc[rt][ct] = __builtin_amdgcn_mfma_f32_16x16x32_bf16(af[rt], bf[ct], acc[rt][ct], 0, 0, 0);
  }

  // epilogue: bf16 C store + attention dots
  #pragma unroll
  for (int ct=0;ct<3;ct++){
    const int nbase = wave*48 + ct*16;
    const int n = nbase + l16;
    const int head = nbase >> 6;
    const float as_n = att_src[n], ad_n = att_dst[n];
    #pragma unroll
    for (int rt=0;rt<4;rt++){
      #pragma unroll
      for (int reg=0;reg<4;reg++){
        const int m = rt*16 + quad*4 + reg;
        const float v = acc[rt][ct][reg];
        const int grow = r0 + m;
        if (grow < NN) C[(size_t)grow*F + n] = f2bf(v);
        float ps = v*as_n, pd = v*ad_n;
        #pragma unroll
        for (int off=1; off<16; off<<=1){
          ps += __shfl_xor(ps, off);
          pd += __shfl_xor(pd, off);
        }
        if (l16 == 0){
          atomicAdd(&sd_src[m*NH + head], ps);
          atomicAdd(&sd_dst[m*NH + head], pd);
        }
      }
    }
  }
  __syncthreads();
  if (t < 64){
    int grow = r0 + t;
    if (grow < NN){
      float4 vs = make_float4(sd_src[t*NH+0], sd_src[t*NH+1], sd_src[t*NH+2], 0.f);
      float4 vd = make_float4(sd_dst[t*NH+0], sd_dst[t*NH+1], sd_dst[t*NH+2], 0.f);
      *(float4*)&a_src4[(size_t)grow*4] = vs;
      *(float4*)&a_dst4[(size_t)grow*4] = vd;
    }
  }
}

// ---------------- GAT aggregation: one WAVE per dst node, no LDS, no barriers -----
__global__ __launch_bounds__(256) void gat_agg_wave(const u16* __restrict__ hb,
    const float* __restrict__ a_src4, const float* __restrict__ a_dst4,
    const int* __restrict__ row_ptr, const int* __restrict__ col,
    const float* __restrict__ bias, u16* __restrict__ out){
  const int t = threadIdx.x;
  const int lane = t & 63;
  const int d = blockIdx.x*4 + (t >> 6);
  if (d >= NN) return;
  const int e0  = row_ptr[d];
  const int deg = row_ptr[d+1] - e0;
  const int ecount = deg + 1;                 // implicit self-loop at j==deg
  const float4 ad = *(const float4*)&a_dst4[(size_t)d*4];

  float m0=-1e30f, m1=-1e30f, m2=-1e30f;
  float s0=0.f, s1=0.f, s2=0.f;
  int   sn_r = d;
  float l0r=-1e30f, l1r=-1e30f, l2r=-1e30f;
  const int lastBase = ((ecount-1) >> 6) << 6;

  // ---- pass A: softmax stats ----
  for (int base=0; base<ecount; base+=64){
    int j = base + lane;
    bool valid = j < ecount;
    int sn = d;
    if (j < deg) sn = col[e0+j];
    float4 as = *(const float4*)&a_src4[(size_t)sn*4];
    float l0 = as.x + ad.x; l0 = (l0>0.f)? l0 : 0.2f*l0;
    float l1 = as.y + ad.y; l1 = (l1>0.f)? l1 : 0.2f*l1;
    float l2 = as.z + ad.z; l2 = (l2>0.f)? l2 : 0.2f*l2;
    if (!valid){ l0=-1e30f; l1=-1e30f; l2=-1e30f; }
    float M0=l0, M1=l1, M2=l2;
    #pragma unroll
    for (int off=32; off; off>>=1){
      M0 = fmaxf(M0, __shfl_xor(M0, off));
      M1 = fmaxf(M1, __shfl_xor(M1, off));
      M2 = fmaxf(M2, __shfl_xor(M2, off));
    }
    float E0 = valid? __expf(l0-M0) : 0.f;
    float E1 = valid? __expf(l1-M1) : 0.f;
    float E2 = valid? __expf(l2-M2) : 0.f;
    float S0=E0, S1=E1, S2=E2;
    #pragma unroll
    for (int off=32; off; off>>=1){
      S0 += __shfl_xor(S0, off);
      S1 += __shfl_xor(S1, off);
      S2 += __shfl_xor(S2, off);
    }
    float n0 = fmaxf(m0,M0); s0 = s0*__expf(m0-n0) + S0*__expf(M0-n0); m0 = n0;
    float n1 = fmaxf(m1,M1); s1 = s1*__expf(m1-n1) + S1*__expf(M1-n1); m1 = n1;
    float n2 = fmaxf(m2,M2); s2 = s2*__expf(m2-n2) + S2*__expf(M2-n2); m2 = n2;
    sn_r = sn; l0r = l0; l1r = l1; l2r = l2;
  }
  const float i0 = 1.f/s0, i1 = 1.f/s1, i2 = 1.f/s2;

  // ---- pass B: gather ----
  const int cg = (lane < 48)? lane : lane - 48;   // column group (lanes 48..63 shadow 0..15)
  const int hg = lane >> 4;                        // 0..2 real, 3 = shadow
  float4 acc = make_float4(0.f,0.f,0.f,0.f);
  for (int base=0; base<ecount; base+=64){
    int j = base + lane;
    bool valid = j < ecount;
    int sn; float l0,l1,l2;
    if (base == lastBase){ sn = sn_r; l0 = l0r; l1 = l1r; l2 = l2r; }
    else {
      sn = d;
      if (j < deg) sn = col[e0+j];
      float4 as = *(const float4*)&a_src4[(size_t)sn*4];
      l0 = as.x + ad.x; l0 = (l0>0.f)? l0 : 0.2f*l0;
      l1 = as.y + ad.y; l1 = (l1>0.f)? l1 : 0.2f*l1;
      l2 = as.z + ad.z; l2 = (l2>0.f)? l2 : 0.2f*l2;
    }
    float e0a = valid? __expf(l0-m0)*i0 : 0.f;
    float e1a = valid? __expf(l1-m1)*i1 : 0.f;
    float e2a = valid? __expf(l2-m2)*i2 : 0.f;
    int cnt = ecount - base; if (cnt > 64) cnt = 64;
    for (int jj=0; jj<cnt; jj++){
      int   snj = __builtin_amdgcn_readlane(sn, jj);
      float a0  = __int_as_float(__builtin_amdgcn_readlane(__float_as_int(e0a), jj));
      float a1  = __int_as_float(__builtin_amdgcn_readlane(__float_as_int(e1a), jj));
      float a2  = __int_as_float(__builtin_amdgcn_readlane(__float_as_int(e2a), jj));
      float al  = (hg==0)? a0 : ((hg==1)? a1 : a2);
      uint2 p = *(const uint2*)(hb + (size_t)snj*F + cg*4);
      acc.x = fmaf(al, __uint_as_float(p.x << 16),        acc.x);
      acc.y = fmaf(al, __uint_as_float(p.x & 0xffff0000u), acc.y);
      acc.z = fmaf(al, __uint_as_float(p.y << 16),        acc.z);
      acc.w = fmaf(al, __uint_as_float(p.y & 0xffff0000u), acc.w);
    }
  }
  if (lane < 48){
    float4 b4 = *(const float4*)&bias[cg*4];
    uint2 o;
    o.x = (u32)f2bf(fmaxf(acc.x + b4.x, 0.f)) | ((u32)f2bf(fmaxf(acc.y + b4.y, 0.f)) << 16);
    o.y = (u32)f2bf(fmaxf(acc.z + b4.z, 0.f)) | ((u32)f2bf(fmaxf(acc.w + b4.w, 0.f)) << 16);
    *(uint2*)&out[(size_t)d*F + cg*4] = o;
  }
}

// ---------------- output GEMM: A[NN x 192](bf16) @ W[192 x 40](fp32) + bout -> fp32 ----
#define SA 132
__global__ __launch_bounds__(256) void gemm_out_kernel(const u16* __restrict__ A,
    const float* __restrict__ W, const float* __restrict__ bias, float* __restrict__ C){
  __shared__ __align__(16) float As[32*SA];   // [k][m]
  __shared__ float Ws[32*NC];                  // [k][c]
  const int t = threadIdx.x;
  const int tx = t & 7, ty = t >> 3;
  const int r0 = blockIdx.x*128;
  float acc[4][5];
  #pragma unroll
  for (int r=0;r<4;r++)
    #pragma unroll
    for (int c=0;c<5;c++) acc[r][c]=0.f;

  for (int k0=0; k0<F; k0+=32){
    __syncthreads();
    #pragma unroll
    for (int i=0;i<4;i++){
      int idx = t + i*256;
      int row = idx >> 3, kq = idx & 7;
      uint2 v = make_uint2(0,0);
      if (r0+row < NN) v = *(const uint2*)&A[(size_t)(r0+row)*F + k0 + kq*4];
      As[(kq*4+0)*SA + row] = __uint_as_float(v.x << 16);
      As[(kq*4+1)*SA + row] = __uint_as_float(v.x & 0xffff0000u);
      As[(kq*4+2)*SA + row] = __uint_as_float(v.y << 16);
      As[(kq*4+3)*SA + row] = __uint_as_float(v.y & 0xffff0000u);
    }
    #pragma unroll
    for (int i=0;i<5;i++){
      int idx = t + i*256;
      int k = idx/NC, c = idx%NC;
      Ws[k*NC + c] = W[(size_t)(k0+k)*NC + c];
    }
    __syncthreads();
    #pragma unroll
    for (int k=0;k<32;k++){
      float4 a = *(float4*)&As[k*SA + ty*4];
      float av[4] = {a.x,a.y,a.z,a.w};
      float bv[5];
      #pragma unroll
      for (int c=0;c<5;c++) bv[c] = Ws[k*NC + tx*5 + c];
      #pragma unroll
      for (int r=0;r<4;r++)
        #pragma unroll
        for (int c=0;c<5;c++) acc[r][c] = fmaf(av[r], bv[c], acc[r][c]);
    }
  }
  #pragma unroll
  for (int r=0;r<4;r++){
    int row = r0 + ty*4 + r;
    if (row < NN){
      #pragma unroll
      for (int c=0;c<5;c++) C[(size_t)row*NC + tx*5 + c] = acc[r][c] + bias[tx*5+c];
    }
  }
}

extern "C" void kernel_launch(void* const* d_in, const int* in_sizes, int n_in,
                              void* d_out, int out_size, void* d_ws, size_t ws_size,
                              hipStream_t stream){
  const float* x    = (const float*)d_in[0];
  const int*   ei   = (const int*)  d_in[1];
  const float* W1   = (const float*)d_in[2];
  const float* as1  = (const float*)d_in[3];
  const float* ad1  = (const float*)d_in[4];
  const float* b1   = (const float*)d_in[5];
  const float* W2   = (const float*)d_in[6];
  const float* as2  = (const float*)d_in[7];
  const float* ad2  = (const float*)d_in[8];
  const float* b2   = (const float*)d_in[9];
  const float* Wout = (const float*)d_in[10];
  const float* bout = (const float*)d_in[11];
  float* out = (float*)d_out;

  // workspace carve-out (~108 MB)
  u16* xb  = (u16*)d_ws;                          // NN*KIN
  u16* w1t = xb  + (size_t)NN*KIN;                // F*KIN
  u16* w2t = w1t + (size_t)F*KIN;                 // F*F
  u16* hb1 = w2t + (size_t)F*F;                   // NN*F
  u16* hb2 = hb1 + (size_t)NN*F;                  // NN*F
  u16* gb1 = hb2 + (size_t)NN*F;                  // NN*F
  u16* gb2 = gb1 + (size_t)NN*F;                  // NN*F
  float* a_src4 = (float*)(gb2 + (size_t)NN*F);   // NN*4
  float* a_dst4 = a_src4 + (size_t)NN*4;          // NN*4
  int* row_ptr  = (int*)(a_dst4 + (size_t)NN*4);  // NN+1
  int* col      = row_ptr + (NN+1);               // NE
  int* cnt      = col + NE;                       // NN
  int* partials = cnt + NN;                       // NBLK
  int* offsets  = partials + NBLK;                // NBLK

  const int* srcv = ei;
  const int* dstv = ei + NE;

  // CSR by destination (rebuilt every call); multi-block scan
  hipMemsetAsync(cnt, 0, NN*sizeof(int), stream);
  count_kernel<<<(NE+255)/256, 256, 0, stream>>>(dstv, cnt);
  partial_kernel<<<NBLK, 256, 0, stream>>>(cnt, partials);
  scan_partials<<<1, 64, 0, stream>>>(partials, offsets, row_ptr);
  emit_kernel<<<NBLK, 256, 0, stream>>>(cnt, offsets, row_ptr);
  hipMemsetAsync(cnt, 0, NN*sizeof(int), stream);
  fill_kernel<<<(NE+255)/256, 256, 0, stream>>>(srcv, dstv, row_ptr, cnt, col);

  // bf16 converts
  conv_x_kernel<<<(NN*KIN/4 + 255)/256, 256, 0, stream>>>(x, xb, NN*KIN/4);
  conv_wt_kernel<<<(KIN*F + 255)/256, 256, 0, stream>>>(W1, w1t, KIN, F);
  conv_wt_kernel<<<(F*F + 255)/256, 256, 0, stream>>>(W2, w2t, F, F);

  const int GEMM_GRID = (NN + 63)/64;
  const int AGG_GRID  = (NN + 3)/4;
  // layer 1
  gemm_mfma<KIN><<<GEMM_GRID, 256, 0, stream>>>(xb, w1t, hb1, as1, ad1, a_src4, a_dst4);
  gat_agg_wave<<<AGG_GRID, 256, 0, stream>>>(hb1, a_src4, a_dst4, row_ptr, col, b1, gb1);
  // layer 2
  gemm_mfma<F><<<GEMM_GRID, 256, 0, stream>>>(gb1, w2t, hb2, as2, ad2, a_src4, a_dst4);
  gat_agg_wave<<<AGG_GRID, 256, 0, stream>>>(hb2, a_src4, a_dst4, row_ptr, col, b2, gb2);
  // readout
  gemm_out_kernel<<<(NN + 127)/128, 256, 0, stream>>>(gb2, Wout, bout, out);
}

// Round 7
// 414.190 us; speedup vs baseline: 2.6042x; 1.0986x over previous
//
#include <hip/hip_runtime.h>
#include <math.h>

#define NN 50000
#define NE 800000
#define KIN 256
#define F 192      // HEADS*HID
#define NH 3
#define NC 40
#define NBLK 49    // ceil(NN/1024) scan blocks

typedef unsigned short u16;
typedef unsigned int   u32;
typedef __attribute__((ext_vector_type(8))) short bf16x8;
typedef __attribute__((ext_vector_type(4))) float f32x4;

static __device__ __forceinline__ u16 f2bf(float f){
  u32 u = __float_as_uint(f);
  u32 r = (u + 0x7fffu + ((u >> 16) & 1u)) >> 16;   // RNE
  return (u16)r;
}

// ---------------- CSR build ----------------
__global__ void count_kernel(const int* __restrict__ dst, int* __restrict__ cnt){
  int e = blockIdx.x*256 + threadIdx.x;
  if (e < NE) atomicAdd(&cnt[dst[e]], 1);
}

__global__ __launch_bounds__(256) void partial_kernel(const int* __restrict__ cnt, int* __restrict__ partials){
  __shared__ int red[256];
  const int t = threadIdx.x;
  const int base = blockIdx.x*1024 + t*4;
  int s = 0;
  if (base + 3 < NN){
    int4 v = *(const int4*)&cnt[base];
    s = v.x + v.y + v.z + v.w;
  } else if (base < NN){
    for (int i=base; i<NN; i++) s += cnt[i];
  }
  red[t] = s;
  __syncthreads();
  for (int off=128; off; off>>=1){
    if (t < off) red[t] += red[t+off];
    __syncthreads();
  }
  if (t==0) partials[blockIdx.x] = red[0];
}

__global__ __launch_bounds__(64) void scan_partials(const int* __restrict__ partials,
                                                    int* __restrict__ offsets, int* __restrict__ row_ptr){
  const int lane = threadIdx.x;
  int p = (lane < NBLK)? partials[lane] : 0;
  int inc = p;
  #pragma unroll
  for (int off=1; off<64; off<<=1){
    int v = __shfl_up(inc, off);
    if (lane >= off) inc += v;
  }
  if (lane < NBLK) offsets[lane] = inc - p;
  if (lane == NBLK-1) row_ptr[NN] = inc;
}

__global__ __launch_bounds__(256) void emit_kernel(const int* __restrict__ cnt,
                                                   const int* __restrict__ offsets,
                                                   int* __restrict__ row_ptr){
  __shared__ int ts[256];
  const int t = threadIdx.x;
  const int base = blockIdx.x*1024 + t*4;
  int4 v = make_int4(0,0,0,0);
  if (base + 3 < NN) v = *(const int4*)&cnt[base];
  else if (base < NN){
    v.x = cnt[base];
    if (base+1 < NN) v.y = cnt[base+1];
    if (base+2 < NN) v.z = cnt[base+2];
  }
  int tot = v.x + v.y + v.z + v.w;
  ts[t] = tot;
  __syncthreads();
  #pragma unroll
  for (int off=1; off<256; off<<=1){
    int val = (t >= off)? ts[t-off] : 0;
    __syncthreads();
    ts[t] += val;
    __syncthreads();
  }
  int off0 = offsets[blockIdx.x] + ts[t] - tot;
  if (base < NN)     row_ptr[base]   = off0;
  if (base+1 < NN)   row_ptr[base+1] = off0 + v.x;
  if (base+2 < NN)   row_ptr[base+2] = off0 + v.x + v.y;
  if (base+3 < NN)   row_ptr[base+3] = off0 + v.x + v.y + v.z;
}

__global__ void fill_kernel(const int* __restrict__ src, const int* __restrict__ dst,
                            const int* __restrict__ row_ptr, int* __restrict__ cur,
                            int* __restrict__ col){
  int e = blockIdx.x*256 + threadIdx.x;
  if (e < NE){
    int d = dst[e];
    int p = row_ptr[d] + atomicAdd(&cur[d], 1);
    col[p] = src[e];
  }
}

// ---------------- fp32 -> bf16 convert (x) ----------------
__global__ void conv_x_kernel(const float* __restrict__ src, u16* __restrict__ dst, int n4){
  int i = blockIdx.x*256 + threadIdx.x;
  if (i < n4){
    float4 v = *(const float4*)&src[(size_t)i*4];
    uint2 p;
    p.x = (u32)f2bf(v.x) | ((u32)f2bf(v.y) << 16);
    p.y = (u32)f2bf(v.z) | ((u32)f2bf(v.w) << 16);
    *(uint2*)&dst[(size_t)i*4] = p;
  }
}

__global__ void conv_wt_kernel(const float* __restrict__ src, u16* __restrict__ dst, int R, int C){
  int e = blockIdx.x*256 + threadIdx.x;
  if (e < R*C){
    int r = e / C, c = e % C;
    dst[(size_t)c*R + r] = f2bf(src[e]);
  }
}

// ---------------- MFMA GEMM (unchanged from R6) ----------------
#define SAK 40
template<int K>
__global__ __launch_bounds__(256) void gemm_mfma(const u16* __restrict__ Ab, const u16* __restrict__ Bt,
                                                 u16* __restrict__ C,
                                                 const float* __restrict__ att_src, const float* __restrict__ att_dst,
                                                 float* __restrict__ a_src4, float* __restrict__ a_dst4){
  __shared__ __align__(16) u16 As[64*SAK];
  __shared__ __align__(16) u16 Bs[192*SAK];
  __shared__ float sd_src[64*NH];
  __shared__ float sd_dst[64*NH];
  const int t = threadIdx.x;
  const int wave = t >> 6, lane = t & 63;
  const int quad = lane >> 4, l16 = lane & 15;
  const int r0 = blockIdx.x*64;

  for (int i=t; i<64*NH; i+=256){ sd_src[i]=0.f; sd_dst[i]=0.f; }

  f32x4 acc[4][3];
  #pragma unroll
  for (int rt=0;rt<4;rt++)
    #pragma unroll
    for (int ct=0;ct<3;ct++) acc[rt][ct] = (f32x4){0.f,0.f,0.f,0.f};

  for (int k0=0; k0<K; k0+=32){
    __syncthreads();
    {
      int row = t >> 2, kq = t & 3;
      uint4 v = make_uint4(0,0,0,0);
      if (r0+row < NN) v = *(const uint4*)&Ab[(size_t)(r0+row)*K + k0 + kq*8];
      *(uint4*)&As[row*SAK + kq*8] = v;
    }
    #pragma unroll
    for (int i=0;i<3;i++){
      int idx = t + i*256;
      int n = idx >> 2, kq = idx & 3;
      *(uint4*)&Bs[n*SAK + kq*8] = *(const uint4*)&Bt[(size_t)n*K + k0 + kq*8];
    }
    __syncthreads();
    bf16x8 af[4], bf[3];
    #pragma unroll
    for (int rt=0;rt<4;rt++) af[rt] = *(const bf16x8*)&As[(rt*16 + l16)*SAK + quad*8];
    #pragma unroll
    for (int ct=0;ct<3;ct++) bf[ct] = *(const bf16x8*)&Bs[(wave*48 + ct*16 + l16)*SAK + quad*8];
    #pragma unroll
    for (int rt=0;rt<4;rt++)
      #pragma unroll
      for (int ct=0;ct<3;ct++)
        acc[rt][ct] = __builtin_amdgcn_mfma_f32_16x16x32_bf16(af[rt], bf[ct], acc[rt][ct], 0, 0, 0);
  }

  #pragma unroll
  for (int ct=0;ct<3;ct++){
    const int nbase = wave*48 + ct*16;
    const int n = nbase + l16;
    const int head = nbase >> 6;
    const float as_n = att_src[n], ad_n = att_dst[n];
    #pragma unroll
    for (int rt=0;rt<4;rt++){
      #pragma unroll
      for (int reg=0;reg<4;reg++){
        const int m = rt*16 + quad*4 + reg;
        const float v = acc[rt][ct][reg];
        const int grow = r0 + m;
        if (grow < NN) C[(size_t)grow*F + n] = f2bf(v);
        float ps = v*as_n, pd = v*ad_n;
        #pragma unroll
        for (int off=1; off<16; off<<=1){
          ps += __shfl_xor(ps, off);
          pd += __shfl_xor(pd, off);
        }
        if (l16 == 0){
          atomicAdd(&sd_src[m*NH + head], ps);
          atomicAdd(&sd_dst[m*NH + head], pd);
        }
      }
    }
  }
  __syncthreads();
  if (t < 64){
    int grow = r0 + t;
    if (grow < NN){
      float4 vs = make_float4(sd_src[t*NH+0], sd_src[t*NH+1], sd_src[t*NH+2], 0.f);
      float4 vd = make_float4(sd_dst[t*NH+0], sd_dst[t*NH+1], sd_dst[t*NH+2], 0.f);
      *(float4*)&a_src4[(size_t)grow*4] = vs;
      *(float4*)&a_dst4[(size_t)grow*4] = vd;
    }
  }
}

// ---------------- GAT aggregation: one WAVE per dst node -----------------
// Pass B: alphas staged per-chunk in wave-private LDS (ds_write_b128, broadcast
// ds_read_b32), scalar row bases via one readlane, gather unrolled 4x.
__global__ __launch_bounds__(256) void gat_agg_wave(const u16* __restrict__ hb,
    const float* __restrict__ a_src4, const float* __restrict__ a_dst4,
    const int* __restrict__ row_ptr, const int* __restrict__ col,
    const float* __restrict__ bias, u16* __restrict__ out){
  __shared__ float s_al[4][64][4];   // [wave][edge-in-chunk][head(+pad)]
  const int t = threadIdx.x;
  const int lane = t & 63;
  const int w = t >> 6;
  const int d = blockIdx.x*4 + w;
  if (d >= NN) return;
  const int e0  = row_ptr[d];
  const int deg = row_ptr[d+1] - e0;
  const int ecount = deg + 1;                 // implicit self-loop at j==deg
  const float4 ad = *(const float4*)&a_dst4[(size_t)d*4];

  float m0=-1e30f, m1=-1e30f, m2=-1e30f;
  float s0=0.f, s1=0.f, s2=0.f;
  int   sn_r = d;
  float l0r=-1e30f, l1r=-1e30f, l2r=-1e30f;
  const int lastBase = ((ecount-1) >> 6) << 6;

  // ---- pass A: softmax stats ----
  for (int base=0; base<ecount; base+=64){
    int j = base + lane;
    bool valid = j < ecount;
    int sn = d;
    if (j < deg) sn = col[e0+j];
    float4 as = *(const float4*)&a_src4[(size_t)sn*4];
    float l0 = as.x + ad.x; l0 = (l0>0.f)? l0 : 0.2f*l0;
    float l1 = as.y + ad.y; l1 = (l1>0.f)? l1 : 0.2f*l1;
    float l2 = as.z + ad.z; l2 = (l2>0.f)? l2 : 0.2f*l2;
    if (!valid){ l0=-1e30f; l1=-1e30f; l2=-1e30f; }
    float M0=l0, M1=l1, M2=l2;
    #pragma unroll
    for (int off=32; off; off>>=1){
      M0 = fmaxf(M0, __shfl_xor(M0, off));
      M1 = fmaxf(M1, __shfl_xor(M1, off));
      M2 = fmaxf(M2, __shfl_xor(M2, off));
    }
    float E0 = valid? __expf(l0-M0) : 0.f;
    float E1 = valid? __expf(l1-M1) : 0.f;
    float E2 = valid? __expf(l2-M2) : 0.f;
    float S0=E0, S1=E1, S2=E2;
    #pragma unroll
    for (int off=32; off; off>>=1){
      S0 += __shfl_xor(S0, off);
      S1 += __shfl_xor(S1, off);
      S2 += __shfl_xor(S2, off);
    }
    float n0 = fmaxf(m0,M0); s0 = s0*__expf(m0-n0) + S0*__expf(M0-n0); m0 = n0;
    float n1 = fmaxf(m1,M1); s1 = s1*__expf(m1-n1) + S1*__expf(M1-n1); m1 = n1;
    float n2 = fmaxf(m2,M2); s2 = s2*__expf(m2-n2) + S2*__expf(M2-n2); m2 = n2;
    sn_r = sn; l0r = l0; l1r = l1; l2r = l2;
  }
  const float i0 = 1.f/s0, i1 = 1.f/s1, i2 = 1.f/s2;

  // ---- pass B: gather ----
  const int cg = (lane < 48)? lane : lane - 48;   // column group
  const int hg = (lane < 48)? (lane >> 4) : (lane >> 4) - 3; // head (shadow lanes -> head 0)
  const int cgo = cg*4;                            // u16 offset within row
  float4 acc = make_float4(0.f,0.f,0.f,0.f);
  for (int base=0; base<ecount; base+=64){
    int j = base + lane;
    bool valid = j < ecount;
    int sn; float l0,l1,l2;
    if (base == lastBase){ sn = sn_r; l0 = l0r; l1 = l1r; l2 = l2r; }
    else {
      sn = d;
      if (j < deg) sn = col[e0+j];
      float4 as = *(const float4*)&a_src4[(size_t)sn*4];
      l0 = as.x + ad.x; l0 = (l0>0.f)? l0 : 0.2f*l0;
      l1 = as.y + ad.y; l1 = (l1>0.f)? l1 : 0.2f*l1;
      l2 = as.z + ad.z; l2 = (l2>0.f)? l2 : 0.2f*l2;
    }
    float4 st;
    st.x = valid? __expf(l0-m0)*i0 : 0.f;
    st.y = valid? __expf(l1-m1)*i1 : 0.f;
    st.z = valid? __expf(l2-m2)*i2 : 0.f;
    st.w = 0.f;
    *(float4*)&s_al[w][lane][0] = st;              // coalesced ds_write_b128
    __builtin_amdgcn_wave_barrier();               // keep compiler from sinking reads above
    int cnt = ecount - base; if (cnt > 64) cnt = 64;
    int jj = 0;
    for (; jj+4 <= cnt; jj += 4){
      int sA = __builtin_amdgcn_readlane(sn, jj);
      int sB = __builtin_amdgcn_readlane(sn, jj+1);
      int sC = __builtin_amdgcn_readlane(sn, jj+2);
      int sD = __builtin_amdgcn_readlane(sn, jj+3);
      uint2 pA = *(const uint2*)(hb + sA*F + cgo);
      uint2 pB = *(const uint2*)(hb + sB*F + cgo);
      uint2 pC = *(const uint2*)(hb + sC*F + cgo);
      uint2 pD = *(const uint2*)(hb + sD*F + cgo);
      float aA = s_al[w][jj  ][hg];
      float aB = s_al[w][jj+1][hg];
      float aC = s_al[w][jj+2][hg];
      float aD = s_al[w][jj+3][hg];
      acc.x = fmaf(aA, __uint_as_float(pA.x << 16),         acc.x);
      acc.y = fmaf(aA, __uint_as_float(pA.x & 0xffff0000u), acc.y);
      acc.z = fmaf(aA, __uint_as_float(pA.y << 16),         acc.z);
      acc.w = fmaf(aA, __uint_as_float(pA.y & 0xffff0000u), acc.w);
      acc.x = fmaf(aB, __uint_as_float(pB.x << 16),         acc.x);
      acc.y = fmaf(aB, __uint_as_float(pB.x & 0xffff0000u), acc.y);
      acc.z = fmaf(aB, __uint_as_float(pB.y << 16),         acc.z);
      acc.w = fmaf(aB, __uint_as_float(pB.y & 0xffff0000u), acc.w);
      acc.x = fmaf(aC, __uint_as_float(pC.x << 16),         acc.x);
      acc.y = fmaf(aC, __uint_as_float(pC.x & 0xffff0000u), acc.y);
      acc.z = fmaf(aC, __uint_as_float(pC.y << 16),         acc.z);
      acc.w = fmaf(aC, __uint_as_float(pC.y & 0xffff0000u), acc.w);
      acc.x = fmaf(aD, __uint_as_float(pD.x << 16),         acc.x);
      acc.y = fmaf(aD, __uint_as_float(pD.x & 0xffff0000u), acc.y);
      acc.z = fmaf(aD, __uint_as_float(pD.y << 16),         acc.z);
      acc.w = fmaf(aD, __uint_as_float(pD.y & 0xffff0000u), acc.w);
    }
    for (; jj < cnt; jj++){
      int sA = __builtin_amdgcn_readlane(sn, jj);
      uint2 pA = *(const uint2*)(hb + sA*F + cgo);
      float aA = s_al[w][jj][hg];
      acc.x = fmaf(aA, __uint_as_float(pA.x << 16),         acc.x);
      acc.y = fmaf(aA, __uint_as_float(pA.x & 0xffff0000u), acc.y);
      acc.z = fmaf(aA, __uint_as_float(pA.y << 16),         acc.z);
      acc.w = fmaf(aA, __uint_as_float(pA.y & 0xffff0000u), acc.w);
    }
    __builtin_amdgcn_wave_barrier();               // writes of next chunk stay after reads
  }
  if (lane < 48){
    float4 b4 = *(const float4*)&bias[cg*4];
    uint2 o;
    o.x = (u32)f2bf(fmaxf(acc.x + b4.x, 0.f)) | ((u32)f2bf(fmaxf(acc.y + b4.y, 0.f)) << 16);
    o.y = (u32)f2bf(fmaxf(acc.z + b4.z, 0.f)) | ((u32)f2bf(fmaxf(acc.w + b4.w, 0.f)) << 16);
    *(uint2*)&out[(size_t)d*F + cg*4] = o;
  }
}

// ---------------- output GEMM: A[NN x 192](bf16) @ W[192 x 40](fp32) + bout -> fp32 ----
#define SA 132
__global__ __launch_bounds__(256) void gemm_out_kernel(const u16* __restrict__ A,
    const float* __restrict__ W, const float* __restrict__ bias, float* __restrict__ C){
  __shared__ __align__(16) float As[32*SA];
  __shared__ float Ws[32*NC];
  const int t = threadIdx.x;
  const int tx = t & 7, ty = t >> 3;
  const int r0 = blockIdx.x*128;
  float acc[4][5];
  #pragma unroll
  for (int r=0;r<4;r++)
    #pragma unroll
    for (int c=0;c<5;c++) acc[r][c]=0.f;

  for (int k0=0; k0<F; k0+=32){
    __syncthreads();
    #pragma unroll
    for (int i=0;i<4;i++){
      int idx = t + i*256;
      int row = idx >> 3, kq = idx & 7;
      uint2 v = make_uint2(0,0);
      if (r0+row < NN) v = *(const uint2*)&A[(size_t)(r0+row)*F + k0 + kq*4];
      As[(kq*4+0)*SA + row] = __uint_as_float(v.x << 16);
      As[(kq*4+1)*SA + row] = __uint_as_float(v.x & 0xffff0000u);
      As[(kq*4+2)*SA + row] = __uint_as_float(v.y << 16);
      As[(kq*4+3)*SA + row] = __uint_as_float(v.y & 0xffff0000u);
    }
    #pragma unroll
    for (int i=0;i<5;i++){
      int idx = t + i*256;
      int k = idx/NC, c = idx%NC;
      Ws[k*NC + c] = W[(size_t)(k0+k)*NC + c];
    }
    __syncthreads();
    #pragma unroll
    for (int k=0;k<32;k++){
      float4 a = *(float4*)&As[k*SA + ty*4];
      float av[4] = {a.x,a.y,a.z,a.w};
      float bv[5];
      #pragma unroll
      for (int c=0;c<5;c++) bv[c] = Ws[k*NC + tx*5 + c];
      #pragma unroll
      for (int r=0;r<4;r++)
        #pragma unroll
        for (int c=0;c<5;c++) acc[r][c] = fmaf(av[r], bv[c], acc[r][c]);
    }
  }
  #pragma unroll
  for (int r=0;r<4;r++){
    int row = r0 + ty*4 + r;
    if (row < NN){
      #pragma unroll
      for (int c=0;c<5;c++) C[(size_t)row*NC + tx*5 + c] = acc[r][c] + bias[tx*5+c];
    }
  }
}

extern "C" void kernel_launch(void* const* d_in, const int* in_sizes, int n_in,
                              void* d_out, int out_size, void* d_ws, size_t ws_size,
                              hipStream_t stream){
  const float* x    = (const float*)d_in[0];
  const int*   ei   = (const int*)  d_in[1];
  const float* W1   = (const float*)d_in[2];
  const float* as1  = (const float*)d_in[3];
  const float* ad1  = (const float*)d_in[4];
  const float* b1   = (const float*)d_in[5];
  const float* W2   = (const float*)d_in[6];
  const float* as2  = (const float*)d_in[7];
  const float* ad2  = (const float*)d_in[8];
  const float* b2   = (const float*)d_in[9];
  const float* Wout = (const float*)d_in[10];
  const float* bout = (const float*)d_in[11];
  float* out = (float*)d_out;

  // workspace carve-out
  u16* xb  = (u16*)d_ws;                          // NN*KIN
  u16* w1t = xb  + (size_t)NN*KIN;                // F*KIN
  u16* w2t = w1t + (size_t)F*KIN;                 // F*F
  u16* hb1 = w2t + (size_t)F*F;                   // NN*F
  u16* hb2 = hb1 + (size_t)NN*F;                  // NN*F
  u16* gb1 = hb2 + (size_t)NN*F;                  // NN*F
  u16* gb2 = gb1 + (size_t)NN*F;                  // NN*F
  float* a_src4 = (float*)(gb2 + (size_t)NN*F);   // NN*4
  float* a_dst4 = a_src4 + (size_t)NN*4;          // NN*4
  int* row_ptr  = (int*)(a_dst4 + (size_t)NN*4);  // NN+1
  int* col      = row_ptr + (NN+1);               // NE
  int* cnt      = col + NE;                       // NN
  int* partials = cnt + NN;                       // NBLK
  int* offsets  = partials + NBLK;                // NBLK

  const int* srcv = ei;
  const int* dstv = ei + NE;

  // CSR by destination (rebuilt every call); multi-block scan
  hipMemsetAsync(cnt, 0, NN*sizeof(int), stream);
  count_kernel<<<(NE+255)/256, 256, 0, stream>>>(dstv, cnt);
  partial_kernel<<<NBLK, 256, 0, stream>>>(cnt, partials);
  scan_partials<<<1, 64, 0, stream>>>(partials, offsets, row_ptr);
  emit_kernel<<<NBLK, 256, 0, stream>>>(cnt, offsets, row_ptr);
  hipMemsetAsync(cnt, 0, NN*sizeof(int), stream);
  fill_kernel<<<(NE+255)/256, 256, 0, stream>>>(srcv, dstv, row_ptr, cnt, col);

  // bf16 converts
  conv_x_kernel<<<(NN*KIN/4 + 255)/256, 256, 0, stream>>>(x, xb, NN*KIN/4);
  conv_wt_kernel<<<(KIN*F + 255)/256, 256, 0, stream>>>(W1, w1t, KIN, F);
  conv_wt_kernel<<<(F*F + 255)/256, 256, 0, stream>>>(W2, w2t, F, F);

  const int GEMM_GRID = (NN + 63)/64;
  const int AGG_GRID  = (NN + 3)/4;
  // layer 1
  gemm_mfma<KIN><<<GEMM_GRID, 256, 0, stream>>>(xb, w1t, hb1, as1, ad1, a_src4, a_dst4);
  gat_agg_wave<<<AGG_GRID, 256, 0, stream>>>(hb1, a_src4, a_dst4, row_ptr, col, b1, gb1);
  // layer 2
  gemm_mfma<F><<<GEMM_GRID, 256, 0, stream>>>(gb1, w2t, hb2, as2, ad2, a_src4, a_dst4);
  gat_agg_wave<<<AGG_GRID, 256, 0, stream>>>(hb2, a_src4, a_dst4, row_ptr, col, b2, gb2);
  // readout
  gemm_out_kernel<<<(NN + 127)/128, 256, 0, stream>>>(gb2, Wout, bout, out);
}

// Round 8
// 363.455 us; speedup vs baseline: 2.9678x; 1.1396x over previous
//
#include <hip/hip_runtime.h>
#include <math.h>

#define NN 50000
#define NE 800000
#define KIN 256
#define F 192      // HEADS*HID
#define NH 3
#define NC 40
#define NBLK 49    // ceil(NN/1024) scan blocks

typedef unsigned short u16;
typedef unsigned int   u32;
typedef __attribute__((ext_vector_type(8))) short bf16x8;
typedef __attribute__((ext_vector_type(4))) float f32x4;

static __device__ __forceinline__ u16 f2bf(float f){
  u32 u = __float_as_uint(f);
  u32 r = (u + 0x7fffu + ((u >> 16) & 1u)) >> 16;   // RNE
  return (u16)r;
}

// ---------------- CSR build ----------------
__global__ void count_kernel(const int* __restrict__ dst, int* __restrict__ cnt){
  int e = blockIdx.x*256 + threadIdx.x;
  if (e < NE) atomicAdd(&cnt[dst[e]], 1);
}

__global__ __launch_bounds__(256) void partial_kernel(const int* __restrict__ cnt, int* __restrict__ partials){
  __shared__ int red[256];
  const int t = threadIdx.x;
  const int base = blockIdx.x*1024 + t*4;
  int s = 0;
  if (base + 3 < NN){
    int4 v = *(const int4*)&cnt[base];
    s = v.x + v.y + v.z + v.w;
  } else if (base < NN){
    for (int i=base; i<NN; i++) s += cnt[i];
  }
  red[t] = s;
  __syncthreads();
  for (int off=128; off; off>>=1){
    if (t < off) red[t] += red[t+off];
    __syncthreads();
  }
  if (t==0) partials[blockIdx.x] = red[0];
}

__global__ __launch_bounds__(64) void scan_partials(const int* __restrict__ partials,
                                                    int* __restrict__ offsets, int* __restrict__ row_ptr){
  const int lane = threadIdx.x;
  int p = (lane < NBLK)? partials[lane] : 0;
  int inc = p;
  #pragma unroll
  for (int off=1; off<64; off<<=1){
    int v = __shfl_up(inc, off);
    if (lane >= off) inc += v;
  }
  if (lane < NBLK) offsets[lane] = inc - p;
  if (lane == NBLK-1) row_ptr[NN] = inc;
}

// emit row_ptr AND zero cnt (so fill can reuse cnt as its cursor; saves a memset)
__global__ __launch_bounds__(256) void emit_kernel(int* __restrict__ cnt,
                                                   const int* __restrict__ offsets,
                                                   int* __restrict__ row_ptr){
  __shared__ int ts[256];
  const int t = threadIdx.x;
  const int base = blockIdx.x*1024 + t*4;
  int4 v = make_int4(0,0,0,0);
  if (base + 3 < NN) v = *(const int4*)&cnt[base];
  else if (base < NN){
    v.x = cnt[base];
    if (base+1 < NN) v.y = cnt[base+1];
    if (base+2 < NN) v.z = cnt[base+2];
  }
  int tot = v.x + v.y + v.z + v.w;
  ts[t] = tot;
  __syncthreads();
  #pragma unroll
  for (int off=1; off<256; off<<=1){
    int val = (t >= off)? ts[t-off] : 0;
    __syncthreads();
    ts[t] += val;
    __syncthreads();
  }
  int off0 = offsets[blockIdx.x] + ts[t] - tot;
  if (base + 3 < NN){
    row_ptr[base]   = off0;
    row_ptr[base+1] = off0 + v.x;
    row_ptr[base+2] = off0 + v.x + v.y;
    row_ptr[base+3] = off0 + v.x + v.y + v.z;
    *(int4*)&cnt[base] = make_int4(0,0,0,0);
  } else if (base < NN){
    row_ptr[base] = off0; cnt[base] = 0;
    if (base+1 < NN){ row_ptr[base+1] = off0 + v.x; cnt[base+1] = 0; }
    if (base+2 < NN){ row_ptr[base+2] = off0 + v.x + v.y; cnt[base+2] = 0; }
  }
}

__global__ void fill_kernel(const int* __restrict__ src, const int* __restrict__ dst,
                            const int* __restrict__ row_ptr, int* __restrict__ cur,
                            int* __restrict__ col){
  int e = blockIdx.x*256 + threadIdx.x;
  if (e < NE){
    int d = dst[e];
    int p = row_ptr[d] + atomicAdd(&cur[d], 1);
    col[p] = src[e];
  }
}

// ---------------- weight converts ----------------
// fp32 [R x C] -> bf16 transposed [C x R]
__global__ void conv_wt_kernel(const float* __restrict__ src, u16* __restrict__ dst, int R, int C){
  int e = blockIdx.x*256 + threadIdx.x;
  if (e < R*C){
    int r = e / C, c = e % C;
    dst[(size_t)c*R + r] = f2bf(src[e]);
  }
}

// Wout[192 x 40] fp32 -> bf16 [48 x 192] transposed, rows 40..47 zeroed
__global__ void conv_wout_kernel(const float* __restrict__ W, u16* __restrict__ dst){
  int e = blockIdx.x*256 + threadIdx.x;
  if (e < 48*F){
    int n = e / F, k = e % F;
    dst[e] = (n < NC)? f2bf(W[(size_t)k*NC + n]) : (u16)0;
  }
}

// ---------------- MFMA GEMM: A[NN x K] @ Bt[192 x K](bf16) -> C[NN x 192](bf16)
// + fused attention dots. CONVA: A is fp32 (converted to bf16 during staging).
// BM=64, BN=192, BK=32. 256 thr = 4 waves; wave w owns cols w*48..w*48+47.
// Epilogue: C staged to LDS (union over As/Bs), coalesced dwordx4 global write,
// attention dots as LDS row-dots (no shfl, no atomics).
#define SAK 40
#define SC  196   // u16 stride for C-stage: 98 dwords, 98%32=2 -> quads hit distinct banks
template<int K, bool CONVA>
__global__ __launch_bounds__(256) void gemm_mfma(const void* __restrict__ Araw, const u16* __restrict__ Bt,
                                                 u16* __restrict__ C,
                                                 const float* __restrict__ att_src, const float* __restrict__ att_dst,
                                                 float* __restrict__ a_src4, float* __restrict__ a_dst4){
  __shared__ __align__(16) union {
    struct { u16 As[64*SAK]; u16 Bs[192*SAK]; } st;
    u16 Cs[64*SC];
  } sh;
  const int t = threadIdx.x;
  const int wave = t >> 6, lane = t & 63;
  const int quad = lane >> 4, l16 = lane & 15;
  const int r0 = blockIdx.x*64;

  f32x4 acc[4][3];
  #pragma unroll
  for (int rt=0;rt<4;rt++)
    #pragma unroll
    for (int ct=0;ct<3;ct++) acc[rt][ct] = (f32x4){0.f,0.f,0.f,0.f};

  for (int k0=0; k0<K; k0+=32){
    __syncthreads();
    // A tile staging: 64 rows x 32 k, 4 threads/row
    {
      int row = t >> 2, kq = t & 3;
      if (CONVA){
        const float* Af = (const float*)Araw;
        float4 v0 = make_float4(0.f,0.f,0.f,0.f), v1 = make_float4(0.f,0.f,0.f,0.f);
        if (r0+row < NN){
          v0 = *(const float4*)&Af[(size_t)(r0+row)*K + k0 + kq*8];
          v1 = *(const float4*)&Af[(size_t)(r0+row)*K + k0 + kq*8 + 4];
        }
        uint4 p;
        p.x = (u32)f2bf(v0.x) | ((u32)f2bf(v0.y) << 16);
        p.y = (u32)f2bf(v0.z) | ((u32)f2bf(v0.w) << 16);
        p.z = (u32)f2bf(v1.x) | ((u32)f2bf(v1.y) << 16);
        p.w = (u32)f2bf(v1.z) | ((u32)f2bf(v1.w) << 16);
        *(uint4*)&sh.st.As[row*SAK + kq*8] = p;
      } else {
        const u16* Ab = (const u16*)Araw;
        uint4 v = make_uint4(0,0,0,0);
        if (r0+row < NN) v = *(const uint4*)&Ab[(size_t)(r0+row)*K + k0 + kq*8];
        *(uint4*)&sh.st.As[row*SAK + kq*8] = v;
      }
    }
    // B tile staging: 192 rows x 32 k
    #pragma unroll
    for (int i=0;i<3;i++){
      int idx = t + i*256;
      int n = idx >> 2, kq = idx & 3;
      *(uint4*)&sh.st.Bs[n*SAK + kq*8] = *(const uint4*)&Bt[(size_t)n*K + k0 + kq*8];
    }
    __syncthreads();
    bf16x8 af[4], bf[3];
    #pragma unroll
    for (int rt=0;rt<4;rt++) af[rt] = *(const bf16x8*)&sh.st.As[(rt*16 + l16)*SAK + quad*8];
    #pragma unroll
    for (int ct=0;ct<3;ct++) bf[ct] = *(const bf16x8*)&sh.st.Bs[(wave*48 + ct*16 + l16)*SAK + quad*8];
    #pragma unroll
    for (int rt=0;rt<4;rt++)
      #pragma unroll
      for (int ct=0;ct<3;ct++)
        acc[rt][ct] = __builtin_amdgcn_mfma_f32_16x16x32_bf16(af[rt], bf[ct], acc[rt][ct], 0, 0, 0);
  }

  __syncthreads();   // all frag reads done -> safe to overwrite union with Cs
  // C tiles -> LDS bf16 [m][n], stride SC
  #pragma unroll
  for (int ct=0;ct<3;ct++){
    const int n = wave*48 + ct*16 + l16;
    #pragma unroll
    for (int rt=0;rt<4;rt++){
      #pragma unroll
      for (int reg=0;reg<4;reg++){
        const int m = rt*16 + quad*4 + reg;
        sh.Cs[m*SC + n] = f2bf(acc[rt][ct][reg]);
      }
    }
  }
  __syncthreads();
  // coalesced C global write: 4 threads/row, 6 chunks of 8 u16 each
  {
    int row = t >> 2, c0 = (t & 3)*6;
    int grow = r0 + row;
    if (grow < NN){
      #pragma unroll
      for (int j=0;j<6;j++){
        int ch = c0 + j;
        uint4 v = *(const uint4*)&sh.Cs[row*SC + ch*8];
        *(uint4*)&C[(size_t)grow*F + ch*8] = v;
      }
    }
  }
  // attention dots: thread (row, head) dots 64 cols from LDS
  if (t < 192){
    int row = t & 63, head = t >> 6;
    int grow = r0 + row;
    if (grow < NN){
      float ps = 0.f, pd = 0.f;
      #pragma unroll
      for (int j=0;j<8;j++){
        uint4 v = *(const uint4*)&sh.Cs[row*SC + head*64 + j*8];
        float4 w0 = *(const float4*)&att_src[head*64 + j*8];
        float4 w1 = *(const float4*)&att_src[head*64 + j*8 + 4];
        float4 d0 = *(const float4*)&att_dst[head*64 + j*8];
        float4 d1 = *(const float4*)&att_dst[head*64 + j*8 + 4];
        float c0f = __uint_as_float(v.x << 16), c1f = __uint_as_float(v.x & 0xffff0000u);
        float c2f = __uint_as_float(v.y << 16), c3f = __uint_as_float(v.y & 0xffff0000u);
        float c4f = __uint_as_float(v.z << 16), c5f = __uint_as_float(v.z & 0xffff0000u);
        float c6f = __uint_as_float(v.w << 16), c7f = __uint_as_float(v.w & 0xffff0000u);
        ps = fmaf(c0f,w0.x,fmaf(c1f,w0.y,fmaf(c2f,w0.z,fmaf(c3f,w0.w,ps))));
        ps = fmaf(c4f,w1.x,fmaf(c5f,w1.y,fmaf(c6f,w1.z,fmaf(c7f,w1.w,ps))));
        pd = fmaf(c0f,d0.x,fmaf(c1f,d0.y,fmaf(c2f,d0.z,fmaf(c3f,d0.w,pd))));
        pd = fmaf(c4f,d1.x,fmaf(c5f,d1.y,fmaf(c6f,d1.z,fmaf(c7f,d1.w,pd))));
      }
      a_src4[(size_t)grow*4 + head] = ps;
      a_dst4[(size_t)grow*4 + head] = pd;
    }
  }
}

// ---------------- GAT aggregation: one WAVE per dst node (unchanged from R7) ------
__global__ __launch_bounds__(256) void gat_agg_wave(const u16* __restrict__ hb,
    const float* __restrict__ a_src4, const float* __restrict__ a_dst4,
    const int* __restrict__ row_ptr, const int* __restrict__ col,
    const float* __restrict__ bias, u16* __restrict__ out){
  __shared__ float s_al[4][64][4];
  const int t = threadIdx.x;
  const int lane = t & 63;
  const int w = t >> 6;
  const int d = blockIdx.x*4 + w;
  if (d >= NN) return;
  const int e0  = row_ptr[d];
  const int deg = row_ptr[d+1] - e0;
  const int ecount = deg + 1;
  const float4 ad = *(const float4*)&a_dst4[(size_t)d*4];

  float m0=-1e30f, m1=-1e30f, m2=-1e30f;
  float s0=0.f, s1=0.f, s2=0.f;
  int   sn_r = d;
  float l0r=-1e30f, l1r=-1e30f, l2r=-1e30f;
  const int lastBase = ((ecount-1) >> 6) << 6;

  for (int base=0; base<ecount; base+=64){
    int j = base + lane;
    bool valid = j < ecount;
    int sn = d;
    if (j < deg) sn = col[e0+j];
    float4 as = *(const float4*)&a_src4[(size_t)sn*4];
    float l0 = as.x + ad.x; l0 = (l0>0.f)? l0 : 0.2f*l0;
    float l1 = as.y + ad.y; l1 = (l1>0.f)? l1 : 0.2f*l1;
    float l2 = as.z + ad.z; l2 = (l2>0.f)? l2 : 0.2f*l2;
    if (!valid){ l0=-1e30f; l1=-1e30f; l2=-1e30f; }
    float M0=l0, M1=l1, M2=l2;
    #pragma unroll
    for (int off=32; off; off>>=1){
      M0 = fmaxf(M0, __shfl_xor(M0, off));
      M1 = fmaxf(M1, __shfl_xor(M1, off));
      M2 = fmaxf(M2, __shfl_xor(M2, off));
    }
    float E0 = valid? __expf(l0-M0) : 0.f;
    float E1 = valid? __expf(l1-M1) : 0.f;
    float E2 = valid? __expf(l2-M2) : 0.f;
    float S0=E0, S1=E1, S2=E2;
    #pragma unroll
    for (int off=32; off; off>>=1){
      S0 += __shfl_xor(S0, off);
      S1 += __shfl_xor(S1, off);
      S2 += __shfl_xor(S2, off);
    }
    float n0 = fmaxf(m0,M0); s0 = s0*__expf(m0-n0) + S0*__expf(M0-n0); m0 = n0;
    float n1 = fmaxf(m1,M1); s1 = s1*__expf(m1-n1) + S1*__expf(M1-n1); m1 = n1;
    float n2 = fmaxf(m2,M2); s2 = s2*__expf(m2-n2) + S2*__expf(M2-n2); m2 = n2;
    sn_r = sn; l0r = l0; l1r = l1; l2r = l2;
  }
  const float i0 = 1.f/s0, i1 = 1.f/s1, i2 = 1.f/s2;

  const int cg = (lane < 48)? lane : lane - 48;
  const int hg = (lane < 48)? (lane >> 4) : (lane >> 4) - 3;
  const int cgo = cg*4;
  float4 acc = make_float4(0.f,0.f,0.f,0.f);
  for (int base=0; base<ecount; base+=64){
    int j = base + lane;
    bool valid = j < ecount;
    int sn; float l0,l1,l2;
    if (base == lastBase){ sn = sn_r; l0 = l0r; l1 = l1r; l2 = l2r; }
    else {
      sn = d;
      if (j < deg) sn = col[e0+j];
      float4 as = *(const float4*)&a_src4[(size_t)sn*4];
      l0 = as.x + ad.x; l0 = (l0>0.f)? l0 : 0.2f*l0;
      l1 = as.y + ad.y; l1 = (l1>0.f)? l1 : 0.2f*l1;
      l2 = as.z + ad.z; l2 = (l2>0.f)? l2 : 0.2f*l2;
    }
    float4 st;
    st.x = valid? __expf(l0-m0)*i0 : 0.f;
    st.y = valid? __expf(l1-m1)*i1 : 0.f;
    st.z = valid? __expf(l2-m2)*i2 : 0.f;
    st.w = 0.f;
    *(float4*)&s_al[w][lane][0] = st;
    __builtin_amdgcn_wave_barrier();
    int cnt = ecount - base; if (cnt > 64) cnt = 64;
    int jj = 0;
    for (; jj+4 <= cnt; jj += 4){
      int sA = __builtin_amdgcn_readlane(sn, jj);
      int sB = __builtin_amdgcn_readlane(sn, jj+1);
      int sC = __builtin_amdgcn_readlane(sn, jj+2);
      int sD = __builtin_amdgcn_readlane(sn, jj+3);
      uint2 pA = *(const uint2*)(hb + sA*F + cgo);
      uint2 pB = *(const uint2*)(hb + sB*F + cgo);
      uint2 pC = *(const uint2*)(hb + sC*F + cgo);
      uint2 pD = *(const uint2*)(hb + sD*F + cgo);
      float aA = s_al[w][jj  ][hg];
      float aB = s_al[w][jj+1][hg];
      float aC = s_al[w][jj+2][hg];
      float aD = s_al[w][jj+3][hg];
      acc.x = fmaf(aA, __uint_as_float(pA.x << 16),         acc.x);
      acc.y = fmaf(aA, __uint_as_float(pA.x & 0xffff0000u), acc.y);
      acc.z = fmaf(aA, __uint_as_float(pA.y << 16),         acc.z);
      acc.w = fmaf(aA, __uint_as_float(pA.y & 0xffff0000u), acc.w);
      acc.x = fmaf(aB, __uint_as_float(pB.x << 16),         acc.x);
      acc.y = fmaf(aB, __uint_as_float(pB.x & 0xffff0000u), acc.y);
      acc.z = fmaf(aB, __uint_as_float(pB.y << 16),         acc.z);
      acc.w = fmaf(aB, __uint_as_float(pB.y & 0xffff0000u), acc.w);
      acc.x = fmaf(aC, __uint_as_float(pC.x << 16),         acc.x);
      acc.y = fmaf(aC, __uint_as_float(pC.x & 0xffff0000u), acc.y);
      acc.z = fmaf(aC, __uint_as_float(pC.y << 16),         acc.z);
      acc.w = fmaf(aC, __uint_as_float(pC.y & 0xffff0000u), acc.w);
      acc.x = fmaf(aD, __uint_as_float(pD.x << 16),         acc.x);
      acc.y = fmaf(aD, __uint_as_float(pD.x & 0xffff0000u), acc.y);
      acc.z = fmaf(aD, __uint_as_float(pD.y << 16),         acc.z);
      acc.w = fmaf(aD, __uint_as_float(pD.y & 0xffff0000u), acc.w);
    }
    for (; jj < cnt; jj++){
      int sA = __builtin_amdgcn_readlane(sn, jj);
      uint2 pA = *(const uint2*)(hb + sA*F + cgo);
      float aA = s_al[w][jj][hg];
      acc.x = fmaf(aA, __uint_as_float(pA.x << 16),         acc.x);
      acc.y = fmaf(aA, __uint_as_float(pA.x & 0xffff0000u), acc.y);
      acc.z = fmaf(aA, __uint_as_float(pA.y << 16),         acc.z);
      acc.w = fmaf(aA, __uint_as_float(pA.y & 0xffff0000u), acc.w);
    }
    __builtin_amdgcn_wave_barrier();
  }
  if (lane < 48){
    float4 b4 = *(const float4*)&bias[cg*4];
    uint2 o;
    o.x = (u32)f2bf(fmaxf(acc.x + b4.x, 0.f)) | ((u32)f2bf(fmaxf(acc.y + b4.y, 0.f)) << 16);
    o.y = (u32)f2bf(fmaxf(acc.z + b4.z, 0.f)) | ((u32)f2bf(fmaxf(acc.w + b4.w, 0.f)) << 16);
    *(uint2*)&out[(size_t)d*F + cg*4] = o;
  }
}

// ---------------- output GEMM via MFMA, no LDS: A[NN x 192](bf16) @ Wt[48 x 192](bf16)
// block = 4 waves; each wave: 16 rows x 48 cols (3 col-tiles), K=192 in 6 steps.
__global__ __launch_bounds__(256) void gemm_out_mfma(const u16* __restrict__ A,
    const u16* __restrict__ Wt, const float* __restrict__ bias, float* __restrict__ out){
  const int t = threadIdx.x;
  const int wave = t >> 6, lane = t & 63;
  const int quad = lane >> 4, l16 = lane & 15;
  const int rbase = blockIdx.x*64 + wave*16;
  const int arow = rbase + l16;
  f32x4 acc[3];
  #pragma unroll
  for (int ct=0;ct<3;ct++) acc[ct] = (f32x4){0.f,0.f,0.f,0.f};
  #pragma unroll
  for (int ks=0; ks<6; ks++){
    const int k0 = ks*32;
    union { uint4 u; bf16x8 h; } cva;
    cva.u = make_uint4(0,0,0,0);
    if (arow < NN) cva.u = *(const uint4*)&A[(size_t)arow*F + k0 + quad*8];
    #pragma unroll
    for (int ct=0;ct<3;ct++){
      bf16x8 bfr = *(const bf16x8*)&Wt[(size_t)(ct*16 + l16)*F + k0 + quad*8];
      acc[ct] = __builtin_amdgcn_mfma_f32_16x16x32_bf16(cva.h, bfr, acc[ct], 0, 0, 0);
    }
  }
  #pragma unroll
  for (int ct=0;ct<3;ct++){
    const int n = ct*16 + l16;
    #pragma unroll
    for (int reg=0;reg<4;reg++){
      const int m = quad*4 + reg;
      const int grow = rbase + m;
      if (grow < NN && n < NC) out[(size_t)grow*NC + n] = acc[ct][reg] + bias[n];
    }
  }
}

extern "C" void kernel_launch(void* const* d_in, const int* in_sizes, int n_in,
                              void* d_out, int out_size, void* d_ws, size_t ws_size,
                              hipStream_t stream){
  const float* x    = (const float*)d_in[0];
  const int*   ei   = (const int*)  d_in[1];
  const float* W1   = (const float*)d_in[2];
  const float* as1  = (const float*)d_in[3];
  const float* ad1  = (const float*)d_in[4];
  const float* b1   = (const float*)d_in[5];
  const float* W2   = (const float*)d_in[6];
  const float* as2  = (const float*)d_in[7];
  const float* ad2  = (const float*)d_in[8];
  const float* b2   = (const float*)d_in[9];
  const float* Wout = (const float*)d_in[10];
  const float* bout = (const float*)d_in[11];
  float* out = (float*)d_out;

  // workspace carve-out
  u16* w1t = (u16*)d_ws;                          // F*KIN  (W1^T bf16)
  u16* w2t = w1t + (size_t)F*KIN;                 // F*F    (W2^T bf16)
  u16* wot = w2t + (size_t)F*F;                   // 48*F   (Wout^T bf16, padded)
  u16* hb1 = wot + (size_t)48*F;                  // NN*F
  u16* hb2 = hb1 + (size_t)NN*F;                  // NN*F
  u16* gb1 = hb2 + (size_t)NN*F;                  // NN*F
  u16* gb2 = gb1 + (size_t)NN*F;                  // NN*F
  float* a_src4 = (float*)(gb2 + (size_t)NN*F);   // NN*4
  float* a_dst4 = a_src4 + (size_t)NN*4;          // NN*4
  int* row_ptr  = (int*)(a_dst4 + (size_t)NN*4);  // NN+1
  int* col      = row_ptr + (NN+1);               // NE
  int* cnt      = col + NE;                       // NN
  int* partials = cnt + NN;                       // NBLK
  int* offsets  = partials + NBLK;                // NBLK

  const int* srcv = ei;
  const int* dstv = ei + NE;

  // CSR by destination (rebuilt every call); emit zeroes cnt for fill's cursor
  hipMemsetAsync(cnt, 0, NN*sizeof(int), stream);
  count_kernel<<<(NE+255)/256, 256, 0, stream>>>(dstv, cnt);
  partial_kernel<<<NBLK, 256, 0, stream>>>(cnt, partials);
  scan_partials<<<1, 64, 0, stream>>>(partials, offsets, row_ptr);
  emit_kernel<<<NBLK, 256, 0, stream>>>(cnt, offsets, row_ptr);
  fill_kernel<<<(NE+255)/256, 256, 0, stream>>>(srcv, dstv, row_ptr, cnt, col);

  // weight converts (bf16, transposed)
  conv_wt_kernel<<<(KIN*F + 255)/256, 256, 0, stream>>>(W1, w1t, KIN, F);
  conv_wt_kernel<<<(F*F + 255)/256, 256, 0, stream>>>(W2, w2t, F, F);
  conv_wout_kernel<<<(48*F + 255)/256, 256, 0, stream>>>(Wout, wot);

  const int GEMM_GRID = (NN + 63)/64;
  const int AGG_GRID  = (NN + 3)/4;
  // layer 1 (x converted to bf16 inside staging)
  gemm_mfma<KIN,true><<<GEMM_GRID, 256, 0, stream>>>(x, w1t, hb1, as1, ad1, a_src4, a_dst4);
  gat_agg_wave<<<AGG_GRID, 256, 0, stream>>>(hb1, a_src4, a_dst4, row_ptr, col, b1, gb1);
  // layer 2
  gemm_mfma<F,false><<<GEMM_GRID, 256, 0, stream>>>(gb1, w2t, hb2, as2, ad2, a_src4, a_dst4);
  gat_agg_wave<<<AGG_GRID, 256, 0, stream>>>(hb2, a_src4, a_dst4, row_ptr, col, b2, gb2);
  // readout
  gemm_out_mfma<<<GEMM_GRID, 256, 0, stream>>>(gb2, wot, bout, out);
}

// Round 9
// 356.824 us; speedup vs baseline: 3.0229x; 1.0186x over previous
//
#include <hip/hip_runtime.h>
#include <math.h>

#define NN 50000
#define NE 800000
#define KIN 256
#define F 192      // HEADS*HID
#define NH 3
#define NC 40
#define NBLK 49    // ceil(NN/1024) scan blocks

typedef unsigned short u16;
typedef unsigned int   u32;
typedef __attribute__((ext_vector_type(8))) short bf16x8;
typedef __attribute__((ext_vector_type(4))) float f32x4;

static __device__ __forceinline__ u16 f2bf(float f){
  u32 u = __float_as_uint(f);
  u32 r = (u + 0x7fffu + ((u >> 16) & 1u)) >> 16;   // RNE
  return (u16)r;
}

// ---------------- CSR build ----------------
__global__ void count_kernel(const int* __restrict__ dst, int* __restrict__ cnt){
  int e = blockIdx.x*256 + threadIdx.x;
  if (e < NE) atomicAdd(&cnt[dst[e]], 1);
}

__global__ __launch_bounds__(256) void partial_kernel(const int* __restrict__ cnt, int* __restrict__ partials){
  __shared__ int red[256];
  const int t = threadIdx.x;
  const int base = blockIdx.x*1024 + t*4;
  int s = 0;
  if (base + 3 < NN){
    int4 v = *(const int4*)&cnt[base];
    s = v.x + v.y + v.z + v.w;
  } else if (base < NN){
    for (int i=base; i<NN; i++) s += cnt[i];
  }
  red[t] = s;
  __syncthreads();
  for (int off=128; off; off>>=1){
    if (t < off) red[t] += red[t+off];
    __syncthreads();
  }
  if (t==0) partials[blockIdx.x] = red[0];
}

__global__ __launch_bounds__(64) void scan_partials(const int* __restrict__ partials,
                                                    int* __restrict__ offsets, int* __restrict__ row_ptr){
  const int lane = threadIdx.x;
  int p = (lane < NBLK)? partials[lane] : 0;
  int inc = p;
  #pragma unroll
  for (int off=1; off<64; off<<=1){
    int v = __shfl_up(inc, off);
    if (lane >= off) inc += v;
  }
  if (lane < NBLK) offsets[lane] = inc - p;
  if (lane == NBLK-1) row_ptr[NN] = inc;
}

// emit row_ptr AND zero cnt (fill reuses cnt as cursor)
__global__ __launch_bounds__(256) void emit_kernel(int* __restrict__ cnt,
                                                   const int* __restrict__ offsets,
                                                   int* __restrict__ row_ptr){
  __shared__ int ts[256];
  const int t = threadIdx.x;
  const int base = blockIdx.x*1024 + t*4;
  int4 v = make_int4(0,0,0,0);
  if (base + 3 < NN) v = *(const int4*)&cnt[base];
  else if (base < NN){
    v.x = cnt[base];
    if (base+1 < NN) v.y = cnt[base+1];
    if (base+2 < NN) v.z = cnt[base+2];
  }
  int tot = v.x + v.y + v.z + v.w;
  ts[t] = tot;
  __syncthreads();
  #pragma unroll
  for (int off=1; off<256; off<<=1){
    int val = (t >= off)? ts[t-off] : 0;
    __syncthreads();
    ts[t] += val;
    __syncthreads();
  }
  int off0 = offsets[blockIdx.x] + ts[t] - tot;
  if (base + 3 < NN){
    row_ptr[base]   = off0;
    row_ptr[base+1] = off0 + v.x;
    row_ptr[base+2] = off0 + v.x + v.y;
    row_ptr[base+3] = off0 + v.x + v.y + v.z;
    *(int4*)&cnt[base] = make_int4(0,0,0,0);
  } else if (base < NN){
    row_ptr[base] = off0; cnt[base] = 0;
    if (base+1 < NN){ row_ptr[base+1] = off0 + v.x; cnt[base+1] = 0; }
    if (base+2 < NN){ row_ptr[base+2] = off0 + v.x + v.y; cnt[base+2] = 0; }
  }
}

__global__ void fill_kernel(const int* __restrict__ src, const int* __restrict__ dst,
                            const int* __restrict__ row_ptr, int* __restrict__ cur,
                            int* __restrict__ col){
  int e = blockIdx.x*256 + threadIdx.x;
  if (e < NE){
    int d = dst[e];
    int p = row_ptr[d] + atomicAdd(&cur[d], 1);
    col[p] = src[e];
  }
}

// ---------------- merged weight converts (bf16, transposed) ----------------
// w1t[F][KIN] <- W1[KIN][F];  w2t[F][F] <- W2[F][F];  wot[48][F] <- Wout[F][NC] (pad 0)
__global__ void conv_all(const float* __restrict__ W1, const float* __restrict__ W2,
                         const float* __restrict__ Wout,
                         u16* __restrict__ w1t, u16* __restrict__ w2t, u16* __restrict__ wot){
  int e = blockIdx.x*256 + threadIdx.x;
  if (e < F*KIN){
    int c = e / KIN, r = e % KIN;
    w1t[e] = f2bf(W1[(size_t)r*F + c]);
    return;
  }
  int e2 = e - F*KIN;
  if (e2 < F*F){
    int c = e2 / F, r = e2 % F;
    w2t[e2] = f2bf(W2[(size_t)r*F + c]);
    return;
  }
  int e3 = e2 - F*F;
  if (e3 < 48*F){
    int n = e3 / F, k = e3 % F;
    wot[e3] = (n < NC)? f2bf(Wout[(size_t)k*NC + n]) : (u16)0;
  }
}

// ---------------- MFMA GEMM: A[NN x K] @ Bt[192 x K](bf16) -> C[NN x 192](bf16)
// + fused attention dots. CONVA: A is fp32 (converted to bf16 during staging).
// BM=64, BN=192, BK=64. 256 thr = 4 waves; wave w owns cols w*48..w*48+47.
#define SAK 72   // u16 stride; dword stride 36 -> all ds ops <=2-way bank alias (free)
#define SC  196  // u16 stride for C-stage
template<int K, bool CONVA>
__global__ __launch_bounds__(256) void gemm_mfma(const void* __restrict__ Araw, const u16* __restrict__ Bt,
                                                 u16* __restrict__ C,
                                                 const float* __restrict__ att_src, const float* __restrict__ att_dst,
                                                 float* __restrict__ a_src4, float* __restrict__ a_dst4){
  __shared__ __align__(16) union {
    struct { u16 As[64*SAK]; u16 Bs[192*SAK]; } st;
    u16 Cs[64*SC];
  } sh;
  const int t = threadIdx.x;
  const int wave = t >> 6, lane = t & 63;
  const int quad = lane >> 4, l16 = lane & 15;
  const int r0 = blockIdx.x*64;

  f32x4 acc[4][3];
  #pragma unroll
  for (int rt=0;rt<4;rt++)
    #pragma unroll
    for (int ct=0;ct<3;ct++) acc[rt][ct] = (f32x4){0.f,0.f,0.f,0.f};

  for (int k0=0; k0<K; k0+=64){
    __syncthreads();
    // A tile: 64 rows x 64 k; thread -> 32 u16 (two uint4 stores)
    {
      int row = t >> 2, kq = (t & 3)*16;   // u16 offset within row
      bool ok = (r0+row) < NN;
      if (CONVA){
        const float* Af = (const float*)Araw;
        float4 v0 = make_float4(0,0,0,0), v1 = v0, v2 = v0, v3 = v0;
        if (ok){
          const float* p = &Af[(size_t)(r0+row)*K + k0 + kq];
          v0 = *(const float4*)(p+0);
          v1 = *(const float4*)(p+4);
          v2 = *(const float4*)(p+8);
          v3 = *(const float4*)(p+12);
        }
        uint4 pa, pb;
        pa.x = (u32)f2bf(v0.x) | ((u32)f2bf(v0.y) << 16);
        pa.y = (u32)f2bf(v0.z) | ((u32)f2bf(v0.w) << 16);
        pa.z = (u32)f2bf(v1.x) | ((u32)f2bf(v1.y) << 16);
        pa.w = (u32)f2bf(v1.z) | ((u32)f2bf(v1.w) << 16);
        pb.x = (u32)f2bf(v2.x) | ((u32)f2bf(v2.y) << 16);
        pb.y = (u32)f2bf(v2.z) | ((u32)f2bf(v2.w) << 16);
        pb.z = (u32)f2bf(v3.x) | ((u32)f2bf(v3.y) << 16);
        pb.w = (u32)f2bf(v3.z) | ((u32)f2bf(v3.w) << 16);
        *(uint4*)&sh.st.As[row*SAK + kq]     = pa;
        *(uint4*)&sh.st.As[row*SAK + kq + 8] = pb;
      } else {
        const u16* Ab = (const u16*)Araw;
        uint4 va = make_uint4(0,0,0,0), vb = va;
        if (ok){
          va = *(const uint4*)&Ab[(size_t)(r0+row)*K + k0 + kq];
          vb = *(const uint4*)&Ab[(size_t)(r0+row)*K + k0 + kq + 8];
        }
        *(uint4*)&sh.st.As[row*SAK + kq]     = va;
        *(uint4*)&sh.st.As[row*SAK + kq + 8] = vb;
      }
    }
    // B tile: 192 rows x 64 k = 1536 chunks of 8 u16; 6 per thread
    #pragma unroll
    for (int i=0;i<6;i++){
      int idx = t + i*256;
      int n = idx >> 3, kc = idx & 7;
      *(uint4*)&sh.st.Bs[n*SAK + kc*8] = *(const uint4*)&Bt[(size_t)n*K + k0 + kc*8];
    }
    __syncthreads();
    bf16x8 af[4][2], bf[3][2];
    #pragma unroll
    for (int kf=0;kf<2;kf++){
      #pragma unroll
      for (int rt=0;rt<4;rt++) af[rt][kf] = *(const bf16x8*)&sh.st.As[(rt*16 + l16)*SAK + kf*32 + quad*8];
      #pragma unroll
      for (int ct=0;ct<3;ct++) bf[ct][kf] = *(const bf16x8*)&sh.st.Bs[(wave*48 + ct*16 + l16)*SAK + kf*32 + quad*8];
    }
    #pragma unroll
    for (int kf=0;kf<2;kf++)
      #pragma unroll
      for (int rt=0;rt<4;rt++)
        #pragma unroll
        for (int ct=0;ct<3;ct++)
          acc[rt][ct] = __builtin_amdgcn_mfma_f32_16x16x32_bf16(af[rt][kf], bf[ct][kf], acc[rt][ct], 0, 0, 0);
  }

  __syncthreads();   // frag reads done -> safe to overwrite union with Cs
  #pragma unroll
  for (int ct=0;ct<3;ct++){
    const int n = wave*48 + ct*16 + l16;
    #pragma unroll
    for (int rt=0;rt<4;rt++){
      #pragma unroll
      for (int reg=0;reg<4;reg++){
        const int m = rt*16 + quad*4 + reg;
        sh.Cs[m*SC + n] = f2bf(acc[rt][ct][reg]);
      }
    }
  }
  __syncthreads();
  // coalesced C global write: 4 threads/row, 6 chunks of 8 u16 each
  {
    int row = t >> 2, c0 = (t & 3)*6;
    int grow = r0 + row;
    if (grow < NN){
      #pragma unroll
      for (int j=0;j<6;j++){
        int ch = c0 + j;
        uint4 v = *(const uint4*)&sh.Cs[row*SC + ch*8];
        *(uint4*)&C[(size_t)grow*F + ch*8] = v;
      }
    }
  }
  // attention dots: thread (row, head) dots 64 cols from LDS
  if (t < 192){
    int row = t & 63, head = t >> 6;
    int grow = r0 + row;
    if (grow < NN){
      float ps = 0.f, pd = 0.f;
      #pragma unroll
      for (int j=0;j<8;j++){
        uint4 v = *(const uint4*)&sh.Cs[row*SC + head*64 + j*8];
        float4 w0 = *(const float4*)&att_src[head*64 + j*8];
        float4 w1 = *(const float4*)&att_src[head*64 + j*8 + 4];
        float4 d0 = *(const float4*)&att_dst[head*64 + j*8];
        float4 d1 = *(const float4*)&att_dst[head*64 + j*8 + 4];
        float c0f = __uint_as_float(v.x << 16), c1f = __uint_as_float(v.x & 0xffff0000u);
        float c2f = __uint_as_float(v.y << 16), c3f = __uint_as_float(v.y & 0xffff0000u);
        float c4f = __uint_as_float(v.z << 16), c5f = __uint_as_float(v.z & 0xffff0000u);
        float c6f = __uint_as_float(v.w << 16), c7f = __uint_as_float(v.w & 0xffff0000u);
        ps = fmaf(c0f,w0.x,fmaf(c1f,w0.y,fmaf(c2f,w0.z,fmaf(c3f,w0.w,ps))));
        ps = fmaf(c4f,w1.x,fmaf(c5f,w1.y,fmaf(c6f,w1.z,fmaf(c7f,w1.w,ps))));
        pd = fmaf(c0f,d0.x,fmaf(c1f,d0.y,fmaf(c2f,d0.z,fmaf(c3f,d0.w,pd))));
        pd = fmaf(c4f,d1.x,fmaf(c5f,d1.y,fmaf(c6f,d1.z,fmaf(c7f,d1.w,pd))));
      }
      a_src4[(size_t)grow*4 + head] = ps;
      a_dst4[(size_t)grow*4 + head] = pd;
    }
  }
}

// ---------------- GAT aggregation: one WAVE per dst node ----------------
// No max-subtraction (logits bounded: |l| << 88, exp cannot overflow fp32).
// Pass A: e=exp(leaky(l)), butterfly-sum only. Pass B reuses saved e for the
// (common) last chunk; gather unrolled x8 for load batching.
__global__ __launch_bounds__(256) void gat_agg_wave(const u16* __restrict__ hb,
    const float* __restrict__ a_src4, const float* __restrict__ a_dst4,
    const int* __restrict__ row_ptr, const int* __restrict__ col,
    const float* __restrict__ bias, u16* __restrict__ out){
  __shared__ float s_al[4][64][4];
  const int t = threadIdx.x;
  const int lane = t & 63;
  const int w = t >> 6;
  const int d = blockIdx.x*4 + w;
  if (d >= NN) return;
  const int e0  = row_ptr[d];
  const int deg = row_ptr[d+1] - e0;
  const int ecount = deg + 1;                 // implicit self-loop at j==deg
  const float4 ad = *(const float4*)&a_dst4[(size_t)d*4];

  float s0=0.f, s1=0.f, s2=0.f;
  int   sn_r = d;
  float e0r=0.f, e1r=0.f, e2r=0.f;
  const int lastBase = ((ecount-1) >> 6) << 6;

  // ---- pass A: softmax denominators (no max shift) ----
  for (int base=0; base<ecount; base+=64){
    int j = base + lane;
    bool valid = j < ecount;
    int sn = d;
    if (j < deg) sn = col[e0+j];
    float4 as = *(const float4*)&a_src4[(size_t)sn*4];
    float l0 = as.x + ad.x; l0 = (l0>0.f)? l0 : 0.2f*l0;
    float l1 = as.y + ad.y; l1 = (l1>0.f)? l1 : 0.2f*l1;
    float l2 = as.z + ad.z; l2 = (l2>0.f)? l2 : 0.2f*l2;
    float E0 = valid? __expf(l0) : 0.f;
    float E1 = valid? __expf(l1) : 0.f;
    float E2 = valid? __expf(l2) : 0.f;
    float S0=E0, S1=E1, S2=E2;
    #pragma unroll
    for (int off=32; off; off>>=1){
      S0 += __shfl_xor(S0, off);
      S1 += __shfl_xor(S1, off);
      S2 += __shfl_xor(S2, off);
    }
    s0 += S0; s1 += S1; s2 += S2;
    sn_r = sn; e0r = E0; e1r = E1; e2r = E2;
  }
  const float i0 = 1.f/s0, i1 = 1.f/s1, i2 = 1.f/s2;

  // ---- pass B: gather ----
  const int cg = (lane < 48)? lane : lane - 48;             // column group
  const int hg = (lane < 48)? (lane >> 4) : (lane >> 4) - 3;
  const int cgo = cg*4;
  float4 acc = make_float4(0.f,0.f,0.f,0.f);
  for (int base=0; base<ecount; base+=64){
    int sn; float E0,E1,E2;
    if (base == lastBase){ sn = sn_r; E0 = e0r; E1 = e1r; E2 = e2r; }
    else {
      int j = base + lane;                   // full chunk: always valid
      sn = (j < deg)? col[e0+j] : d;
      float4 as = *(const float4*)&a_src4[(size_t)sn*4];
      float l0 = as.x + ad.x; l0 = (l0>0.f)? l0 : 0.2f*l0;
      float l1 = as.y + ad.y; l1 = (l1>0.f)? l1 : 0.2f*l1;
      float l2 = as.z + ad.z; l2 = (l2>0.f)? l2 : 0.2f*l2;
      E0 = __expf(l0); E1 = __expf(l1); E2 = __expf(l2);
    }
    float4 st;
    st.x = E0*i0; st.y = E1*i1; st.z = E2*i2; st.w = 0.f;
    *(float4*)&s_al[w][lane][0] = st;
    __builtin_amdgcn_wave_barrier();
    int cnt = ecount - base; if (cnt > 64) cnt = 64;
    int jj = 0;
    for (; jj+8 <= cnt; jj += 8){
      int   sA[8]; uint2 p[8]; float a[8];
      #pragma unroll
      for (int q=0;q<8;q++) sA[q] = __builtin_amdgcn_readlane(sn, jj+q);
      #pragma unroll
      for (int q=0;q<8;q++) p[q] = *(const uint2*)(hb + sA[q]*F + cgo);
      #pragma unroll
      for (int q=0;q<8;q++) a[q] = s_al[w][jj+q][hg];
      #pragma unroll
      for (int q=0;q<8;q++){
        acc.x = fmaf(a[q], __uint_as_float(p[q].x << 16),         acc.x);
        acc.y = fmaf(a[q], __uint_as_float(p[q].x & 0xffff0000u), acc.y);
        acc.z = fmaf(a[q], __uint_as_float(p[q].y << 16),         acc.z);
        acc.w = fmaf(a[q], __uint_as_float(p[q].y & 0xffff0000u), acc.w);
      }
    }
    for (; jj < cnt; jj++){
      int sA = __builtin_amdgcn_readlane(sn, jj);
      uint2 pA = *(const uint2*)(hb + sA*F + cgo);
      float aA = s_al[w][jj][hg];
      acc.x = fmaf(aA, __uint_as_float(pA.x << 16),         acc.x);
      acc.y = fmaf(aA, __uint_as_float(pA.x & 0xffff0000u), acc.y);
      acc.z = fmaf(aA, __uint_as_float(pA.y << 16),         acc.z);
      acc.w = fmaf(aA, __uint_as_float(pA.y & 0xffff0000u), acc.w);
    }
    __builtin_amdgcn_wave_barrier();
  }
  if (lane < 48){
    float4 b4 = *(const float4*)&bias[cg*4];
    uint2 o;
    o.x = (u32)f2bf(fmaxf(acc.x + b4.x, 0.f)) | ((u32)f2bf(fmaxf(acc.y + b4.y, 0.f)) << 16);
    o.y = (u32)f2bf(fmaxf(acc.z + b4.z, 0.f)) | ((u32)f2bf(fmaxf(acc.w + b4.w, 0.f)) << 16);
    *(uint2*)&out[(size_t)d*F + cg*4] = o;
  }
}

// ---------------- output GEMM via MFMA, no LDS: A[NN x 192](bf16) @ Wt[48 x 192](bf16)
__global__ __launch_bounds__(256) void gemm_out_mfma(const u16* __restrict__ A,
    const u16* __restrict__ Wt, const float* __restrict__ bias, float* __restrict__ out){
  const int t = threadIdx.x;
  const int wave = t >> 6, lane = t & 63;
  const int quad = lane >> 4, l16 = lane & 15;
  const int rbase = blockIdx.x*64 + wave*16;
  const int arow = rbase + l16;
  f32x4 acc[3];
  #pragma unroll
  for (int ct=0;ct<3;ct++) acc[ct] = (f32x4){0.f,0.f,0.f,0.f};
  #pragma unroll
  for (int ks=0; ks<6; ks++){
    const int k0 = ks*32;
    union { uint4 u; bf16x8 h; } cva;
    cva.u = make_uint4(0,0,0,0);
    if (arow < NN) cva.u = *(const uint4*)&A[(size_t)arow*F + k0 + quad*8];
    #pragma unroll
    for (int ct=0;ct<3;ct++){
      bf16x8 bfr = *(const bf16x8*)&Wt[(size_t)(ct*16 + l16)*F + k0 + quad*8];
      acc[ct] = __builtin_amdgcn_mfma_f32_16x16x32_bf16(cva.h, bfr, acc[ct], 0, 0, 0);
    }
  }
  #pragma unroll
  for (int ct=0;ct<3;ct++){
    const int n = ct*16 + l16;
    #pragma unroll
    for (int reg=0;reg<4;reg++){
      const int m = quad*4 + reg;
      const int grow = rbase + m;
      if (grow < NN && n < NC) out[(size_t)grow*NC + n] = acc[ct][reg] + bias[n];
    }
  }
}

extern "C" void kernel_launch(void* const* d_in, const int* in_sizes, int n_in,
                              void* d_out, int out_size, void* d_ws, size_t ws_size,
                              hipStream_t stream){
  const float* x    = (const float*)d_in[0];
  const int*   ei   = (const int*)  d_in[1];
  const float* W1   = (const float*)d_in[2];
  const float* as1  = (const float*)d_in[3];
  const float* ad1  = (const float*)d_in[4];
  const float* b1   = (const float*)d_in[5];
  const float* W2   = (const float*)d_in[6];
  const float* as2  = (const float*)d_in[7];
  const float* ad2  = (const float*)d_in[8];
  const float* b2   = (const float*)d_in[9];
  const float* Wout = (const float*)d_in[10];
  const float* bout = (const float*)d_in[11];
  float* out = (float*)d_out;

  // workspace carve-out
  u16* w1t = (u16*)d_ws;                          // F*KIN  (W1^T bf16)
  u16* w2t = w1t + (size_t)F*KIN;                 // F*F    (W2^T bf16)
  u16* wot = w2t + (size_t)F*F;                   // 48*F   (Wout^T bf16, padded)
  u16* hb1 = wot + (size_t)48*F;                  // NN*F
  u16* hb2 = hb1 + (size_t)NN*F;                  // NN*F
  u16* gb1 = hb2 + (size_t)NN*F;                  // NN*F
  u16* gb2 = gb1 + (size_t)NN*F;                  // NN*F
  float* a_src4 = (float*)(gb2 + (size_t)NN*F);   // NN*4
  float* a_dst4 = a_src4 + (size_t)NN*4;          // NN*4
  int* row_ptr  = (int*)(a_dst4 + (size_t)NN*4);  // NN+1
  int* col      = row_ptr + (NN+1);               // NE
  int* cnt      = col + NE;                       // NN
  int* partials = cnt + NN;                       // NBLK
  int* offsets  = partials + NBLK;                // NBLK

  const int* srcv = ei;
  const int* dstv = ei + NE;

  // CSR by destination (rebuilt every call)
  hipMemsetAsync(cnt, 0, NN*sizeof(int), stream);
  count_kernel<<<(NE+255)/256, 256, 0, stream>>>(dstv, cnt);
  partial_kernel<<<NBLK, 256, 0, stream>>>(cnt, partials);
  scan_partials<<<1, 64, 0, stream>>>(partials, offsets, row_ptr);
  emit_kernel<<<NBLK, 256, 0, stream>>>(cnt, offsets, row_ptr);
  fill_kernel<<<(NE+255)/256, 256, 0, stream>>>(srcv, dstv, row_ptr, cnt, col);

  // merged weight converts
  const int CONV_N = F*KIN + F*F + 48*F;
  conv_all<<<(CONV_N + 255)/256, 256, 0, stream>>>(W1, W2, Wout, w1t, w2t, wot);

  const int GEMM_GRID = (NN + 63)/64;
  const int AGG_GRID  = (NN + 3)/4;
  // layer 1 (x converted to bf16 inside staging)
  gemm_mfma<KIN,true><<<GEMM_GRID, 256, 0, stream>>>(x, w1t, hb1, as1, ad1, a_src4, a_dst4);
  gat_agg_wave<<<AGG_GRID, 256, 0, stream>>>(hb1, a_src4, a_dst4, row_ptr, col, b1, gb1);
  // layer 2
  gemm_mfma<F,false><<<GEMM_GRID, 256, 0, stream>>>(gb1, w2t, hb2, as2, ad2, a_src4, a_dst4);
  gat_agg_wave<<<AGG_GRID, 256, 0, stream>>>(hb2, a_src4, a_dst4, row_ptr, col, b2, gb2);
  // readout
  gemm_out_mfma<<<GEMM_GRID, 256, 0, stream>>>(gb2, wot, bout, out);
}

// Round 10
// 346.120 us; speedup vs baseline: 3.1164x; 1.0309x over previous
//
#include <hip/hip_runtime.h>
#include <math.h>

#define NN 50000
#define NE 800000
#define KIN 256
#define F 192      // HEADS*HID
#define NH 3
#define NC 40
#define NBLK 49    // ceil(NN/1024) scan blocks

typedef unsigned short u16;
typedef unsigned int   u32;
typedef __attribute__((ext_vector_type(8))) short bf16x8;
typedef __attribute__((ext_vector_type(4))) float f32x4;

static __device__ __forceinline__ u16 f2bf(float f){
  u32 u = __float_as_uint(f);
  u32 r = (u + 0x7fffu + ((u >> 16) & 1u)) >> 16;   // RNE
  return (u16)r;
}

// ---------------- CSR build ----------------
__global__ void count_kernel(const int* __restrict__ dst, int* __restrict__ cnt){
  int e = blockIdx.x*256 + threadIdx.x;
  if (e < NE) atomicAdd(&cnt[dst[e]], 1);
}

__global__ __launch_bounds__(256) void partial_kernel(const int* __restrict__ cnt, int* __restrict__ partials){
  __shared__ int red[256];
  const int t = threadIdx.x;
  const int base = blockIdx.x*1024 + t*4;
  int s = 0;
  if (base + 3 < NN){
    int4 v = *(const int4*)&cnt[base];
    s = v.x + v.y + v.z + v.w;
  } else if (base < NN){
    for (int i=base; i<NN; i++) s += cnt[i];
  }
  red[t] = s;
  __syncthreads();
  for (int off=128; off; off>>=1){
    if (t < off) red[t] += red[t+off];
    __syncthreads();
  }
  if (t==0) partials[blockIdx.x] = red[0];
}

__global__ __launch_bounds__(64) void scan_partials(const int* __restrict__ partials,
                                                    int* __restrict__ offsets, int* __restrict__ row_ptr){
  const int lane = threadIdx.x;
  int p = (lane < NBLK)? partials[lane] : 0;
  int inc = p;
  #pragma unroll
  for (int off=1; off<64; off<<=1){
    int v = __shfl_up(inc, off);
    if (lane >= off) inc += v;
  }
  if (lane < NBLK) offsets[lane] = inc - p;
  if (lane == NBLK-1) row_ptr[NN] = inc;
}

// emit row_ptr AND zero cnt (fill reuses cnt as cursor)
__global__ __launch_bounds__(256) void emit_kernel(int* __restrict__ cnt,
                                                   const int* __restrict__ offsets,
                                                   int* __restrict__ row_ptr){
  __shared__ int ts[256];
  const int t = threadIdx.x;
  const int base = blockIdx.x*1024 + t*4;
  int4 v = make_int4(0,0,0,0);
  if (base + 3 < NN) v = *(const int4*)&cnt[base];
  else if (base < NN){
    v.x = cnt[base];
    if (base+1 < NN) v.y = cnt[base+1];
    if (base+2 < NN) v.z = cnt[base+2];
  }
  int tot = v.x + v.y + v.z + v.w;
  ts[t] = tot;
  __syncthreads();
  #pragma unroll
  for (int off=1; off<256; off<<=1){
    int val = (t >= off)? ts[t-off] : 0;
    __syncthreads();
    ts[t] += val;
    __syncthreads();
  }
  int off0 = offsets[blockIdx.x] + ts[t] - tot;
  if (base + 3 < NN){
    row_ptr[base]   = off0;
    row_ptr[base+1] = off0 + v.x;
    row_ptr[base+2] = off0 + v.x + v.y;
    row_ptr[base+3] = off0 + v.x + v.y + v.z;
    *(int4*)&cnt[base] = make_int4(0,0,0,0);
  } else if (base < NN){
    row_ptr[base] = off0; cnt[base] = 0;
    if (base+1 < NN){ row_ptr[base+1] = off0 + v.x; cnt[base+1] = 0; }
    if (base+2 < NN){ row_ptr[base+2] = off0 + v.x + v.y; cnt[base+2] = 0; }
  }
}

__global__ void fill_kernel(const int* __restrict__ src, const int* __restrict__ dst,
                            const int* __restrict__ row_ptr, int* __restrict__ cur,
                            int* __restrict__ col){
  int e = blockIdx.x*256 + threadIdx.x;
  if (e < NE){
    int d = dst[e];
    int p = row_ptr[d] + atomicAdd(&cur[d], 1);
    col[p] = src[e];
  }
}

// ---------------- merged weight converts (bf16, transposed) ----------------
__global__ void conv_all(const float* __restrict__ W1, const float* __restrict__ W2,
                         const float* __restrict__ Wout,
                         u16* __restrict__ w1t, u16* __restrict__ w2t, u16* __restrict__ wot){
  int e = blockIdx.x*256 + threadIdx.x;
  if (e < F*KIN){
    int c = e / KIN, r = e % KIN;
    w1t[e] = f2bf(W1[(size_t)r*F + c]);
    return;
  }
  int e2 = e - F*KIN;
  if (e2 < F*F){
    int c = e2 / F, r = e2 % F;
    w2t[e2] = f2bf(W2[(size_t)r*F + c]);
    return;
  }
  int e3 = e2 - F*F;
  if (e3 < 48*F){
    int n = e3 / F, k = e3 % F;
    wot[e3] = (n < NC)? f2bf(Wout[(size_t)k*NC + n]) : (u16)0;
  }
}

// ---------------- MFMA GEMM: A[NN x K] @ Bt[192 x K](bf16) -> C[NN x 192](bf16)
// + fused attention dots. CONVA: A is fp32 (converted to bf16 during staging).
// BM=64, BN=192, BK=64. 256 thr = 4 waves; wave w owns cols w*48..w*48+47.
#define SAK 72   // u16 stride; dword stride 36 -> all ds ops <=2-way bank alias (free)
#define SC  196  // u16 stride for C-stage
template<int K, bool CONVA>
__global__ __launch_bounds__(256) void gemm_mfma(const void* __restrict__ Araw, const u16* __restrict__ Bt,
                                                 u16* __restrict__ C,
                                                 const float* __restrict__ att_src, const float* __restrict__ att_dst,
                                                 float* __restrict__ a_src4, float* __restrict__ a_dst4){
  __shared__ __align__(16) union {
    struct { u16 As[64*SAK]; u16 Bs[192*SAK]; } st;
    u16 Cs[64*SC];
  } sh;
  const int t = threadIdx.x;
  const int wave = t >> 6, lane = t & 63;
  const int quad = lane >> 4, l16 = lane & 15;
  const int r0 = blockIdx.x*64;

  f32x4 acc[4][3];
  #pragma unroll
  for (int rt=0;rt<4;rt++)
    #pragma unroll
    for (int ct=0;ct<3;ct++) acc[rt][ct] = (f32x4){0.f,0.f,0.f,0.f};

  for (int k0=0; k0<K; k0+=64){
    __syncthreads();
    // A tile: 64 rows x 64 k; thread -> 32 u16 (two uint4 stores)
    {
      int row = t >> 2, kq = (t & 3)*16;
      bool ok = (r0+row) < NN;
      if (CONVA){
        const float* Af = (const float*)Araw;
        float4 v0 = make_float4(0,0,0,0), v1 = v0, v2 = v0, v3 = v0;
        if (ok){
          const float* p = &Af[(size_t)(r0+row)*K + k0 + kq];
          v0 = *(const float4*)(p+0);
          v1 = *(const float4*)(p+4);
          v2 = *(const float4*)(p+8);
          v3 = *(const float4*)(p+12);
        }
        uint4 pa, pb;
        pa.x = (u32)f2bf(v0.x) | ((u32)f2bf(v0.y) << 16);
        pa.y = (u32)f2bf(v0.z) | ((u32)f2bf(v0.w) << 16);
        pa.z = (u32)f2bf(v1.x) | ((u32)f2bf(v1.y) << 16);
        pa.w = (u32)f2bf(v1.z) | ((u32)f2bf(v1.w) << 16);
        pb.x = (u32)f2bf(v2.x) | ((u32)f2bf(v2.y) << 16);
        pb.y = (u32)f2bf(v2.z) | ((u32)f2bf(v2.w) << 16);
        pb.z = (u32)f2bf(v3.x) | ((u32)f2bf(v3.y) << 16);
        pb.w = (u32)f2bf(v3.z) | ((u32)f2bf(v3.w) << 16);
        *(uint4*)&sh.st.As[row*SAK + kq]     = pa;
        *(uint4*)&sh.st.As[row*SAK + kq + 8] = pb;
      } else {
        const u16* Ab = (const u16*)Araw;
        uint4 va = make_uint4(0,0,0,0), vb = va;
        if (ok){
          va = *(const uint4*)&Ab[(size_t)(r0+row)*K + k0 + kq];
          vb = *(const uint4*)&Ab[(size_t)(r0+row)*K + k0 + kq + 8];
        }
        *(uint4*)&sh.st.As[row*SAK + kq]     = va;
        *(uint4*)&sh.st.As[row*SAK + kq + 8] = vb;
      }
    }
    // B tile: 192 rows x 64 k = 1536 chunks of 8 u16; 6 per thread
    #pragma unroll
    for (int i=0;i<6;i++){
      int idx = t + i*256;
      int n = idx >> 3, kc = idx & 7;
      *(uint4*)&sh.st.Bs[n*SAK + kc*8] = *(const uint4*)&Bt[(size_t)n*K + k0 + kc*8];
    }
    __syncthreads();
    bf16x8 af[4][2], bf[3][2];
    #pragma unroll
    for (int kf=0;kf<2;kf++){
      #pragma unroll
      for (int rt=0;rt<4;rt++) af[rt][kf] = *(const bf16x8*)&sh.st.As[(rt*16 + l16)*SAK + kf*32 + quad*8];
      #pragma unroll
      for (int ct=0;ct<3;ct++) bf[ct][kf] = *(const bf16x8*)&sh.st.Bs[(wave*48 + ct*16 + l16)*SAK + kf*32 + quad*8];
    }
    #pragma unroll
    for (int kf=0;kf<2;kf++)
      #pragma unroll
      for (int rt=0;rt<4;rt++)
        #pragma unroll
        for (int ct=0;ct<3;ct++)
          acc[rt][ct] = __builtin_amdgcn_mfma_f32_16x16x32_bf16(af[rt][kf], bf[ct][kf], acc[rt][ct], 0, 0, 0);
  }

  __syncthreads();   // frag reads done -> safe to overwrite union with Cs
  #pragma unroll
  for (int ct=0;ct<3;ct++){
    const int n = wave*48 + ct*16 + l16;
    #pragma unroll
    for (int rt=0;rt<4;rt++){
      #pragma unroll
      for (int reg=0;reg<4;reg++){
        const int m = rt*16 + quad*4 + reg;
        sh.Cs[m*SC + n] = f2bf(acc[rt][ct][reg]);
      }
    }
  }
  __syncthreads();
  // coalesced C global write: 4 threads/row, 6 chunks of 8 u16 each
  {
    int row = t >> 2, c0 = (t & 3)*6;
    int grow = r0 + row;
    if (grow < NN){
      #pragma unroll
      for (int j=0;j<6;j++){
        int ch = c0 + j;
        uint4 v = *(const uint4*)&sh.Cs[row*SC + ch*8];
        *(uint4*)&C[(size_t)grow*F + ch*8] = v;
      }
    }
  }
  // attention dots: thread (row, head) dots 64 cols from LDS
  if (t < 192){
    int row = t & 63, head = t >> 6;
    int grow = r0 + row;
    if (grow < NN){
      float ps = 0.f, pd = 0.f;
      #pragma unroll
      for (int j=0;j<8;j++){
        uint4 v = *(const uint4*)&sh.Cs[row*SC + head*64 + j*8];
        float4 w0 = *(const float4*)&att_src[head*64 + j*8];
        float4 w1 = *(const float4*)&att_src[head*64 + j*8 + 4];
        float4 d0 = *(const float4*)&att_dst[head*64 + j*8];
        float4 d1 = *(const float4*)&att_dst[head*64 + j*8 + 4];
        float c0f = __uint_as_float(v.x << 16), c1f = __uint_as_float(v.x & 0xffff0000u);
        float c2f = __uint_as_float(v.y << 16), c3f = __uint_as_float(v.y & 0xffff0000u);
        float c4f = __uint_as_float(v.z << 16), c5f = __uint_as_float(v.z & 0xffff0000u);
        float c6f = __uint_as_float(v.w << 16), c7f = __uint_as_float(v.w & 0xffff0000u);
        ps = fmaf(c0f,w0.x,fmaf(c1f,w0.y,fmaf(c2f,w0.z,fmaf(c3f,w0.w,ps))));
        ps = fmaf(c4f,w1.x,fmaf(c5f,w1.y,fmaf(c6f,w1.z,fmaf(c7f,w1.w,ps))));
        pd = fmaf(c0f,d0.x,fmaf(c1f,d0.y,fmaf(c2f,d0.z,fmaf(c3f,d0.w,pd))));
        pd = fmaf(c4f,d1.x,fmaf(c5f,d1.y,fmaf(c6f,d1.z,fmaf(c7f,d1.w,pd))));
      }
      a_src4[(size_t)grow*4 + head] = ps;
      a_dst4[(size_t)grow*4 + head] = pd;
    }
  }
}

// ---------------- GAT aggregation: one WAVE per dst node ----------------
// No max-subtraction (logits bounded). Gather: x4 readlane-explicit (VGPR 32,
// occupancy ~70% — the x8 variant cost 8 VGPR and 20% occupancy, net loss).
__global__ __launch_bounds__(256) void gat_agg_wave(const u16* __restrict__ hb,
    const float* __restrict__ a_src4, const float* __restrict__ a_dst4,
    const int* __restrict__ row_ptr, const int* __restrict__ col,
    const float* __restrict__ bias, u16* __restrict__ out){
  __shared__ float s_al[4][64][4];
  const int t = threadIdx.x;
  const int lane = t & 63;
  const int w = t >> 6;
  const int d = blockIdx.x*4 + w;
  if (d >= NN) return;
  const int e0  = row_ptr[d];
  const int deg = row_ptr[d+1] - e0;
  const int ecount = deg + 1;                 // implicit self-loop at j==deg
  const float4 ad = *(const float4*)&a_dst4[(size_t)d*4];

  float s0=0.f, s1=0.f, s2=0.f;
  int   sn_r = d;
  float e0r=0.f, e1r=0.f, e2r=0.f;
  const int lastBase = ((ecount-1) >> 6) << 6;

  // ---- pass A: softmax denominators (no max shift) ----
  for (int base=0; base<ecount; base+=64){
    int j = base + lane;
    bool valid = j < ecount;
    int sn = d;
    if (j < deg) sn = col[e0+j];
    float4 as = *(const float4*)&a_src4[(size_t)sn*4];
    float l0 = as.x + ad.x; l0 = (l0>0.f)? l0 : 0.2f*l0;
    float l1 = as.y + ad.y; l1 = (l1>0.f)? l1 : 0.2f*l1;
    float l2 = as.z + ad.z; l2 = (l2>0.f)? l2 : 0.2f*l2;
    float E0 = valid? __expf(l0) : 0.f;
    float E1 = valid? __expf(l1) : 0.f;
    float E2 = valid? __expf(l2) : 0.f;
    float S0=E0, S1=E1, S2=E2;
    #pragma unroll
    for (int off=32; off; off>>=1){
      S0 += __shfl_xor(S0, off);
      S1 += __shfl_xor(S1, off);
      S2 += __shfl_xor(S2, off);
    }
    s0 += S0; s1 += S1; s2 += S2;
    sn_r = sn; e0r = E0; e1r = E1; e2r = E2;
  }
  const float i0 = 1.f/s0, i1 = 1.f/s1, i2 = 1.f/s2;

  // ---- pass B: gather ----
  const int cg = (lane < 48)? lane : lane - 48;
  const int hg = (lane < 48)? (lane >> 4) : (lane >> 4) - 3;
  const int cgo = cg*4;
  float4 acc = make_float4(0.f,0.f,0.f,0.f);
  for (int base=0; base<ecount; base+=64){
    int sn; float E0,E1,E2;
    if (base == lastBase){ sn = sn_r; E0 = e0r; E1 = e1r; E2 = e2r; }
    else {
      int j = base + lane;                   // full chunk: always valid
      sn = (j < deg)? col[e0+j] : d;
      float4 as = *(const float4*)&a_src4[(size_t)sn*4];
      float l0 = as.x + ad.x; l0 = (l0>0.f)? l0 : 0.2f*l0;
      float l1 = as.y + ad.y; l1 = (l1>0.f)? l1 : 0.2f*l1;
      float l2 = as.z + ad.z; l2 = (l2>0.f)? l2 : 0.2f*l2;
      E0 = __expf(l0); E1 = __expf(l1); E2 = __expf(l2);
    }
    float4 st;
    st.x = E0*i0; st.y = E1*i1; st.z = E2*i2; st.w = 0.f;
    *(float4*)&s_al[w][lane][0] = st;
    __builtin_amdgcn_wave_barrier();
    int cnt = ecount - base; if (cnt > 64) cnt = 64;
    int jj = 0;
    for (; jj+4 <= cnt; jj += 4){
      int sA = __builtin_amdgcn_readlane(sn, jj);
      int sB = __builtin_amdgcn_readlane(sn, jj+1);
      int sC = __builtin_amdgcn_readlane(sn, jj+2);
      int sD = __builtin_amdgcn_readlane(sn, jj+3);
      uint2 pA = *(const uint2*)(hb + sA*F + cgo);
      uint2 pB = *(const uint2*)(hb + sB*F + cgo);
      uint2 pC = *(const uint2*)(hb + sC*F + cgo);
      uint2 pD = *(const uint2*)(hb + sD*F + cgo);
      float aA = s_al[w][jj  ][hg];
      float aB = s_al[w][jj+1][hg];
      float aC = s_al[w][jj+2][hg];
      float aD = s_al[w][jj+3][hg];
      acc.x = fmaf(aA, __uint_as_float(pA.x << 16),         acc.x);
      acc.y = fmaf(aA, __uint_as_float(pA.x & 0xffff0000u), acc.y);
      acc.z = fmaf(aA, __uint_as_float(pA.y << 16),         acc.z);
      acc.w = fmaf(aA, __uint_as_float(pA.y & 0xffff0000u), acc.w);
      acc.x = fmaf(aB, __uint_as_float(pB.x << 16),         acc.x);
      acc.y = fmaf(aB, __uint_as_float(pB.x & 0xffff0000u), acc.y);
      acc.z = fmaf(aB, __uint_as_float(pB.y << 16),         acc.z);
      acc.w = fmaf(aB, __uint_as_float(pB.y & 0xffff0000u), acc.w);
      acc.x = fmaf(aC, __uint_as_float(pC.x << 16),         acc.x);
      acc.y = fmaf(aC, __uint_as_float(pC.x & 0xffff0000u), acc.y);
      acc.z = fmaf(aC, __uint_as_float(pC.y << 16),         acc.z);
      acc.w = fmaf(aC, __uint_as_float(pC.y & 0xffff0000u), acc.w);
      acc.x = fmaf(aD, __uint_as_float(pD.x << 16),         acc.x);
      acc.y = fmaf(aD, __uint_as_float(pD.x & 0xffff0000u), acc.y);
      acc.z = fmaf(aD, __uint_as_float(pD.y << 16),         acc.z);
      acc.w = fmaf(aD, __uint_as_float(pD.y & 0xffff0000u), acc.w);
    }
    for (; jj < cnt; jj++){
      int sA = __builtin_amdgcn_readlane(sn, jj);
      uint2 pA = *(const uint2*)(hb + sA*F + cgo);
      float aA = s_al[w][jj][hg];
      acc.x = fmaf(aA, __uint_as_float(pA.x << 16),         acc.x);
      acc.y = fmaf(aA, __uint_as_float(pA.x & 0xffff0000u), acc.y);
      acc.z = fmaf(aA, __uint_as_float(pA.y << 16),         acc.z);
      acc.w = fmaf(aA, __uint_as_float(pA.y & 0xffff0000u), acc.w);
    }
    __builtin_amdgcn_wave_barrier();
  }
  if (lane < 48){
    float4 b4 = *(const float4*)&bias[cg*4];
    uint2 o;
    o.x = (u32)f2bf(fmaxf(acc.x + b4.x, 0.f)) | ((u32)f2bf(fmaxf(acc.y + b4.y, 0.f)) << 16);
    o.y = (u32)f2bf(fmaxf(acc.z + b4.z, 0.f)) | ((u32)f2bf(fmaxf(acc.w + b4.w, 0.f)) << 16);
    *(uint2*)&out[(size_t)d*F + cg*4] = o;
  }
}

// ---------------- output GEMM via MFMA, no LDS ----------------
__global__ __launch_bounds__(256) void gemm_out_mfma(const u16* __restrict__ A,
    const u16* __restrict__ Wt, const float* __restrict__ bias, float* __restrict__ out){
  const int t = threadIdx.x;
  const int wave = t >> 6, lane = t & 63;
  const int quad = lane >> 4, l16 = lane & 15;
  const int rbase = blockIdx.x*64 + wave*16;
  const int arow = rbase + l16;
  f32x4 acc[3];
  #pragma unroll
  for (int ct=0;ct<3;ct++) acc[ct] = (f32x4){0.f,0.f,0.f,0.f};
  #pragma unroll
  for (int ks=0; ks<6; ks++){
    const int k0 = ks*32;
    union { uint4 u; bf16x8 h; } cva;
    cva.u = make_uint4(0,0,0,0);
    if (arow < NN) cva.u = *(const uint4*)&A[(size_t)arow*F + k0 + quad*8];
    #pragma unroll
    for (int ct=0;ct<3;ct++){
      bf16x8 bfr = *(const bf16x8*)&Wt[(size_t)(ct*16 + l16)*F + k0 + quad*8];
      acc[ct] = __builtin_amdgcn_mfma_f32_16x16x32_bf16(cva.h, bfr, acc[ct], 0, 0, 0);
    }
  }
  #pragma unroll
  for (int ct=0;ct<3;ct++){
    const int n = ct*16 + l16;
    #pragma unroll
    for (int reg=0;reg<4;reg++){
      const int m = quad*4 + reg;
      const int grow = rbase + m;
      if (grow < NN && n < NC) out[(size_t)grow*NC + n] = acc[ct][reg] + bias[n];
    }
  }
}

extern "C" void kernel_launch(void* const* d_in, const int* in_sizes, int n_in,
                              void* d_out, int out_size, void* d_ws, size_t ws_size,
                              hipStream_t stream){
  const float* x    = (const float*)d_in[0];
  const int*   ei   = (const int*)  d_in[1];
  const float* W1   = (const float*)d_in[2];
  const float* as1  = (const float*)d_in[3];
  const float* ad1  = (const float*)d_in[4];
  const float* b1   = (const float*)d_in[5];
  const float* W2   = (const float*)d_in[6];
  const float* as2  = (const float*)d_in[7];
  const float* ad2  = (const float*)d_in[8];
  const float* b2   = (const float*)d_in[9];
  const float* Wout = (const float*)d_in[10];
  const float* bout = (const float*)d_in[11];
  float* out = (float*)d_out;

  // workspace carve-out
  u16* w1t = (u16*)d_ws;                          // F*KIN  (W1^T bf16)
  u16* w2t = w1t + (size_t)F*KIN;                 // F*F    (W2^T bf16)
  u16* wot = w2t + (size_t)F*F;                   // 48*F   (Wout^T bf16, padded)
  u16* hb1 = wot + (size_t)48*F;                  // NN*F
  u16* hb2 = hb1 + (size_t)NN*F;                  // NN*F
  u16* gb1 = hb2 + (size_t)NN*F;                  // NN*F
  u16* gb2 = gb1 + (size_t)NN*F;                  // NN*F
  float* a_src4 = (float*)(gb2 + (size_t)NN*F);   // NN*4
  float* a_dst4 = a_src4 + (size_t)NN*4;          // NN*4
  int* row_ptr  = (int*)(a_dst4 + (size_t)NN*4);  // NN+1
  int* col      = row_ptr + (NN+1);               // NE
  int* cnt      = col + NE;                       // NN
  int* partials = cnt + NN;                       // NBLK
  int* offsets  = partials + NBLK;                // NBLK

  const int* srcv = ei;
  const int* dstv = ei + NE;

  // CSR by destination (rebuilt every call)
  hipMemsetAsync(cnt, 0, NN*sizeof(int), stream);
  count_kernel<<<(NE+255)/256, 256, 0, stream>>>(dstv, cnt);
  partial_kernel<<<NBLK, 256, 0, stream>>>(cnt, partials);
  scan_partials<<<1, 64, 0, stream>>>(partials, offsets, row_ptr);
  emit_kernel<<<NBLK, 256, 0, stream>>>(cnt, offsets, row_ptr);
  fill_kernel<<<(NE+255)/256, 256, 0, stream>>>(srcv, dstv, row_ptr, cnt, col);

  // merged weight converts
  const int CONV_N = F*KIN + F*F + 48*F;
  conv_all<<<(CONV_N + 255)/256, 256, 0, stream>>>(W1, W2, Wout, w1t, w2t, wot);

  const int GEMM_GRID = (NN + 63)/64;
  const int AGG_GRID  = (NN + 3)/4;
  // layer 1 (x converted to bf16 inside staging)
  gemm_mfma<KIN,true><<<GEMM_GRID, 256, 0, stream>>>(x, w1t, hb1, as1, ad1, a_src4, a_dst4);
  gat_agg_wave<<<AGG_GRID, 256, 0, stream>>>(hb1, a_src4, a_dst4, row_ptr, col, b1, gb1);
  // layer 2
  gemm_mfma<F,false><<<GEMM_GRID, 256, 0, stream>>>(gb1, w2t, hb2, as2, ad2, a_src4, a_dst4);
  gat_agg_wave<<<AGG_GRID, 256, 0, stream>>>(hb2, a_src4, a_dst4, row_ptr, col, b2, gb2);
  // readout
  gemm_out_mfma<<<GEMM_GRID, 256, 0, stream>>>(gb2, wot, bout, out);
}

// Round 11
// 342.098 us; speedup vs baseline: 3.1530x; 1.0118x over previous
//
#include <hip/hip_runtime.h>
#include <math.h>

#define NN 50000
#define NE 800000
#define KIN 256
#define F 192      // HEADS*HID
#define NH 3
#define NC 40
#define NBLK 49    // ceil(NN/1024) scan blocks
#define CNT_BLKS ((NE+255)/256)            // 3125
#define CONV_N (F*KIN + F*F + 48*F)        // 95232
#define CONV_BLKS ((CONV_N+255)/256)       // 372

typedef unsigned short u16;
typedef unsigned int   u32;
typedef __attribute__((ext_vector_type(8))) short bf16x8;
typedef __attribute__((ext_vector_type(4))) float f32x4;

static __device__ __forceinline__ u16 f2bf(float f){
  u32 u = __float_as_uint(f);
  u32 r = (u + 0x7fffu + ((u >> 16) & 1u)) >> 16;   // RNE
  return (u16)r;
}

// ---------------- CSR count + (independent) weight converts, one launch ----------
__global__ void count_conv_kernel(const int* __restrict__ dst, int* __restrict__ cnt,
                                  const float* __restrict__ W1, const float* __restrict__ W2,
                                  const float* __restrict__ Wout,
                                  u16* __restrict__ w1t, u16* __restrict__ w2t, u16* __restrict__ wot){
  int b = blockIdx.x;
  if (b < CNT_BLKS){
    int e = b*256 + threadIdx.x;
    if (e < NE) atomicAdd(&cnt[dst[e]], 1);
    return;
  }
  int e = (b - CNT_BLKS)*256 + threadIdx.x;
  if (e < F*KIN){
    int c = e / KIN, r = e % KIN;
    w1t[e] = f2bf(W1[(size_t)r*F + c]);
    return;
  }
  int e2 = e - F*KIN;
  if (e2 < F*F){
    int c = e2 / F, r = e2 % F;
    w2t[e2] = f2bf(W2[(size_t)r*F + c]);
    return;
  }
  int e3 = e2 - F*F;
  if (e3 < 48*F){
    int n = e3 / F, k = e3 % F;
    wot[e3] = (n < NC)? f2bf(Wout[(size_t)k*NC + n]) : (u16)0;
  }
}

__global__ __launch_bounds__(256) void partial_kernel(const int* __restrict__ cnt, int* __restrict__ partials){
  __shared__ int red[256];
  const int t = threadIdx.x;
  const int base = blockIdx.x*1024 + t*4;
  int s = 0;
  if (base + 3 < NN){
    int4 v = *(const int4*)&cnt[base];
    s = v.x + v.y + v.z + v.w;
  } else if (base < NN){
    for (int i=base; i<NN; i++) s += cnt[i];
  }
  red[t] = s;
  __syncthreads();
  for (int off=128; off; off>>=1){
    if (t < off) red[t] += red[t+off];
    __syncthreads();
  }
  if (t==0) partials[blockIdx.x] = red[0];
}

__global__ __launch_bounds__(64) void scan_partials(const int* __restrict__ partials,
                                                    int* __restrict__ offsets, int* __restrict__ row_ptr){
  const int lane = threadIdx.x;
  int p = (lane < NBLK)? partials[lane] : 0;
  int inc = p;
  #pragma unroll
  for (int off=1; off<64; off<<=1){
    int v = __shfl_up(inc, off);
    if (lane >= off) inc += v;
  }
  if (lane < NBLK) offsets[lane] = inc - p;
  if (lane == NBLK-1) row_ptr[NN] = inc;
}

// emit row_ptr AND zero cnt (fill reuses cnt as cursor)
__global__ __launch_bounds__(256) void emit_kernel(int* __restrict__ cnt,
                                                   const int* __restrict__ offsets,
                                                   int* __restrict__ row_ptr){
  __shared__ int ts[256];
  const int t = threadIdx.x;
  const int base = blockIdx.x*1024 + t*4;
  int4 v = make_int4(0,0,0,0);
  if (base + 3 < NN) v = *(const int4*)&cnt[base];
  else if (base < NN){
    v.x = cnt[base];
    if (base+1 < NN) v.y = cnt[base+1];
    if (base+2 < NN) v.z = cnt[base+2];
  }
  int tot = v.x + v.y + v.z + v.w;
  ts[t] = tot;
  __syncthreads();
  #pragma unroll
  for (int off=1; off<256; off<<=1){
    int val = (t >= off)? ts[t-off] : 0;
    __syncthreads();
    ts[t] += val;
    __syncthreads();
  }
  int off0 = offsets[blockIdx.x] + ts[t] - tot;
  if (base + 3 < NN){
    row_ptr[base]   = off0;
    row_ptr[base+1] = off0 + v.x;
    row_ptr[base+2] = off0 + v.x + v.y;
    row_ptr[base+3] = off0 + v.x + v.y + v.z;
    *(int4*)&cnt[base] = make_int4(0,0,0,0);
  } else if (base < NN){
    row_ptr[base] = off0; cnt[base] = 0;
    if (base+1 < NN){ row_ptr[base+1] = off0 + v.x; cnt[base+1] = 0; }
    if (base+2 < NN){ row_ptr[base+2] = off0 + v.x + v.y; cnt[base+2] = 0; }
  }
}

__global__ void fill_kernel(const int* __restrict__ src, const int* __restrict__ dst,
                            const int* __restrict__ row_ptr, int* __restrict__ cur,
                            int* __restrict__ col){
  int e = blockIdx.x*256 + threadIdx.x;
  if (e < NE){
    int d = dst[e];
    int p = row_ptr[d] + atomicAdd(&cur[d], 1);
    col[p] = src[e];
  }
}

// ---------------- MFMA GEMM: A[NN x K] @ Bt[192 x K](bf16) -> C[NN x 192](bf16)
// + fused attention dots. CONVA: A is fp32 (converted to bf16 during staging).
#define SAK 72   // u16 stride; dword stride 36 -> all ds ops <=2-way bank alias (free)
#define SC  196  // u16 stride for C-stage
template<int K, bool CONVA>
__global__ __launch_bounds__(256) void gemm_mfma(const void* __restrict__ Araw, const u16* __restrict__ Bt,
                                                 u16* __restrict__ C,
                                                 const float* __restrict__ att_src, const float* __restrict__ att_dst,
                                                 float* __restrict__ a_src4, float* __restrict__ a_dst4){
  __shared__ __align__(16) union {
    struct { u16 As[64*SAK]; u16 Bs[192*SAK]; } st;
    u16 Cs[64*SC];
  } sh;
  const int t = threadIdx.x;
  const int wave = t >> 6, lane = t & 63;
  const int quad = lane >> 4, l16 = lane & 15;
  const int r0 = blockIdx.x*64;

  f32x4 acc[4][3];
  #pragma unroll
  for (int rt=0;rt<4;rt++)
    #pragma unroll
    for (int ct=0;ct<3;ct++) acc[rt][ct] = (f32x4){0.f,0.f,0.f,0.f};

  for (int k0=0; k0<K; k0+=64){
    __syncthreads();
    {
      int row = t >> 2, kq = (t & 3)*16;
      bool ok = (r0+row) < NN;
      if (CONVA){
        const float* Af = (const float*)Araw;
        float4 v0 = make_float4(0,0,0,0), v1 = v0, v2 = v0, v3 = v0;
        if (ok){
          const float* p = &Af[(size_t)(r0+row)*K + k0 + kq];
          v0 = *(const float4*)(p+0);
          v1 = *(const float4*)(p+4);
          v2 = *(const float4*)(p+8);
          v3 = *(const float4*)(p+12);
        }
        uint4 pa, pb;
        pa.x = (u32)f2bf(v0.x) | ((u32)f2bf(v0.y) << 16);
        pa.y = (u32)f2bf(v0.z) | ((u32)f2bf(v0.w) << 16);
        pa.z = (u32)f2bf(v1.x) | ((u32)f2bf(v1.y) << 16);
        pa.w = (u32)f2bf(v1.z) | ((u32)f2bf(v1.w) << 16);
        pb.x = (u32)f2bf(v2.x) | ((u32)f2bf(v2.y) << 16);
        pb.y = (u32)f2bf(v2.z) | ((u32)f2bf(v2.w) << 16);
        pb.z = (u32)f2bf(v3.x) | ((u32)f2bf(v3.y) << 16);
        pb.w = (u32)f2bf(v3.z) | ((u32)f2bf(v3.w) << 16);
        *(uint4*)&sh.st.As[row*SAK + kq]     = pa;
        *(uint4*)&sh.st.As[row*SAK + kq + 8] = pb;
      } else {
        const u16* Ab = (const u16*)Araw;
        uint4 va = make_uint4(0,0,0,0), vb = va;
        if (ok){
          va = *(const uint4*)&Ab[(size_t)(r0+row)*K + k0 + kq];
          vb = *(const uint4*)&Ab[(size_t)(r0+row)*K + k0 + kq + 8];
        }
        *(uint4*)&sh.st.As[row*SAK + kq]     = va;
        *(uint4*)&sh.st.As[row*SAK + kq + 8] = vb;
      }
    }
    #pragma unroll
    for (int i=0;i<6;i++){
      int idx = t + i*256;
      int n = idx >> 3, kc = idx & 7;
      *(uint4*)&sh.st.Bs[n*SAK + kc*8] = *(const uint4*)&Bt[(size_t)n*K + k0 + kc*8];
    }
    __syncthreads();
    bf16x8 af[4][2], bf[3][2];
    #pragma unroll
    for (int kf=0;kf<2;kf++){
      #pragma unroll
      for (int rt=0;rt<4;rt++) af[rt][kf] = *(const bf16x8*)&sh.st.As[(rt*16 + l16)*SAK + kf*32 + quad*8];
      #pragma unroll
      for (int ct=0;ct<3;ct++) bf[ct][kf] = *(const bf16x8*)&sh.st.Bs[(wave*48 + ct*16 + l16)*SAK + kf*32 + quad*8];
    }
    #pragma unroll
    for (int kf=0;kf<2;kf++)
      #pragma unroll
      for (int rt=0;rt<4;rt++)
        #pragma unroll
        for (int ct=0;ct<3;ct++)
          acc[rt][ct] = __builtin_amdgcn_mfma_f32_16x16x32_bf16(af[rt][kf], bf[ct][kf], acc[rt][ct], 0, 0, 0);
  }

  __syncthreads();   // frag reads done -> safe to overwrite union with Cs
  #pragma unroll
  for (int ct=0;ct<3;ct++){
    const int n = wave*48 + ct*16 + l16;
    #pragma unroll
    for (int rt=0;rt<4;rt++){
      #pragma unroll
      for (int reg=0;reg<4;reg++){
        const int m = rt*16 + quad*4 + reg;
        sh.Cs[m*SC + n] = f2bf(acc[rt][ct][reg]);
      }
    }
  }
  __syncthreads();
  {
    int row = t >> 2, c0 = (t & 3)*6;
    int grow = r0 + row;
    if (grow < NN){
      #pragma unroll
      for (int j=0;j<6;j++){
        int ch = c0 + j;
        uint4 v = *(const uint4*)&sh.Cs[row*SC + ch*8];
        *(uint4*)&C[(size_t)grow*F + ch*8] = v;
      }
    }
  }
  if (t < 192){
    int row = t & 63, head = t >> 6;
    int grow = r0 + row;
    if (grow < NN){
      float ps = 0.f, pd = 0.f;
      #pragma unroll
      for (int j=0;j<8;j++){
        uint4 v = *(const uint4*)&sh.Cs[row*SC + head*64 + j*8];
        float4 w0 = *(const float4*)&att_src[head*64 + j*8];
        float4 w1 = *(const float4*)&att_src[head*64 + j*8 + 4];
        float4 d0 = *(const float4*)&att_dst[head*64 + j*8];
        float4 d1 = *(const float4*)&att_dst[head*64 + j*8 + 4];
        float c0f = __uint_as_float(v.x << 16), c1f = __uint_as_float(v.x & 0xffff0000u);
        float c2f = __uint_as_float(v.y << 16), c3f = __uint_as_float(v.y & 0xffff0000u);
        float c4f = __uint_as_float(v.z << 16), c5f = __uint_as_float(v.z & 0xffff0000u);
        float c6f = __uint_as_float(v.w << 16), c7f = __uint_as_float(v.w & 0xffff0000u);
        ps = fmaf(c0f,w0.x,fmaf(c1f,w0.y,fmaf(c2f,w0.z,fmaf(c3f,w0.w,ps))));
        ps = fmaf(c4f,w1.x,fmaf(c5f,w1.y,fmaf(c6f,w1.z,fmaf(c7f,w1.w,ps))));
        pd = fmaf(c0f,d0.x,fmaf(c1f,d0.y,fmaf(c2f,d0.z,fmaf(c3f,d0.w,pd))));
        pd = fmaf(c4f,d1.x,fmaf(c5f,d1.y,fmaf(c6f,d1.z,fmaf(c7f,d1.w,pd))));
      }
      a_src4[(size_t)grow*4 + head] = ps;
      a_dst4[(size_t)grow*4 + head] = pd;
    }
  }
}

// ---------------- GAT aggregation: ONE-PASS, one wave per dst node ----------------
// Unnormalized accumulate: acc = sum_j exp(leaky(l_j)) * h[sn_j]; denominators kept
// as per-lane partials (sl0..2), butterflied ONCE at the end; acc /= s in epilogue.
// No max-shift needed: |logits| <= ~15 here, exp and acc far from fp32 limits
// (validated R9/R10: absmax identical to shifted version).
__global__ __launch_bounds__(256) void gat_agg_wave(const u16* __restrict__ hb,
    const float* __restrict__ a_src4, const float* __restrict__ a_dst4,
    const int* __restrict__ row_ptr, const int* __restrict__ col,
    const float* __restrict__ bias, u16* __restrict__ out){
  __shared__ float s_al[4][64][4];
  const int t = threadIdx.x;
  const int lane = t & 63;
  const int w = t >> 6;
  const int d = blockIdx.x*4 + w;
  if (d >= NN) return;
  const int e0  = row_ptr[d];
  const int deg = row_ptr[d+1] - e0;
  const int ecount = deg + 1;                 // implicit self-loop at j==deg
  const float4 ad = *(const float4*)&a_dst4[(size_t)d*4];

  const int cg = (lane < 48)? lane : lane - 48;
  const int hg = (lane < 48)? (lane >> 4) : 0;
  const int cgo = cg*4;
  float4 acc = make_float4(0.f,0.f,0.f,0.f);
  float sl0=0.f, sl1=0.f, sl2=0.f;            // per-lane denominator partials

  for (int base=0; base<ecount; base+=64){
    int j = base + lane;
    bool valid = j < ecount;
    int sn = d;
    if (j < deg) sn = col[e0+j];
    float4 as = *(const float4*)&a_src4[(size_t)sn*4];
    float l0 = as.x + ad.x; l0 = (l0>0.f)? l0 : 0.2f*l0;
    float l1 = as.y + ad.y; l1 = (l1>0.f)? l1 : 0.2f*l1;
    float l2 = as.z + ad.z; l2 = (l2>0.f)? l2 : 0.2f*l2;
    float E0 = valid? __expf(l0) : 0.f;
    float E1 = valid? __expf(l1) : 0.f;
    float E2 = valid? __expf(l2) : 0.f;
    sl0 += E0; sl1 += E1; sl2 += E2;
    float4 st; st.x = E0; st.y = E1; st.z = E2; st.w = 0.f;
    *(float4*)&s_al[w][lane][0] = st;          // coalesced ds_write_b128
    __builtin_amdgcn_wave_barrier();
    int cnt = ecount - base; if (cnt > 64) cnt = 64;
    int jj = 0;
    for (; jj+4 <= cnt; jj += 4){
      int sA = __builtin_amdgcn_readlane(sn, jj);
      int sB = __builtin_amdgcn_readlane(sn, jj+1);
      int sC = __builtin_amdgcn_readlane(sn, jj+2);
      int sD = __builtin_amdgcn_readlane(sn, jj+3);
      uint2 pA = *(const uint2*)(hb + sA*F + cgo);
      uint2 pB = *(const uint2*)(hb + sB*F + cgo);
      uint2 pC = *(const uint2*)(hb + sC*F + cgo);
      uint2 pD = *(const uint2*)(hb + sD*F + cgo);
      float aA = s_al[w][jj  ][hg];
      float aB = s_al[w][jj+1][hg];
      float aC = s_al[w][jj+2][hg];
      float aD = s_al[w][jj+3][hg];
      acc.x = fmaf(aA, __uint_as_float(pA.x << 16),         acc.x);
      acc.y = fmaf(aA, __uint_as_float(pA.x & 0xffff0000u), acc.y);
      acc.z = fmaf(aA, __uint_as_float(pA.y << 16),         acc.z);
      acc.w = fmaf(aA, __uint_as_float(pA.y & 0xffff0000u), acc.w);
      acc.x = fmaf(aB, __uint_as_float(pB.x << 16),         acc.x);
      acc.y = fmaf(aB, __uint_as_float(pB.x & 0xffff0000u), acc.y);
      acc.z = fmaf(aB, __uint_as_float(pB.y << 16),         acc.z);
      acc.w = fmaf(aB, __uint_as_float(pB.y & 0xffff0000u), acc.w);
      acc.x = fmaf(aC, __uint_as_float(pC.x << 16),         acc.x);
      acc.y = fmaf(aC, __uint_as_float(pC.x & 0xffff0000u), acc.y);
      acc.z = fmaf(aC, __uint_as_float(pC.y << 16),         acc.z);
      acc.w = fmaf(aC, __uint_as_float(pC.y & 0xffff0000u), acc.w);
      acc.x = fmaf(aD, __uint_as_float(pD.x << 16),         acc.x);
      acc.y = fmaf(aD, __uint_as_float(pD.x & 0xffff0000u), acc.y);
      acc.z = fmaf(aD, __uint_as_float(pD.y << 16),         acc.z);
      acc.w = fmaf(aD, __uint_as_float(pD.y & 0xffff0000u), acc.w);
    }
    for (; jj < cnt; jj++){
      int sA = __builtin_amdgcn_readlane(sn, jj);
      uint2 pA = *(const uint2*)(hb + sA*F + cgo);
      float aA = s_al[w][jj][hg];
      acc.x = fmaf(aA, __uint_as_float(pA.x << 16),         acc.x);
      acc.y = fmaf(aA, __uint_as_float(pA.x & 0xffff0000u), acc.y);
      acc.z = fmaf(aA, __uint_as_float(pA.y << 16),         acc.z);
      acc.w = fmaf(aA, __uint_as_float(pA.y & 0xffff0000u), acc.w);
    }
    __builtin_amdgcn_wave_barrier();
  }
  // fold denominators once
  #pragma unroll
  for (int off=32; off; off>>=1){
    sl0 += __shfl_xor(sl0, off);
    sl1 += __shfl_xor(sl1, off);
    sl2 += __shfl_xor(sl2, off);
  }
  if (lane < 48){
    float inv = 1.f / ((hg==0)? sl0 : ((hg==1)? sl1 : sl2));
    float4 b4 = *(const float4*)&bias[cg*4];
    uint2 o;
    o.x = (u32)f2bf(fmaxf(fmaf(acc.x, inv, b4.x), 0.f))
        | ((u32)f2bf(fmaxf(fmaf(acc.y, inv, b4.y), 0.f)) << 16);
    o.y = (u32)f2bf(fmaxf(fmaf(acc.z, inv, b4.z), 0.f))
        | ((u32)f2bf(fmaxf(fmaf(acc.w, inv, b4.w), 0.f)) << 16);
    *(uint2*)&out[(size_t)d*F + cg*4] = o;
  }
}

// ---------------- output GEMM via MFMA, no LDS ----------------
__global__ __launch_bounds__(256) void gemm_out_mfma(const u16* __restrict__ A,
    const u16* __restrict__ Wt, const float* __restrict__ bias, float* __restrict__ out){
  const int t = threadIdx.x;
  const int wave = t >> 6, lane = t & 63;
  const int quad = lane >> 4, l16 = lane & 15;
  const int rbase = blockIdx.x*64 + wave*16;
  const int arow = rbase + l16;
  f32x4 acc[3];
  #pragma unroll
  for (int ct=0;ct<3;ct++) acc[ct] = (f32x4){0.f,0.f,0.f,0.f};
  #pragma unroll
  for (int ks=0; ks<6; ks++){
    const int k0 = ks*32;
    union { uint4 u; bf16x8 h; } cva;
    cva.u = make_uint4(0,0,0,0);
    if (arow < NN) cva.u = *(const uint4*)&A[(size_t)arow*F + k0 + quad*8];
    #pragma unroll
    for (int ct=0;ct<3;ct++){
      bf16x8 bfr = *(const bf16x8*)&Wt[(size_t)(ct*16 + l16)*F + k0 + quad*8];
      acc[ct] = __builtin_amdgcn_mfma_f32_16x16x32_bf16(cva.h, bfr, acc[ct], 0, 0, 0);
    }
  }
  #pragma unroll
  for (int ct=0;ct<3;ct++){
    const int n = ct*16 + l16;
    #pragma unroll
    for (int reg=0;reg<4;reg++){
      const int m = quad*4 + reg;
      const int grow = rbase + m;
      if (grow < NN && n < NC) out[(size_t)grow*NC + n] = acc[ct][reg] + bias[n];
    }
  }
}

extern "C" void kernel_launch(void* const* d_in, const int* in_sizes, int n_in,
                              void* d_out, int out_size, void* d_ws, size_t ws_size,
                              hipStream_t stream){
  const float* x    = (const float*)d_in[0];
  const int*   ei   = (const int*)  d_in[1];
  const float* W1   = (const float*)d_in[2];
  const float* as1  = (const float*)d_in[3];
  const float* ad1  = (const float*)d_in[4];
  const float* b1   = (const float*)d_in[5];
  const float* W2   = (const float*)d_in[6];
  const float* as2  = (const float*)d_in[7];
  const float* ad2  = (const float*)d_in[8];
  const float* b2   = (const float*)d_in[9];
  const float* Wout = (const float*)d_in[10];
  const float* bout = (const float*)d_in[11];
  float* out = (float*)d_out;

  // workspace carve-out
  u16* w1t = (u16*)d_ws;                          // F*KIN  (W1^T bf16)
  u16* w2t = w1t + (size_t)F*KIN;                 // F*F    (W2^T bf16)
  u16* wot = w2t + (size_t)F*F;                   // 48*F   (Wout^T bf16, padded)
  u16* hb1 = wot + (size_t)48*F;                  // NN*F
  u16* hb2 = hb1 + (size_t)NN*F;                  // NN*F
  u16* gb1 = hb2 + (size_t)NN*F;                  // NN*F
  u16* gb2 = gb1 + (size_t)NN*F;                  // NN*F
  float* a_src4 = (float*)(gb2 + (size_t)NN*F);   // NN*4
  float* a_dst4 = a_src4 + (size_t)NN*4;          // NN*4
  int* row_ptr  = (int*)(a_dst4 + (size_t)NN*4);  // NN+1
  int* col      = row_ptr + (NN+1);               // NE
  int* cnt      = col + NE;                       // NN
  int* partials = cnt + NN;                       // NBLK
  int* offsets  = partials + NBLK;                // NBLK

  const int* srcv = ei;
  const int* dstv = ei + NE;

  // CSR by destination (rebuilt every call) + weight converts fused into count
  hipMemsetAsync(cnt, 0, NN*sizeof(int), stream);
  count_conv_kernel<<<CNT_BLKS + CONV_BLKS, 256, 0, stream>>>(dstv, cnt, W1, W2, Wout, w1t, w2t, wot);
  partial_kernel<<<NBLK, 256, 0, stream>>>(cnt, partials);
  scan_partials<<<1, 64, 0, stream>>>(partials, offsets, row_ptr);
  emit_kernel<<<NBLK, 256, 0, stream>>>(cnt, offsets, row_ptr);
  fill_kernel<<<(NE+255)/256, 256, 0, stream>>>(srcv, dstv, row_ptr, cnt, col);

  const int GEMM_GRID = (NN + 63)/64;
  const int AGG_GRID  = (NN + 3)/4;
  // layer 1 (x converted to bf16 inside staging)
  gemm_mfma<KIN,true><<<GEMM_GRID, 256, 0, stream>>>(x, w1t, hb1, as1, ad1, a_src4, a_dst4);
  gat_agg_wave<<<AGG_GRID, 256, 0, stream>>>(hb1, a_src4, a_dst4, row_ptr, col, b1, gb1);
  // layer 2
  gemm_mfma<F,false><<<GEMM_GRID, 256, 0, stream>>>(gb1, w2t, hb2, as2, ad2, a_src4, a_dst4);
  gat_agg_wave<<<AGG_GRID, 256, 0, stream>>>(hb2, a_src4, a_dst4, row_ptr, col, b2, gb2);
  // readout
  gemm_out_mfma<<<GEMM_GRID, 256, 0, stream>>>(gb2, wot, bout, out);
}